// Round 16
// baseline (382.655 us; speedup 1.0000x reference)
//
#include <hip/hip_runtime.h>

typedef unsigned short u16;
typedef unsigned int   u32;
typedef __attribute__((ext_vector_type(8))) short bf16x8;
typedef __attribute__((ext_vector_type(4))) float f32x4;
typedef __attribute__((ext_vector_type(4))) u32   u32x4;

// Problem constants
constexpr int Bc = 2, Cc = 512, Nc = 2048, Mc = 512, Sc = 2560, Kc = 16, PH = 64, AH = 1024;
constexpr int RT = Bc * Nc * Kc;  // 65536 rows (b,n,k)
constexpr float EPS = 1e-5f;

__device__ __forceinline__ u16 f2bf(float f) {
    u32 u = __float_as_uint(f);
    u32 r = (u + 0x7fffu + ((u >> 16) & 1u)) >> 16;  // RNE
    return (u16)r;
}
__device__ __forceinline__ float bf2f(u16 h) { return __uint_as_float(((u32)h) << 16); }

__device__ __forceinline__ void gload_lds16(const void* g, void* l) {
    __builtin_amdgcn_global_load_lds((const __attribute__((address_space(1))) u32*)g,
                                     (__attribute__((address_space(3))) u32*)l, 16, 0, 0);
}

// Bijective XCD-aware workgroup swizzle (m204 form): same-XCD wgs get a
// contiguous run of linear ids. With bn-fastest linearization this makes an
// XCD reuse one A-panel across all bn tiles (L2 locality).
__device__ __forceinline__ void xcd_tiles(u32& bm, u32& bn) {
    u32 gdx = gridDim.x, gdy = gridDim.y;
    u32 nwg = gdx * gdy;
    u32 wg = blockIdx.x + gdx * blockIdx.y;
    u32 q = nwg >> 3, r8 = nwg & 7;
    u32 xcd = wg & 7, loc = wg >> 3;
    u32 swz = (xcd < r8 ? xcd * (q + 1) : r8 * (q + 1) + (xcd - r8) * q) + loc;
    bn = swz % gdy;   // bn fastest within an XCD's contiguous run
    bm = swz / gdy;
}

// lex-min on (d, s): total order, associative -> tree order == scan order
__device__ __forceinline__ void lmin(float& da, int& sa, float db, int sb) {
    bool better = (db < da) || (db == da && sb < sa);
    da = better ? db : da;
    sa = better ? sb : sa;
}

// ---------------------------------------------------------------------------
// Transpose fusion_feat [B,C,S(split)] f32 -> featT [B,S,C] f32
// ---------------------------------------------------------------------------
__global__ __launch_bounds__(256) void transpose_kernel(const float* __restrict__ feat,
                                                        const float* __restrict__ feat_db,
                                                        float* __restrict__ featT) {
    __shared__ float tile[64][65];
    int bid = blockIdx.x;
    int b = bid / (40 * 8);
    int rem = bid - b * (40 * 8);
    int st = rem >> 3, ct = rem & 7;
    int t = threadIdx.x, lane = t & 63, g = t >> 6;
    int s0 = st * 64, c0 = ct * 64;
    const float* src;
    int sl0, stride;
    if (s0 < Nc) { src = feat + (size_t)b * Cc * Nc; sl0 = s0; stride = Nc; }
    else         { src = feat_db + (size_t)b * Cc * Mc; sl0 = s0 - Nc; stride = Mc; }
#pragma unroll
    for (int i = 0; i < 16; i++) {
        int cl = g * 16 + i;
        tile[cl][lane] = src[(size_t)(c0 + cl) * stride + sl0 + lane];
    }
    __syncthreads();
#pragma unroll
    for (int i = 0; i < 16; i++) {
        int sl = g * 16 + i;
        featT[((size_t)b * Sc + s0 + sl) * Cc + c0 + lane] = tile[lane][sl];
    }
}

// ---------------------------------------------------------------------------
// Weight prep: fold attn BN into W1/bias1, cast attn W1/W2 + pos W2 to bf16
// ---------------------------------------------------------------------------
__global__ __launch_bounds__(256) void prep_kernel(const float* __restrict__ aw1, const float* __restrict__ ab1,
                                                   const float* __restrict__ ag, const float* __restrict__ abb,
                                                   const float* __restrict__ am, const float* __restrict__ av,
                                                   const float* __restrict__ aw2, const float* __restrict__ pw2,
                                                   u16* __restrict__ W1b, float* __restrict__ bias1,
                                                   u16* __restrict__ W2b, u16* __restrict__ PW2b) {
    int i = blockIdx.x * 256 + threadIdx.x;  // grid covers 524288
    if (i < AH * Cc) {
        int o = i >> 9;
        float inv = ag[o] / sqrtf(av[o] + EPS);
        W1b[i] = f2bf(aw1[i] * inv);
    }
    if (i < AH) {
        float inv = ag[i] / sqrtf(av[i] + EPS);
        bias1[i] = ab1[i] * inv + abb[i] - am[i] * inv;
    }
    if (i < Cc * AH) W2b[i] = f2bf(aw2[i]);
    if (i < Cc * PH) PW2b[i] = f2bf(pw2[i]);
}

// ---------------------------------------------------------------------------
// KNN (v1 + tree-scan): one wave per query; distances mirror the reference
// decomposition qq + ss - 2*dot, no fma contraction; ties -> smaller index.
// ---------------------------------------------------------------------------
__global__ __launch_bounds__(256) void knn_kernel(const float* __restrict__ pcd,
                                                  const float* __restrict__ pcd_db,
                                                  int* __restrict__ idxout) {
    int t = threadIdx.x, w = t >> 6, l = t & 63;
    int q = blockIdx.x * 4 + w;  // 0..4095
    int b = q >> 11, n = q & (Nc - 1);
    const float* pc = pcd + (size_t)b * 3 * Nc;
    const float* pd = pcd_db + (size_t)b * 3 * Mc;
    float qx = pc[n], qy = pc[Nc + n], qz = pc[2 * Nc + n];
    float qq = __fadd_rn(__fadd_rn(__fmul_rn(qx, qx), __fmul_rn(qy, qy)), __fmul_rn(qz, qz));
    float dist[40];
#pragma unroll
    for (int j = 0; j < 40; j++) {
        int s = j * 64 + l;
        float sx, sy, sz;
        if (s < Nc) { sx = pc[s]; sy = pc[Nc + s]; sz = pc[2 * Nc + s]; }
        else { int ss = s - Nc; sx = pd[ss]; sy = pd[Mc + ss]; sz = pd[2 * Mc + ss]; }
        float ss2 = __fadd_rn(__fadd_rn(__fmul_rn(sx, sx), __fmul_rn(sy, sy)), __fmul_rn(sz, sz));
        float dt  = __fadd_rn(__fadd_rn(__fmul_rn(qx, sx), __fmul_rn(qy, sy)), __fmul_rn(qz, sz));
        dist[j] = __fsub_rn(__fadd_rn(qq, ss2), __fmul_rn(2.0f, dt));
    }
    for (int r = 0; r < 16; r++) {
        // tree lex-min over the 40 (dist[j], j*64+l) pairs
        float td[20];
        int   ts[20];
#pragma unroll
        for (int i = 0; i < 20; i++) {
            float d0 = dist[2 * i], d1 = dist[2 * i + 1];
            int s0 = (2 * i) * 64 + l, s1 = (2 * i + 1) * 64 + l;
            bool bt = (d1 < d0) || (d1 == d0 && s1 < s0);
            td[i] = bt ? d1 : d0;
            ts[i] = bt ? s1 : s0;
        }
#pragma unroll
        for (int i = 0; i < 10; i++) lmin(td[i], ts[i], td[i + 10], ts[i + 10]);
#pragma unroll
        for (int i = 0; i < 5; i++) lmin(td[i], ts[i], td[i + 5], ts[i + 5]);
        lmin(td[0], ts[0], td[3], ts[3]);
        lmin(td[1], ts[1], td[4], ts[4]);
        lmin(td[0], ts[0], td[2], ts[2]);
        lmin(td[0], ts[0], td[1], ts[1]);
        float bd = td[0];
        int   bs = ts[0];
        for (int off = 32; off; off >>= 1) {
            float od = __shfl_xor(bd, off);
            int   os = __shfl_xor(bs, off);
            bool better = (od < bd) || (od == bd && os < bs);
            bd = better ? od : bd;
            bs = better ? os : bs;
        }
        if (l == 0) idxout[q * 16 + r] = bs;
        int wj = bs >> 6, wl = bs & 63;
        if (l == wl) {
#pragma unroll
            for (int j = 0; j < 40; j++)
                if (j == wj) dist[j] = 1e30f;
        }
    }
}

// ---------------------------------------------------------------------------
// HKER: per row, pos-MLP layer-1: h[r][64] = relu(BN(W1 (q - s) + b1)) bf16
// ---------------------------------------------------------------------------
__global__ __launch_bounds__(256) void hker(const float* __restrict__ pcd, const float* __restrict__ pcd_db,
                                            const int* __restrict__ idxb,
                                            const float* __restrict__ pw1, const float* __restrict__ pb1,
                                            const float* __restrict__ pg, const float* __restrict__ pbb,
                                            const float* __restrict__ pm, const float* __restrict__ pv,
                                            u16* __restrict__ H) {
    __shared__ float W1s[64][4];
    int t = threadIdx.x;
    if (t < 64) {
        float inv = pg[t] / sqrtf(pv[t] + EPS);
        W1s[t][0] = pw1[t * 3 + 0] * inv;
        W1s[t][1] = pw1[t * 3 + 1] * inv;
        W1s[t][2] = pw1[t * 3 + 2] * inv;
        W1s[t][3] = pb1[t] * inv + pbb[t] - pm[t] * inv;
    }
    __syncthreads();
    int r = blockIdx.x * 256 + t;
    int b = r >> 15, n = (r >> 4) & (Nc - 1), s = idxb[r];
    const float* pc = pcd + (size_t)b * 3 * Nc;
    float qx = pc[n], qy = pc[Nc + n], qz = pc[2 * Nc + n];
    float sx, sy, sz;
    if (s < Nc) { sx = pc[s]; sy = pc[Nc + s]; sz = pc[2 * Nc + s]; }
    else {
        const float* pd = pcd_db + (size_t)b * 3 * Mc;
        int ss = s - Nc;
        sx = pd[ss]; sy = pd[Mc + ss]; sz = pd[2 * Mc + ss];
    }
    float dx = qx - sx, dy = qy - sy, dz = qz - sz;
    u16* hp = H + (size_t)r * 64;
#pragma unroll
    for (int u0 = 0; u0 < 64; u0 += 8) {
        u16 e[8];
#pragma unroll
        for (int j = 0; j < 8; j++) {
            int u = u0 + j;
            float hv = fmaxf(0.f, dx * W1s[u][0] + dy * W1s[u][1] + dz * W1s[u][2] + W1s[u][3]);
            e[j] = f2bf(hv);
        }
        u32x4 pk;
        pk.x = (u32)e[0] | ((u32)e[1] << 16); pk.y = (u32)e[2] | ((u32)e[3] << 16);
        pk.z = (u32)e[4] | ((u32)e[5] << 16); pk.w = (u32)e[6] | ((u32)e[7] << 16);
        *(u32x4*)(hp + u0) = pk;
    }
}

// ---------------------------------------------------------------------------
// PGEMM_FUSED: P = H @ PW2^T + pb2 via MFMA (M=rows, N=512, K=64), epilogue
// gathers f,g from featT and emits X = f-g+p, V = g+p (bf16).
// ---------------------------------------------------------------------------
__global__ __launch_bounds__(256) void pgemm_fused(const u16* __restrict__ Hg, const u16* __restrict__ Bg,
                                                   const float* __restrict__ pb2,
                                                   const float* __restrict__ featT, const int* __restrict__ idxb,
                                                   u16* __restrict__ X, u16* __restrict__ V, int row0) {
    __shared__ u16 As[128 * 64];
    __shared__ u16 Bs[128 * 64];
    const int t = threadIdx.x;
    u32 bmu, bnu;
    xcd_tiles(bmu, bnu);
    const int bm = (int)bmu, bn = (int)bnu;
    const int w = t >> 6, l = t & 63;
    const int wr = w >> 1, wc = w & 1;
    const int fr = l & 15, fq = l >> 4;
    f32x4 acc[4][4];
#pragma unroll
    for (int i = 0; i < 4; i++)
#pragma unroll
        for (int j = 0; j < 4; j++) {
            f32x4 z = {0.f, 0.f, 0.f, 0.f};
            acc[i][j] = z;
        }
    const char* Abase = (const char*)Hg + ((size_t)row0 + (size_t)bm * 128) * 64 * 2;
    const char* Bbase = (const char*)Bg + (size_t)bn * 128 * 64 * 2;
#pragma unroll
    for (int i = 0; i < 4; i++) {
        int chunk = i * 256 + t;
        int row = chunk >> 3;
        int cb = (chunk & 7) * 16;
        gload_lds16(Abase + (size_t)row * 128 + cb, (char*)As + chunk * 16);
    }
#pragma unroll
    for (int i = 0; i < 4; i++) {
        int chunk = i * 256 + t;
        int row = chunk >> 3;
        int cb = (chunk & 7) * 16;
        gload_lds16(Bbase + (size_t)row * 128 + cb, (char*)Bs + chunk * 16);
    }
    __syncthreads();
    bf16x8 af[4][2], bfv[4][2];
#pragma unroll
    for (int mf = 0; mf < 4; mf++)
#pragma unroll
        for (int ks = 0; ks < 2; ks++)
            af[mf][ks] = *(const bf16x8*)&As[(wr * 64 + mf * 16 + fr) * 64 + ks * 32 + fq * 8];
#pragma unroll
    for (int nf = 0; nf < 4; nf++)
#pragma unroll
        for (int ks = 0; ks < 2; ks++)
            bfv[nf][ks] = *(const bf16x8*)&Bs[(wc * 64 + nf * 16 + fr) * 64 + ks * 32 + fq * 8];
#pragma unroll
    for (int mf = 0; mf < 4; mf++)
#pragma unroll
        for (int nf = 0; nf < 4; nf++)
#pragma unroll
            for (int ks = 0; ks < 2; ks++)
                acc[mf][nf] = __builtin_amdgcn_mfma_f32_16x16x32_bf16(af[mf][ks], bfv[nf][ks], acc[mf][nf], 0, 0, 0);
    // epilogue: per C-row gather f,g; emit X,V
#pragma unroll
    for (int mf = 0; mf < 4; mf++) {
#pragma unroll
        for (int r = 0; r < 4; r++) {
            int gr = bm * 128 + wr * 64 + mf * 16 + fq * 4 + r;  // chunk-local row
            int grow = row0 + gr;                                 // global row
            int b = grow >> 15;
            int n = (grow >> 4) & (Nc - 1);
            int s = idxb[grow];
            const float* frow = featT + ((size_t)b * Sc + n) * Cc;
            const float* grow_p = featT + ((size_t)b * Sc + s) * Cc;
#pragma unroll
            for (int nf = 0; nf < 4; nf++) {
                int gn = bn * 128 + wc * 64 + nf * 16 + fr;
                float p = acc[mf][nf][r] + pb2[gn];
                float fv = frow[gn];
                float gv = grow_p[gn];
                X[(size_t)gr * Cc + gn] = f2bf(fv - gv + p);
                V[(size_t)gr * Cc + gn] = f2bf(gv + p);
            }
        }
    }
}

// ---------------------------------------------------------------------------
// GEMM (m97 structure + XCD swizzle): C[m][n] = f(sum_k A[m][k]*B[n][k]+bias)
// A [M][Kd] bf16, B [N][Kd] bf16 (i.e. B^T layout), 128x128 tile, BK=64.
// ---------------------------------------------------------------------------
template <bool RELU, bool OBF16>
__global__ __launch_bounds__(256) void gemm_bt(const u16* __restrict__ Ag, const u16* __restrict__ Bg,
                                               const float* __restrict__ bias, void* __restrict__ Cg,
                                               int M, int N, int Kd) {
    __shared__ u16 As[128 * 64];
    __shared__ u16 Bs[128 * 64];
    const int t = threadIdx.x;
    u32 bmu, bnu;
    xcd_tiles(bmu, bnu);
    const int bm = (int)bmu, bn = (int)bnu;
    const int w = t >> 6, l = t & 63;
    const int wr = w >> 1, wc = w & 1;
    const int fr = l & 15, fq = l >> 4;
    f32x4 acc[4][4];
#pragma unroll
    for (int i = 0; i < 4; i++)
#pragma unroll
        for (int j = 0; j < 4; j++) {
            f32x4 z = {0.f, 0.f, 0.f, 0.f};
            acc[i][j] = z;
        }
    const char* Abase = (const char*)Ag + (size_t)bm * 128 * (size_t)Kd * 2;
    const char* Bbase = (const char*)Bg + (size_t)bn * 128 * (size_t)Kd * 2;
    const size_t ldb = (size_t)Kd * 2;

    for (int kt = 0; kt < Kd; kt += 64) {
#pragma unroll
        for (int i = 0; i < 4; i++) {
            int chunk = i * 256 + t;
            int row = chunk >> 3;
            int cb = (chunk & 7) * 16;
            gload_lds16(Abase + (size_t)row * ldb + (size_t)kt * 2 + cb, (char*)As + chunk * 16);
        }
#pragma unroll
        for (int i = 0; i < 4; i++) {
            int chunk = i * 256 + t;
            int row = chunk >> 3;
            int cb = (chunk & 7) * 16;
            gload_lds16(Bbase + (size_t)row * ldb + (size_t)kt * 2 + cb, (char*)Bs + chunk * 16);
        }
        __syncthreads();
        bf16x8 af[4][2], bfv[4][2];
#pragma unroll
        for (int mf = 0; mf < 4; mf++)
#pragma unroll
            for (int ks = 0; ks < 2; ks++)
                af[mf][ks] = *(const bf16x8*)&As[(wr * 64 + mf * 16 + fr) * 64 + ks * 32 + fq * 8];
#pragma unroll
        for (int nf = 0; nf < 4; nf++)
#pragma unroll
            for (int ks = 0; ks < 2; ks++)
                bfv[nf][ks] = *(const bf16x8*)&Bs[(wc * 64 + nf * 16 + fr) * 64 + ks * 32 + fq * 8];
#pragma unroll
        for (int mf = 0; mf < 4; mf++)
#pragma unroll
            for (int nf = 0; nf < 4; nf++)
#pragma unroll
                for (int ks = 0; ks < 2; ks++)
                    acc[mf][nf] = __builtin_amdgcn_mfma_f32_16x16x32_bf16(af[mf][ks], bfv[nf][ks], acc[mf][nf], 0, 0, 0);
        __syncthreads();
    }
#pragma unroll
    for (int mf = 0; mf < 4; mf++) {
#pragma unroll
        for (int nf = 0; nf < 4; nf++) {
            int gn = bn * 128 + wc * 64 + nf * 16 + fr;
            float bi = bias[gn];
            int gm0 = bm * 128 + wr * 64 + mf * 16 + fq * 4;
#pragma unroll
            for (int r = 0; r < 4; r++) {
                float v = acc[mf][nf][r] + bi;
                if (RELU) v = fmaxf(v, 0.f);
                size_t o = (size_t)(gm0 + r) * N + gn;
                if (OBF16) ((u16*)Cg)[o] = f2bf(v);
                else ((float*)Cg)[o] = v;
            }
        }
    }
}

// ---------------------------------------------------------------------------
// GEMM2_FUSED (BM=64): logits L = A @ W2^T + ab2 (M=rows, N=512, K=1024)
// with softmax-over-k + weighted-V reduce fused into the epilogue.
// ---------------------------------------------------------------------------
__global__ __launch_bounds__(256) void gemm2_fused(const u16* __restrict__ Ag, const u16* __restrict__ Bg,
                                                   const float* __restrict__ bias, const u16* __restrict__ Vb,
                                                   float* __restrict__ out, int row0, int Kd) {
    __shared__ u16 smem[12288];  // As [64][64] 8KB + Bs [128][64] 16KB; V tile [64][128] 16KB reuses
    u16* As = smem;
    u16* Bs = smem + 64 * 64;
    const int t = threadIdx.x;
    u32 bmu, bnu;
    xcd_tiles(bmu, bnu);
    const int bm = (int)bmu, bn = (int)bnu;
    const int w = t >> 6, l = t & 63;
    const int wr = w >> 1, wc = w & 1;
    const int fr = l & 15, fq = l >> 4;
    f32x4 acc[2][4];
#pragma unroll
    for (int i = 0; i < 2; i++)
#pragma unroll
        for (int j = 0; j < 4; j++) {
            f32x4 z = {0.f, 0.f, 0.f, 0.f};
            acc[i][j] = z;
        }
    const char* Abase = (const char*)Ag + (size_t)bm * 64 * (size_t)Kd * 2;
    const char* Bbase = (const char*)Bg + (size_t)bn * 128 * (size_t)Kd * 2;
    const size_t ldb = (size_t)Kd * 2;

    for (int kt = 0; kt < Kd; kt += 64) {
#pragma unroll
        for (int i = 0; i < 2; i++) {
            int chunk = i * 256 + t;       // 0..511 (64 rows x 8 chunks)
            int row = chunk >> 3;
            int cb = (chunk & 7) * 16;
            gload_lds16(Abase + (size_t)row * ldb + (size_t)kt * 2 + cb, (char*)As + chunk * 16);
        }
#pragma unroll
        for (int i = 0; i < 4; i++) {
            int chunk = i * 256 + t;       // 0..1023 (128 rows x 8 chunks)
            int row = chunk >> 3;
            int cb = (chunk & 7) * 16;
            gload_lds16(Bbase + (size_t)row * ldb + (size_t)kt * 2 + cb, (char*)Bs + chunk * 16);
        }
        __syncthreads();
        bf16x8 af[2][2], bfv[4][2];
#pragma unroll
        for (int mf = 0; mf < 2; mf++)
#pragma unroll
            for (int ks = 0; ks < 2; ks++)
                af[mf][ks] = *(const bf16x8*)&As[(wr * 32 + mf * 16 + fr) * 64 + ks * 32 + fq * 8];
#pragma unroll
        for (int nf = 0; nf < 4; nf++)
#pragma unroll
            for (int ks = 0; ks < 2; ks++)
                bfv[nf][ks] = *(const bf16x8*)&Bs[(wc * 64 + nf * 16 + fr) * 64 + ks * 32 + fq * 8];
#pragma unroll
        for (int mf = 0; mf < 2; mf++)
#pragma unroll
            for (int nf = 0; nf < 4; nf++)
#pragma unroll
                for (int ks = 0; ks < 2; ks++)
                    acc[mf][nf] = __builtin_amdgcn_mfma_f32_16x16x32_bf16(af[mf][ks], bfv[nf][ks], acc[mf][nf], 0, 0, 0);
        __syncthreads();
    }
    // stage V tile [bm*64 .. +64)[bn*128 .. +128) into LDS (coalesced)
    const char* Vbase = (const char*)Vb + (size_t)bm * 64 * Cc * 2 + (size_t)bn * 256;
#pragma unroll
    for (int i = 0; i < 4; i++) {
        int chunk = i * 256 + t;       // 0..1023
        int row = chunk >> 4;          // 0..63
        int cb = (chunk & 15) * 16;    // byte offset in row (256B rows)
        gload_lds16(Vbase + (size_t)row * (Cc * 2) + cb, (char*)smem + chunk * 16);
    }
    __syncthreads();
    // fused epilogue: per (point, channel) softmax over k=fq*4+r + V-reduce
#pragma unroll
    for (int mf = 0; mf < 2; mf++) {
        int lp = bm * 4 + wr * 2 + mf;        // chunk-local point
        int gp = row0 / 16 + lp;              // global point
        int bb = gp >> 11, nn = gp & (Nc - 1);
        int vrow = (wr * 2 + mf) * 16 + fq * 4;  // tile-local V row for r=0
#pragma unroll
        for (int nf = 0; nf < 4; nf++) {
            int gn = bn * 128 + wc * 64 + nf * 16 + fr;
            int vch = wc * 64 + nf * 16 + fr;
            float bi = bias[gn];
            float v0 = acc[mf][nf][0] + bi, v1 = acc[mf][nf][1] + bi;
            float v2 = acc[mf][nf][2] + bi, v3 = acc[mf][nf][3] + bi;
            float mx = fmaxf(fmaxf(v0, v1), fmaxf(v2, v3));
            mx = fmaxf(mx, __shfl_xor(mx, 16));
            mx = fmaxf(mx, __shfl_xor(mx, 32));
            float e0 = __expf(v0 - mx), e1 = __expf(v1 - mx);
            float e2 = __expf(v2 - mx), e3 = __expf(v3 - mx);
            float ws = e0 * bf2f(smem[(size_t)vrow * 128 + vch])
                     + e1 * bf2f(smem[(size_t)(vrow + 1) * 128 + vch])
                     + e2 * bf2f(smem[(size_t)(vrow + 2) * 128 + vch])
                     + e3 * bf2f(smem[(size_t)(vrow + 3) * 128 + vch]);
            float es = e0 + e1 + e2 + e3;
            ws += __shfl_xor(ws, 16); ws += __shfl_xor(ws, 32);
            es += __shfl_xor(es, 16); es += __shfl_xor(es, 32);
            if (fq == 0) out[((size_t)bb * Cc + gn) * Nc + nn] = ws / es;
        }
    }
}

// ---------------------------------------------------------------------------
extern "C" void kernel_launch(void* const* d_in, const int* in_sizes, int n_in,
                              void* d_out, int out_size, void* d_ws, size_t ws_size,
                              hipStream_t stream) {
    (void)in_sizes; (void)n_in; (void)out_size;
    const float* pcd     = (const float*)d_in[0];
    const float* feat    = (const float*)d_in[1];
    const float* pcd_db  = (const float*)d_in[2];
    const float* feat_db = (const float*)d_in[3];
    const float* pw1 = (const float*)d_in[4];
    const float* pb1 = (const float*)d_in[5];
    const float* pg  = (const float*)d_in[6];
    const float* pbb = (const float*)d_in[7];
    const float* pm  = (const float*)d_in[8];
    const float* pv  = (const float*)d_in[9];
    const float* pw2 = (const float*)d_in[10];
    const float* pb2 = (const float*)d_in[11];
    const float* aw1 = (const float*)d_in[12];
    const float* ab1 = (const float*)d_in[13];
    const float* ag  = (const float*)d_in[14];
    const float* abb = (const float*)d_in[15];
    const float* am  = (const float*)d_in[16];
    const float* av  = (const float*)d_in[17];
    const float* aw2 = (const float*)d_in[18];
    const float* ab2 = (const float*)d_in[19];
    float* out = (float*)d_out;

    char* base = (char*)d_ws;
    size_t off = 0;
    auto alloc = [&](size_t bytes) -> char* {
        char* r = base + off;
        off = (off + bytes + 255) & ~(size_t)255;
        return r;
    };
    int*   idxb  = (int*)alloc((size_t)RT * 4);
    float* featT = (float*)alloc((size_t)Bc * Sc * Cc * 4);
    u16*   W1b   = (u16*)alloc((size_t)AH * Cc * 2);
    float* bias1 = (float*)alloc((size_t)AH * 4);
    u16*   W2b   = (u16*)alloc((size_t)Cc * AH * 2);
    u16*   PW2b  = (u16*)alloc((size_t)Cc * PH * 2);
    u16*   Hb    = (u16*)alloc((size_t)RT * PH * 2);

    // single-chunk pipeline (cr=RT): chunking buys no L3 retention (FETCH
    // evidence rounds 13-15) and costs grid concurrency + launch count.
    const size_t perrow = 1024 + 1024 + 2048;  // X,V bf16 + A bf16
    int cr = RT;
    size_t avail = ws_size > off ? ws_size - off : 0;
    if (avail < (size_t)cr * perrow) {
        cr = (int)((avail / perrow) & ~(size_t)127);
        if (cr < 128) cr = 128;
    }
    u16*   Xb = (u16*)alloc((size_t)cr * Cc * 2);
    u16*   Vb = (u16*)alloc((size_t)cr * Cc * 2);
    u16*   Ab = (u16*)alloc((size_t)cr * AH * 2);

    transpose_kernel<<<dim3(Bc * 40 * 8), dim3(256), 0, stream>>>(feat, feat_db, featT);
    prep_kernel<<<dim3((AH * Cc) / 256), dim3(256), 0, stream>>>(aw1, ab1, ag, abb, am, av, aw2, pw2,
                                                                 W1b, bias1, W2b, PW2b);
    knn_kernel<<<dim3(Bc * Nc / 4), dim3(256), 0, stream>>>(pcd, pcd_db, idxb);
    hker<<<dim3(RT / 256), dim3(256), 0, stream>>>(pcd, pcd_db, idxb, pw1, pb1, pg, pbb, pm, pv, Hb);

    for (int r0 = 0; r0 < RT; r0 += cr) {
        int rows = (RT - r0 < cr) ? (RT - r0) : cr;
        pgemm_fused<<<dim3(rows / 128, Cc / 128), dim3(256), 0, stream>>>(Hb, PW2b, pb2, featT, idxb,
                                                                          Xb, Vb, r0);
        gemm_bt<true, true><<<dim3(rows / 128, AH / 128), dim3(256), 0, stream>>>(Xb, W1b, bias1, Ab, rows, AH, Cc);
        gemm2_fused<<<dim3(rows / 64, Cc / 128), dim3(256), 0, stream>>>(Ab, W2b, ab2, Vb, out, r0, AH);
    }
}

// Round 17
// 338.263 us; speedup vs baseline: 1.1312x; 1.1312x over previous
//
#include <hip/hip_runtime.h>

typedef unsigned short u16;
typedef unsigned int   u32;
typedef __attribute__((ext_vector_type(8))) short bf16x8;
typedef __attribute__((ext_vector_type(4))) float f32x4;
typedef __attribute__((ext_vector_type(4))) u32   u32x4;

// Problem constants
constexpr int Bc = 2, Cc = 512, Nc = 2048, Mc = 512, Sc = 2560, Kc = 16, PH = 64, AH = 1024;
constexpr int RT = Bc * Nc * Kc;  // 65536 rows (b,n,k)
constexpr float EPS = 1e-5f;

__device__ __forceinline__ u16 f2bf(float f) {
    u32 u = __float_as_uint(f);
    u32 r = (u + 0x7fffu + ((u >> 16) & 1u)) >> 16;  // RNE
    return (u16)r;
}
__device__ __forceinline__ float bf2f(u16 h) { return __uint_as_float(((u32)h) << 16); }

__device__ __forceinline__ void gload_lds16(const void* g, void* l) {
    __builtin_amdgcn_global_load_lds((const __attribute__((address_space(1))) u32*)g,
                                     (__attribute__((address_space(3))) u32*)l, 16, 0, 0);
}

// Bijective XCD-aware workgroup swizzle (m204 form): same-XCD wgs get a
// contiguous run of linear ids. With bn-fastest linearization this makes an
// XCD reuse one A-panel across all bn tiles (L2 locality).
__device__ __forceinline__ void xcd_tiles(u32& bm, u32& bn) {
    u32 gdx = gridDim.x, gdy = gridDim.y;
    u32 nwg = gdx * gdy;
    u32 wg = blockIdx.x + gdx * blockIdx.y;
    u32 q = nwg >> 3, r8 = nwg & 7;
    u32 xcd = wg & 7, loc = wg >> 3;
    u32 swz = (xcd < r8 ? xcd * (q + 1) : r8 * (q + 1) + (xcd - r8) * q) + loc;
    bn = swz % gdy;   // bn fastest within an XCD's contiguous run
    bm = swz / gdy;
}

// lex-min on (d, s): total order, associative -> tree order == scan order
__device__ __forceinline__ void lmin(float& da, int& sa, float db, int sb) {
    bool better = (db < da) || (db == da && sb < sa);
    da = better ? db : da;
    sa = better ? sb : sa;
}

// ---------------------------------------------------------------------------
// Transpose fusion_feat [B,C,S(split)] f32 -> featT [B,S,C] f32
// ---------------------------------------------------------------------------
__global__ __launch_bounds__(256) void transpose_kernel(const float* __restrict__ feat,
                                                        const float* __restrict__ feat_db,
                                                        float* __restrict__ featT) {
    __shared__ float tile[64][65];
    int bid = blockIdx.x;
    int b = bid / (40 * 8);
    int rem = bid - b * (40 * 8);
    int st = rem >> 3, ct = rem & 7;
    int t = threadIdx.x, lane = t & 63, g = t >> 6;
    int s0 = st * 64, c0 = ct * 64;
    const float* src;
    int sl0, stride;
    if (s0 < Nc) { src = feat + (size_t)b * Cc * Nc; sl0 = s0; stride = Nc; }
    else         { src = feat_db + (size_t)b * Cc * Mc; sl0 = s0 - Nc; stride = Mc; }
#pragma unroll
    for (int i = 0; i < 16; i++) {
        int cl = g * 16 + i;
        tile[cl][lane] = src[(size_t)(c0 + cl) * stride + sl0 + lane];
    }
    __syncthreads();
#pragma unroll
    for (int i = 0; i < 16; i++) {
        int sl = g * 16 + i;
        featT[((size_t)b * Sc + s0 + sl) * Cc + c0 + lane] = tile[lane][sl];
    }
}

// ---------------------------------------------------------------------------
// Weight prep: fold attn BN into W1/bias1, cast attn W1/W2 + pos W2 to bf16
// ---------------------------------------------------------------------------
__global__ __launch_bounds__(256) void prep_kernel(const float* __restrict__ aw1, const float* __restrict__ ab1,
                                                   const float* __restrict__ ag, const float* __restrict__ abb,
                                                   const float* __restrict__ am, const float* __restrict__ av,
                                                   const float* __restrict__ aw2, const float* __restrict__ pw2,
                                                   u16* __restrict__ W1b, float* __restrict__ bias1,
                                                   u16* __restrict__ W2b, u16* __restrict__ PW2b) {
    int i = blockIdx.x * 256 + threadIdx.x;  // grid covers 524288
    if (i < AH * Cc) {
        int o = i >> 9;
        float inv = ag[o] / sqrtf(av[o] + EPS);
        W1b[i] = f2bf(aw1[i] * inv);
    }
    if (i < AH) {
        float inv = ag[i] / sqrtf(av[i] + EPS);
        bias1[i] = ab1[i] * inv + abb[i] - am[i] * inv;
    }
    if (i < Cc * AH) W2b[i] = f2bf(aw2[i]);
    if (i < Cc * PH) PW2b[i] = f2bf(pw2[i]);
}

// ---------------------------------------------------------------------------
// KNN (v1 + tree-scan): one wave per query; distances mirror the reference
// decomposition qq + ss - 2*dot, no fma contraction; ties -> smaller index.
// ---------------------------------------------------------------------------
__global__ __launch_bounds__(256) void knn_kernel(const float* __restrict__ pcd,
                                                  const float* __restrict__ pcd_db,
                                                  int* __restrict__ idxout) {
    int t = threadIdx.x, w = t >> 6, l = t & 63;
    int q = blockIdx.x * 4 + w;  // 0..4095
    int b = q >> 11, n = q & (Nc - 1);
    const float* pc = pcd + (size_t)b * 3 * Nc;
    const float* pd = pcd_db + (size_t)b * 3 * Mc;
    float qx = pc[n], qy = pc[Nc + n], qz = pc[2 * Nc + n];
    float qq = __fadd_rn(__fadd_rn(__fmul_rn(qx, qx), __fmul_rn(qy, qy)), __fmul_rn(qz, qz));
    float dist[40];
#pragma unroll
    for (int j = 0; j < 40; j++) {
        int s = j * 64 + l;
        float sx, sy, sz;
        if (s < Nc) { sx = pc[s]; sy = pc[Nc + s]; sz = pc[2 * Nc + s]; }
        else { int ss = s - Nc; sx = pd[ss]; sy = pd[Mc + ss]; sz = pd[2 * Mc + ss]; }
        float ss2 = __fadd_rn(__fadd_rn(__fmul_rn(sx, sx), __fmul_rn(sy, sy)), __fmul_rn(sz, sz));
        float dt  = __fadd_rn(__fadd_rn(__fmul_rn(qx, sx), __fmul_rn(qy, sy)), __fmul_rn(qz, sz));
        dist[j] = __fsub_rn(__fadd_rn(qq, ss2), __fmul_rn(2.0f, dt));
    }
    for (int r = 0; r < 16; r++) {
        // tree lex-min over the 40 (dist[j], j*64+l) pairs
        float td[20];
        int   ts[20];
#pragma unroll
        for (int i = 0; i < 20; i++) {
            float d0 = dist[2 * i], d1 = dist[2 * i + 1];
            int s0 = (2 * i) * 64 + l, s1 = (2 * i + 1) * 64 + l;
            bool bt = (d1 < d0) || (d1 == d0 && s1 < s0);
            td[i] = bt ? d1 : d0;
            ts[i] = bt ? s1 : s0;
        }
#pragma unroll
        for (int i = 0; i < 10; i++) lmin(td[i], ts[i], td[i + 10], ts[i + 10]);
#pragma unroll
        for (int i = 0; i < 5; i++) lmin(td[i], ts[i], td[i + 5], ts[i + 5]);
        lmin(td[0], ts[0], td[3], ts[3]);
        lmin(td[1], ts[1], td[4], ts[4]);
        lmin(td[0], ts[0], td[2], ts[2]);
        lmin(td[0], ts[0], td[1], ts[1]);
        float bd = td[0];
        int   bs = ts[0];
        for (int off = 32; off; off >>= 1) {
            float od = __shfl_xor(bd, off);
            int   os = __shfl_xor(bs, off);
            bool better = (od < bd) || (od == bd && os < bs);
            bd = better ? od : bd;
            bs = better ? os : bs;
        }
        if (l == 0) idxout[q * 16 + r] = bs;
        int wj = bs >> 6, wl = bs & 63;
        if (l == wl) {
#pragma unroll
            for (int j = 0; j < 40; j++)
                if (j == wj) dist[j] = 1e30f;
        }
    }
}

// ---------------------------------------------------------------------------
// HKER: per row, pos-MLP layer-1: h[r][64] = relu(BN(W1 (q - s) + b1)) bf16
// ---------------------------------------------------------------------------
__global__ __launch_bounds__(256) void hker(const float* __restrict__ pcd, const float* __restrict__ pcd_db,
                                            const int* __restrict__ idxb,
                                            const float* __restrict__ pw1, const float* __restrict__ pb1,
                                            const float* __restrict__ pg, const float* __restrict__ pbb,
                                            const float* __restrict__ pm, const float* __restrict__ pv,
                                            u16* __restrict__ H) {
    __shared__ float W1s[64][4];
    int t = threadIdx.x;
    if (t < 64) {
        float inv = pg[t] / sqrtf(pv[t] + EPS);
        W1s[t][0] = pw1[t * 3 + 0] * inv;
        W1s[t][1] = pw1[t * 3 + 1] * inv;
        W1s[t][2] = pw1[t * 3 + 2] * inv;
        W1s[t][3] = pb1[t] * inv + pbb[t] - pm[t] * inv;
    }
    __syncthreads();
    int r = blockIdx.x * 256 + t;
    int b = r >> 15, n = (r >> 4) & (Nc - 1), s = idxb[r];
    const float* pc = pcd + (size_t)b * 3 * Nc;
    float qx = pc[n], qy = pc[Nc + n], qz = pc[2 * Nc + n];
    float sx, sy, sz;
    if (s < Nc) { sx = pc[s]; sy = pc[Nc + s]; sz = pc[2 * Nc + s]; }
    else {
        const float* pd = pcd_db + (size_t)b * 3 * Mc;
        int ss = s - Nc;
        sx = pd[ss]; sy = pd[Mc + ss]; sz = pd[2 * Mc + ss];
    }
    float dx = qx - sx, dy = qy - sy, dz = qz - sz;
    u16* hp = H + (size_t)r * 64;
#pragma unroll
    for (int u0 = 0; u0 < 64; u0 += 8) {
        u16 e[8];
#pragma unroll
        for (int j = 0; j < 8; j++) {
            int u = u0 + j;
            float hv = fmaxf(0.f, dx * W1s[u][0] + dy * W1s[u][1] + dz * W1s[u][2] + W1s[u][3]);
            e[j] = f2bf(hv);
        }
        u32x4 pk;
        pk.x = (u32)e[0] | ((u32)e[1] << 16); pk.y = (u32)e[2] | ((u32)e[3] << 16);
        pk.z = (u32)e[4] | ((u32)e[5] << 16); pk.w = (u32)e[6] | ((u32)e[7] << 16);
        *(u32x4*)(hp + u0) = pk;
    }
}

// ---------------------------------------------------------------------------
// PGEMM_FUSED: P = H @ PW2^T + pb2 via MFMA (M=rows, N=512, K=64), epilogue
// gathers f,g from featT and emits X = f-g+p, V = g+p (bf16).
// ---------------------------------------------------------------------------
__global__ __launch_bounds__(256) void pgemm_fused(const u16* __restrict__ Hg, const u16* __restrict__ Bg,
                                                   const float* __restrict__ pb2,
                                                   const float* __restrict__ featT, const int* __restrict__ idxb,
                                                   u16* __restrict__ X, u16* __restrict__ V, int row0) {
    __shared__ u16 As[128 * 64];
    __shared__ u16 Bs[128 * 64];
    const int t = threadIdx.x;
    u32 bmu, bnu;
    xcd_tiles(bmu, bnu);
    const int bm = (int)bmu, bn = (int)bnu;
    const int w = t >> 6, l = t & 63;
    const int wr = w >> 1, wc = w & 1;
    const int fr = l & 15, fq = l >> 4;
    f32x4 acc[4][4];
#pragma unroll
    for (int i = 0; i < 4; i++)
#pragma unroll
        for (int j = 0; j < 4; j++) {
            f32x4 z = {0.f, 0.f, 0.f, 0.f};
            acc[i][j] = z;
        }
    const char* Abase = (const char*)Hg + ((size_t)row0 + (size_t)bm * 128) * 64 * 2;
    const char* Bbase = (const char*)Bg + (size_t)bn * 128 * 64 * 2;
#pragma unroll
    for (int i = 0; i < 4; i++) {
        int chunk = i * 256 + t;
        int row = chunk >> 3;
        int cb = (chunk & 7) * 16;
        gload_lds16(Abase + (size_t)row * 128 + cb, (char*)As + chunk * 16);
    }
#pragma unroll
    for (int i = 0; i < 4; i++) {
        int chunk = i * 256 + t;
        int row = chunk >> 3;
        int cb = (chunk & 7) * 16;
        gload_lds16(Bbase + (size_t)row * 128 + cb, (char*)Bs + chunk * 16);
    }
    __syncthreads();
    bf16x8 af[4][2], bfv[4][2];
#pragma unroll
    for (int mf = 0; mf < 4; mf++)
#pragma unroll
        for (int ks = 0; ks < 2; ks++)
            af[mf][ks] = *(const bf16x8*)&As[(wr * 64 + mf * 16 + fr) * 64 + ks * 32 + fq * 8];
#pragma unroll
    for (int nf = 0; nf < 4; nf++)
#pragma unroll
        for (int ks = 0; ks < 2; ks++)
            bfv[nf][ks] = *(const bf16x8*)&Bs[(wc * 64 + nf * 16 + fr) * 64 + ks * 32 + fq * 8];
#pragma unroll
    for (int mf = 0; mf < 4; mf++)
#pragma unroll
        for (int nf = 0; nf < 4; nf++)
#pragma unroll
            for (int ks = 0; ks < 2; ks++)
                acc[mf][nf] = __builtin_amdgcn_mfma_f32_16x16x32_bf16(af[mf][ks], bfv[nf][ks], acc[mf][nf], 0, 0, 0);
    // epilogue: per C-row gather f,g; emit X,V
#pragma unroll
    for (int mf = 0; mf < 4; mf++) {
#pragma unroll
        for (int r = 0; r < 4; r++) {
            int gr = bm * 128 + wr * 64 + mf * 16 + fq * 4 + r;  // chunk-local row
            int grow = row0 + gr;                                 // global row
            int b = grow >> 15;
            int n = (grow >> 4) & (Nc - 1);
            int s = idxb[grow];
            const float* frow = featT + ((size_t)b * Sc + n) * Cc;
            const float* grow_p = featT + ((size_t)b * Sc + s) * Cc;
#pragma unroll
            for (int nf = 0; nf < 4; nf++) {
                int gn = bn * 128 + wc * 64 + nf * 16 + fr;
                float p = acc[mf][nf][r] + pb2[gn];
                float fv = frow[gn];
                float gv = grow_p[gn];
                X[(size_t)gr * Cc + gn] = f2bf(fv - gv + p);
                V[(size_t)gr * Cc + gn] = f2bf(gv + p);
            }
        }
    }
}

// ---------------------------------------------------------------------------
// GEMM (m97 structure + XCD swizzle): C[m][n] = f(sum_k A[m][k]*B[n][k]+bias)
// A [M][Kd] bf16, B [N][Kd] bf16 (i.e. B^T layout), 128x128 tile, BK=64.
// ---------------------------------------------------------------------------
template <bool RELU, bool OBF16>
__global__ __launch_bounds__(256) void gemm_bt(const u16* __restrict__ Ag, const u16* __restrict__ Bg,
                                               const float* __restrict__ bias, void* __restrict__ Cg,
                                               int M, int N, int Kd) {
    __shared__ u16 As[128 * 64];
    __shared__ u16 Bs[128 * 64];
    const int t = threadIdx.x;
    u32 bmu, bnu;
    xcd_tiles(bmu, bnu);
    const int bm = (int)bmu, bn = (int)bnu;
    const int w = t >> 6, l = t & 63;
    const int wr = w >> 1, wc = w & 1;
    const int fr = l & 15, fq = l >> 4;
    f32x4 acc[4][4];
#pragma unroll
    for (int i = 0; i < 4; i++)
#pragma unroll
        for (int j = 0; j < 4; j++) {
            f32x4 z = {0.f, 0.f, 0.f, 0.f};
            acc[i][j] = z;
        }
    const char* Abase = (const char*)Ag + (size_t)bm * 128 * (size_t)Kd * 2;
    const char* Bbase = (const char*)Bg + (size_t)bn * 128 * (size_t)Kd * 2;
    const size_t ldb = (size_t)Kd * 2;

    for (int kt = 0; kt < Kd; kt += 64) {
#pragma unroll
        for (int i = 0; i < 4; i++) {
            int chunk = i * 256 + t;
            int row = chunk >> 3;
            int cb = (chunk & 7) * 16;
            gload_lds16(Abase + (size_t)row * ldb + (size_t)kt * 2 + cb, (char*)As + chunk * 16);
        }
#pragma unroll
        for (int i = 0; i < 4; i++) {
            int chunk = i * 256 + t;
            int row = chunk >> 3;
            int cb = (chunk & 7) * 16;
            gload_lds16(Bbase + (size_t)row * ldb + (size_t)kt * 2 + cb, (char*)Bs + chunk * 16);
        }
        __syncthreads();
        bf16x8 af[4][2], bfv[4][2];
#pragma unroll
        for (int mf = 0; mf < 4; mf++)
#pragma unroll
            for (int ks = 0; ks < 2; ks++)
                af[mf][ks] = *(const bf16x8*)&As[(wr * 64 + mf * 16 + fr) * 64 + ks * 32 + fq * 8];
#pragma unroll
        for (int nf = 0; nf < 4; nf++)
#pragma unroll
            for (int ks = 0; ks < 2; ks++)
                bfv[nf][ks] = *(const bf16x8*)&Bs[(wc * 64 + nf * 16 + fr) * 64 + ks * 32 + fq * 8];
#pragma unroll
        for (int mf = 0; mf < 4; mf++)
#pragma unroll
            for (int nf = 0; nf < 4; nf++)
#pragma unroll
                for (int ks = 0; ks < 2; ks++)
                    acc[mf][nf] = __builtin_amdgcn_mfma_f32_16x16x32_bf16(af[mf][ks], bfv[nf][ks], acc[mf][nf], 0, 0, 0);
        __syncthreads();
    }
#pragma unroll
    for (int mf = 0; mf < 4; mf++) {
#pragma unroll
        for (int nf = 0; nf < 4; nf++) {
            int gn = bn * 128 + wc * 64 + nf * 16 + fr;
            float bi = bias[gn];
            int gm0 = bm * 128 + wr * 64 + mf * 16 + fq * 4;
#pragma unroll
            for (int r = 0; r < 4; r++) {
                float v = acc[mf][nf][r] + bi;
                if (RELU) v = fmaxf(v, 0.f);
                size_t o = (size_t)(gm0 + r) * N + gn;
                if (OBF16) ((u16*)Cg)[o] = f2bf(v);
                else ((float*)Cg)[o] = v;
            }
        }
    }
}

// ---------------------------------------------------------------------------
// GEMM2_FUSED: logits L = A @ W2^T + ab2 (M=rows, N=512, K=1024) with the
// softmax-over-k + weighted-V reduction fused into the epilogue.
// V tile (128 rows x 128 ch = 32 KB) is LDS-staged (coalesced) after the
// K-loop, reusing the As/Bs space.
// ---------------------------------------------------------------------------
__global__ __launch_bounds__(256) void gemm2_fused(const u16* __restrict__ Ag, const u16* __restrict__ Bg,
                                                   const float* __restrict__ bias, const u16* __restrict__ Vb,
                                                   float* __restrict__ out, int row0, int Kd) {
    __shared__ u16 smem[128 * 128];  // As (16KB) + Bs (16KB); reused as V tile
    u16* As = smem;
    u16* Bs = smem + 128 * 64;
    const int t = threadIdx.x;
    u32 bmu, bnu;
    xcd_tiles(bmu, bnu);
    const int bm = (int)bmu, bn = (int)bnu;
    const int w = t >> 6, l = t & 63;
    const int wr = w >> 1, wc = w & 1;
    const int fr = l & 15, fq = l >> 4;
    f32x4 acc[4][4];
#pragma unroll
    for (int i = 0; i < 4; i++)
#pragma unroll
        for (int j = 0; j < 4; j++) {
            f32x4 z = {0.f, 0.f, 0.f, 0.f};
            acc[i][j] = z;
        }
    const char* Abase = (const char*)Ag + (size_t)bm * 128 * (size_t)Kd * 2;
    const char* Bbase = (const char*)Bg + (size_t)bn * 128 * (size_t)Kd * 2;
    const size_t ldb = (size_t)Kd * 2;

    for (int kt = 0; kt < Kd; kt += 64) {
#pragma unroll
        for (int i = 0; i < 4; i++) {
            int chunk = i * 256 + t;
            int row = chunk >> 3;
            int cb = (chunk & 7) * 16;
            gload_lds16(Abase + (size_t)row * ldb + (size_t)kt * 2 + cb, (char*)As + chunk * 16);
        }
#pragma unroll
        for (int i = 0; i < 4; i++) {
            int chunk = i * 256 + t;
            int row = chunk >> 3;
            int cb = (chunk & 7) * 16;
            gload_lds16(Bbase + (size_t)row * ldb + (size_t)kt * 2 + cb, (char*)Bs + chunk * 16);
        }
        __syncthreads();
        bf16x8 af[4][2], bfv[4][2];
#pragma unroll
        for (int mf = 0; mf < 4; mf++)
#pragma unroll
            for (int ks = 0; ks < 2; ks++)
                af[mf][ks] = *(const bf16x8*)&As[(wr * 64 + mf * 16 + fr) * 64 + ks * 32 + fq * 8];
#pragma unroll
        for (int nf = 0; nf < 4; nf++)
#pragma unroll
            for (int ks = 0; ks < 2; ks++)
                bfv[nf][ks] = *(const bf16x8*)&Bs[(wc * 64 + nf * 16 + fr) * 64 + ks * 32 + fq * 8];
#pragma unroll
        for (int mf = 0; mf < 4; mf++)
#pragma unroll
            for (int nf = 0; nf < 4; nf++)
#pragma unroll
                for (int ks = 0; ks < 2; ks++)
                    acc[mf][nf] = __builtin_amdgcn_mfma_f32_16x16x32_bf16(af[mf][ks], bfv[nf][ks], acc[mf][nf], 0, 0, 0);
        __syncthreads();
    }
    // stage V tile [bm*128 .. +128)[bn*128 .. +128) into LDS (coalesced)
    const char* Vbase = (const char*)Vb + (size_t)bm * 128 * Cc * 2 + (size_t)bn * 256;
#pragma unroll
    for (int i = 0; i < 8; i++) {
        int chunk = i * 256 + t;       // 0..2047
        int row = chunk >> 4;          // 0..127
        int cb = (chunk & 15) * 16;    // byte offset in row (256B rows)
        gload_lds16(Vbase + (size_t)row * (Cc * 2) + cb, (char*)smem + chunk * 16);
    }
    __syncthreads();
    // fused epilogue: per (point, channel) softmax over k=fq*4+r + V-reduce
#pragma unroll
    for (int mf = 0; mf < 4; mf++) {
        int lp = bm * 8 + wr * 4 + mf;        // chunk-local point
        int gp = row0 / 16 + lp;              // global point
        int bb = gp >> 11, nn = gp & (Nc - 1);
        int vrow = (wr * 4 + mf) * 16 + fq * 4;  // tile-local V row for r=0
#pragma unroll
        for (int nf = 0; nf < 4; nf++) {
            int gn = bn * 128 + wc * 64 + nf * 16 + fr;
            int vch = wc * 64 + nf * 16 + fr;
            float bi = bias[gn];
            float v0 = acc[mf][nf][0] + bi, v1 = acc[mf][nf][1] + bi;
            float v2 = acc[mf][nf][2] + bi, v3 = acc[mf][nf][3] + bi;
            float mx = fmaxf(fmaxf(v0, v1), fmaxf(v2, v3));
            mx = fmaxf(mx, __shfl_xor(mx, 16));
            mx = fmaxf(mx, __shfl_xor(mx, 32));
            float e0 = __expf(v0 - mx), e1 = __expf(v1 - mx);
            float e2 = __expf(v2 - mx), e3 = __expf(v3 - mx);
            float ws = e0 * bf2f(smem[(size_t)vrow * 128 + vch])
                     + e1 * bf2f(smem[(size_t)(vrow + 1) * 128 + vch])
                     + e2 * bf2f(smem[(size_t)(vrow + 2) * 128 + vch])
                     + e3 * bf2f(smem[(size_t)(vrow + 3) * 128 + vch]);
            float es = e0 + e1 + e2 + e3;
            ws += __shfl_xor(ws, 16); ws += __shfl_xor(ws, 32);
            es += __shfl_xor(es, 16); es += __shfl_xor(es, 32);
            if (fq == 0) out[((size_t)bb * Cc + gn) * Nc + nn] = ws / es;
        }
    }
}

// ---------------------------------------------------------------------------
extern "C" void kernel_launch(void* const* d_in, const int* in_sizes, int n_in,
                              void* d_out, int out_size, void* d_ws, size_t ws_size,
                              hipStream_t stream) {
    (void)in_sizes; (void)n_in; (void)out_size;
    const float* pcd     = (const float*)d_in[0];
    const float* feat    = (const float*)d_in[1];
    const float* pcd_db  = (const float*)d_in[2];
    const float* feat_db = (const float*)d_in[3];
    const float* pw1 = (const float*)d_in[4];
    const float* pb1 = (const float*)d_in[5];
    const float* pg  = (const float*)d_in[6];
    const float* pbb = (const float*)d_in[7];
    const float* pm  = (const float*)d_in[8];
    const float* pv  = (const float*)d_in[9];
    const float* pw2 = (const float*)d_in[10];
    const float* pb2 = (const float*)d_in[11];
    const float* aw1 = (const float*)d_in[12];
    const float* ab1 = (const float*)d_in[13];
    const float* ag  = (const float*)d_in[14];
    const float* abb = (const float*)d_in[15];
    const float* am  = (const float*)d_in[16];
    const float* av  = (const float*)d_in[17];
    const float* aw2 = (const float*)d_in[18];
    const float* ab2 = (const float*)d_in[19];
    float* out = (float*)d_out;

    char* base = (char*)d_ws;
    size_t off = 0;
    auto alloc = [&](size_t bytes) -> char* {
        char* r = base + off;
        off = (off + bytes + 255) & ~(size_t)255;
        return r;
    };
    int*   idxb  = (int*)alloc((size_t)RT * 4);
    float* featT = (float*)alloc((size_t)Bc * Sc * Cc * 4);
    u16*   W1b   = (u16*)alloc((size_t)AH * Cc * 2);
    float* bias1 = (float*)alloc((size_t)AH * 4);
    u16*   W2b   = (u16*)alloc((size_t)Cc * AH * 2);
    u16*   PW2b  = (u16*)alloc((size_t)Cc * PH * 2);
    u16*   Hb    = (u16*)alloc((size_t)RT * PH * 2);

    // chunked row pipeline: cr=32768 is the measured optimum (r14: 338 us;
    // cr=16K and cr=RT both slower; BM=64 gemm2 also slower).
    const size_t perrow = 1024 + 1024 + 2048;  // X,V bf16 + A bf16
    int cr = 32768;
    size_t avail = ws_size > off ? ws_size - off : 0;
    if (avail < (size_t)cr * perrow) {
        cr = (int)((avail / perrow) & ~(size_t)127);
        if (cr < 128) cr = 128;
    }
    u16*   Xb = (u16*)alloc((size_t)cr * Cc * 2);
    u16*   Vb = (u16*)alloc((size_t)cr * Cc * 2);
    u16*   Ab = (u16*)alloc((size_t)cr * AH * 2);

    transpose_kernel<<<dim3(Bc * 40 * 8), dim3(256), 0, stream>>>(feat, feat_db, featT);
    prep_kernel<<<dim3((AH * Cc) / 256), dim3(256), 0, stream>>>(aw1, ab1, ag, abb, am, av, aw2, pw2,
                                                                 W1b, bias1, W2b, PW2b);
    knn_kernel<<<dim3(Bc * Nc / 4), dim3(256), 0, stream>>>(pcd, pcd_db, idxb);
    hker<<<dim3(RT / 256), dim3(256), 0, stream>>>(pcd, pcd_db, idxb, pw1, pb1, pg, pbb, pm, pv, Hb);

    for (int r0 = 0; r0 < RT; r0 += cr) {
        int rows = (RT - r0 < cr) ? (RT - r0) : cr;
        pgemm_fused<<<dim3(rows / 128, Cc / 128), dim3(256), 0, stream>>>(Hb, PW2b, pb2, featT, idxb,
                                                                          Xb, Vb, r0);
        gemm_bt<true, true><<<dim3(rows / 128, AH / 128), dim3(256), 0, stream>>>(Xb, W1b, bias1, Ab, rows, AH, Cc);
        gemm2_fused<<<dim3(rows / 128, Cc / 128), dim3(256), 0, stream>>>(Ab, W2b, ab2, Vb, out, r0, AH);
    }
}

// Round 18
// 318.940 us; speedup vs baseline: 1.1998x; 1.0606x over previous
//
#include <hip/hip_runtime.h>

typedef unsigned short u16;
typedef unsigned int   u32;
typedef __attribute__((ext_vector_type(8))) short bf16x8;
typedef __attribute__((ext_vector_type(4))) float f32x4;
typedef __attribute__((ext_vector_type(4))) u32   u32x4;

// Problem constants
constexpr int Bc = 2, Cc = 512, Nc = 2048, Mc = 512, Sc = 2560, Kc = 16, PH = 64, AH = 1024;
constexpr int RT = Bc * Nc * Kc;  // 65536 rows (b,n,k)
constexpr float EPS = 1e-5f;

__device__ __forceinline__ u16 f2bf(float f) {
    u32 u = __float_as_uint(f);
    u32 r = (u + 0x7fffu + ((u >> 16) & 1u)) >> 16;  // RNE
    return (u16)r;
}
__device__ __forceinline__ float bf2f(u16 h) { return __uint_as_float(((u32)h) << 16); }

__device__ __forceinline__ void gload_lds16(const void* g, void* l) {
    __builtin_amdgcn_global_load_lds((const __attribute__((address_space(1))) u32*)g,
                                     (__attribute__((address_space(3))) u32*)l, 16, 0, 0);
}

// Bijective XCD-aware workgroup swizzle (m204 form): same-XCD wgs get a
// contiguous run of linear ids. With bn-fastest linearization this makes an
// XCD reuse one A-panel across all bn tiles (L2 locality).
__device__ __forceinline__ void xcd_tiles(u32& bm, u32& bn) {
    u32 gdx = gridDim.x, gdy = gridDim.y;
    u32 nwg = gdx * gdy;
    u32 wg = blockIdx.x + gdx * blockIdx.y;
    u32 q = nwg >> 3, r8 = nwg & 7;
    u32 xcd = wg & 7, loc = wg >> 3;
    u32 swz = (xcd < r8 ? xcd * (q + 1) : r8 * (q + 1) + (xcd - r8) * q) + loc;
    bn = swz % gdy;   // bn fastest within an XCD's contiguous run
    bm = swz / gdy;
}

// lex-min on (d, s): total order, associative -> tree order == scan order
__device__ __forceinline__ void lmin(float& da, int& sa, float db, int sb) {
    bool better = (db < da) || (db == da && sb < sa);
    da = better ? db : da;
    sa = better ? sb : sa;
}

// ---------------------------------------------------------------------------
// Transpose fusion_feat [B,C,S(split)] f32 -> featT [B,S,C] f32
// ---------------------------------------------------------------------------
__global__ __launch_bounds__(256) void transpose_kernel(const float* __restrict__ feat,
                                                        const float* __restrict__ feat_db,
                                                        float* __restrict__ featT) {
    __shared__ float tile[64][65];
    int bid = blockIdx.x;
    int b = bid / (40 * 8);
    int rem = bid - b * (40 * 8);
    int st = rem >> 3, ct = rem & 7;
    int t = threadIdx.x, lane = t & 63, g = t >> 6;
    int s0 = st * 64, c0 = ct * 64;
    const float* src;
    int sl0, stride;
    if (s0 < Nc) { src = feat + (size_t)b * Cc * Nc; sl0 = s0; stride = Nc; }
    else         { src = feat_db + (size_t)b * Cc * Mc; sl0 = s0 - Nc; stride = Mc; }
#pragma unroll
    for (int i = 0; i < 16; i++) {
        int cl = g * 16 + i;
        tile[cl][lane] = src[(size_t)(c0 + cl) * stride + sl0 + lane];
    }
    __syncthreads();
#pragma unroll
    for (int i = 0; i < 16; i++) {
        int sl = g * 16 + i;
        featT[((size_t)b * Sc + s0 + sl) * Cc + c0 + lane] = tile[lane][sl];
    }
}

// ---------------------------------------------------------------------------
// Weight prep: fold attn BN into W1/bias1, cast attn W1/W2 + pos W2 to bf16
// ---------------------------------------------------------------------------
__global__ __launch_bounds__(256) void prep_kernel(const float* __restrict__ aw1, const float* __restrict__ ab1,
                                                   const float* __restrict__ ag, const float* __restrict__ abb,
                                                   const float* __restrict__ am, const float* __restrict__ av,
                                                   const float* __restrict__ aw2, const float* __restrict__ pw2,
                                                   u16* __restrict__ W1b, float* __restrict__ bias1,
                                                   u16* __restrict__ W2b, u16* __restrict__ PW2b) {
    int i = blockIdx.x * 256 + threadIdx.x;  // grid covers 524288
    if (i < AH * Cc) {
        int o = i >> 9;
        float inv = ag[o] / sqrtf(av[o] + EPS);
        W1b[i] = f2bf(aw1[i] * inv);
    }
    if (i < AH) {
        float inv = ag[i] / sqrtf(av[i] + EPS);
        bias1[i] = ab1[i] * inv + abb[i] - am[i] * inv;
    }
    if (i < Cc * AH) W2b[i] = f2bf(aw2[i]);
    if (i < Cc * PH) PW2b[i] = f2bf(pw2[i]);
}

// ---------------------------------------------------------------------------
// KNN (v1 + tree-scan): one wave per query; distances mirror the reference
// decomposition qq + ss - 2*dot, no fma contraction; ties -> smaller index.
// ---------------------------------------------------------------------------
__global__ __launch_bounds__(256) void knn_kernel(const float* __restrict__ pcd,
                                                  const float* __restrict__ pcd_db,
                                                  int* __restrict__ idxout) {
    int t = threadIdx.x, w = t >> 6, l = t & 63;
    int q = blockIdx.x * 4 + w;  // 0..4095
    int b = q >> 11, n = q & (Nc - 1);
    const float* pc = pcd + (size_t)b * 3 * Nc;
    const float* pd = pcd_db + (size_t)b * 3 * Mc;
    float qx = pc[n], qy = pc[Nc + n], qz = pc[2 * Nc + n];
    float qq = __fadd_rn(__fadd_rn(__fmul_rn(qx, qx), __fmul_rn(qy, qy)), __fmul_rn(qz, qz));
    float dist[40];
#pragma unroll
    for (int j = 0; j < 40; j++) {
        int s = j * 64 + l;
        float sx, sy, sz;
        if (s < Nc) { sx = pc[s]; sy = pc[Nc + s]; sz = pc[2 * Nc + s]; }
        else { int ss = s - Nc; sx = pd[ss]; sy = pd[Mc + ss]; sz = pd[2 * Mc + ss]; }
        float ss2 = __fadd_rn(__fadd_rn(__fmul_rn(sx, sx), __fmul_rn(sy, sy)), __fmul_rn(sz, sz));
        float dt  = __fadd_rn(__fadd_rn(__fmul_rn(qx, sx), __fmul_rn(qy, sy)), __fmul_rn(qz, sz));
        dist[j] = __fsub_rn(__fadd_rn(qq, ss2), __fmul_rn(2.0f, dt));
    }
    for (int r = 0; r < 16; r++) {
        // tree lex-min over the 40 (dist[j], j*64+l) pairs
        float td[20];
        int   ts[20];
#pragma unroll
        for (int i = 0; i < 20; i++) {
            float d0 = dist[2 * i], d1 = dist[2 * i + 1];
            int s0 = (2 * i) * 64 + l, s1 = (2 * i + 1) * 64 + l;
            bool bt = (d1 < d0) || (d1 == d0 && s1 < s0);
            td[i] = bt ? d1 : d0;
            ts[i] = bt ? s1 : s0;
        }
#pragma unroll
        for (int i = 0; i < 10; i++) lmin(td[i], ts[i], td[i + 10], ts[i + 10]);
#pragma unroll
        for (int i = 0; i < 5; i++) lmin(td[i], ts[i], td[i + 5], ts[i + 5]);
        lmin(td[0], ts[0], td[3], ts[3]);
        lmin(td[1], ts[1], td[4], ts[4]);
        lmin(td[0], ts[0], td[2], ts[2]);
        lmin(td[0], ts[0], td[1], ts[1]);
        float bd = td[0];
        int   bs = ts[0];
        for (int off = 32; off; off >>= 1) {
            float od = __shfl_xor(bd, off);
            int   os = __shfl_xor(bs, off);
            bool better = (od < bd) || (od == bd && os < bs);
            bd = better ? od : bd;
            bs = better ? os : bs;
        }
        if (l == 0) idxout[q * 16 + r] = bs;
        int wj = bs >> 6, wl = bs & 63;
        if (l == wl) {
#pragma unroll
            for (int j = 0; j < 40; j++)
                if (j == wj) dist[j] = 1e30f;
        }
    }
}

// ---------------------------------------------------------------------------
// HKER: per row, pos-MLP layer-1: h[r][64] = relu(BN(W1 (q - s) + b1)) bf16
// ---------------------------------------------------------------------------
__global__ __launch_bounds__(256) void hker(const float* __restrict__ pcd, const float* __restrict__ pcd_db,
                                            const int* __restrict__ idxb,
                                            const float* __restrict__ pw1, const float* __restrict__ pb1,
                                            const float* __restrict__ pg, const float* __restrict__ pbb,
                                            const float* __restrict__ pm, const float* __restrict__ pv,
                                            u16* __restrict__ H) {
    __shared__ float W1s[64][4];
    int t = threadIdx.x;
    if (t < 64) {
        float inv = pg[t] / sqrtf(pv[t] + EPS);
        W1s[t][0] = pw1[t * 3 + 0] * inv;
        W1s[t][1] = pw1[t * 3 + 1] * inv;
        W1s[t][2] = pw1[t * 3 + 2] * inv;
        W1s[t][3] = pb1[t] * inv + pbb[t] - pm[t] * inv;
    }
    __syncthreads();
    int r = blockIdx.x * 256 + t;
    int b = r >> 15, n = (r >> 4) & (Nc - 1), s = idxb[r];
    const float* pc = pcd + (size_t)b * 3 * Nc;
    float qx = pc[n], qy = pc[Nc + n], qz = pc[2 * Nc + n];
    float sx, sy, sz;
    if (s < Nc) { sx = pc[s]; sy = pc[Nc + s]; sz = pc[2 * Nc + s]; }
    else {
        const float* pd = pcd_db + (size_t)b * 3 * Mc;
        int ss = s - Nc;
        sx = pd[ss]; sy = pd[Mc + ss]; sz = pd[2 * Mc + ss];
    }
    float dx = qx - sx, dy = qy - sy, dz = qz - sz;
    u16* hp = H + (size_t)r * 64;
#pragma unroll
    for (int u0 = 0; u0 < 64; u0 += 8) {
        u16 e[8];
#pragma unroll
        for (int j = 0; j < 8; j++) {
            int u = u0 + j;
            float hv = fmaxf(0.f, dx * W1s[u][0] + dy * W1s[u][1] + dz * W1s[u][2] + W1s[u][3]);
            e[j] = f2bf(hv);
        }
        u32x4 pk;
        pk.x = (u32)e[0] | ((u32)e[1] << 16); pk.y = (u32)e[2] | ((u32)e[3] << 16);
        pk.z = (u32)e[4] | ((u32)e[5] << 16); pk.w = (u32)e[6] | ((u32)e[7] << 16);
        *(u32x4*)(hp + u0) = pk;
    }
}

// ---------------------------------------------------------------------------
// PGEMM_FUSED: P = H @ PW2^T + pb2 via MFMA (M=rows, N=512, K=64), epilogue
// gathers f,g from featT and emits X = f-g+p, V = g+p (bf16).
// ---------------------------------------------------------------------------
__global__ __launch_bounds__(256) void pgemm_fused(const u16* __restrict__ Hg, const u16* __restrict__ Bg,
                                                   const float* __restrict__ pb2,
                                                   const float* __restrict__ featT, const int* __restrict__ idxb,
                                                   u16* __restrict__ X, u16* __restrict__ V, int row0) {
    __shared__ u16 As[128 * 64];
    __shared__ u16 Bs[128 * 64];
    const int t = threadIdx.x;
    u32 bmu, bnu;
    xcd_tiles(bmu, bnu);
    const int bm = (int)bmu, bn = (int)bnu;
    const int w = t >> 6, l = t & 63;
    const int wr = w >> 1, wc = w & 1;
    const int fr = l & 15, fq = l >> 4;
    f32x4 acc[4][4];
#pragma unroll
    for (int i = 0; i < 4; i++)
#pragma unroll
        for (int j = 0; j < 4; j++) {
            f32x4 z = {0.f, 0.f, 0.f, 0.f};
            acc[i][j] = z;
        }
    const char* Abase = (const char*)Hg + ((size_t)row0 + (size_t)bm * 128) * 64 * 2;
    const char* Bbase = (const char*)Bg + (size_t)bn * 128 * 64 * 2;
#pragma unroll
    for (int i = 0; i < 4; i++) {
        int chunk = i * 256 + t;
        int row = chunk >> 3;
        int cb = (chunk & 7) * 16;
        gload_lds16(Abase + (size_t)row * 128 + cb, (char*)As + chunk * 16);
    }
#pragma unroll
    for (int i = 0; i < 4; i++) {
        int chunk = i * 256 + t;
        int row = chunk >> 3;
        int cb = (chunk & 7) * 16;
        gload_lds16(Bbase + (size_t)row * 128 + cb, (char*)Bs + chunk * 16);
    }
    __syncthreads();
    bf16x8 af[4][2], bfv[4][2];
#pragma unroll
    for (int mf = 0; mf < 4; mf++)
#pragma unroll
        for (int ks = 0; ks < 2; ks++)
            af[mf][ks] = *(const bf16x8*)&As[(wr * 64 + mf * 16 + fr) * 64 + ks * 32 + fq * 8];
#pragma unroll
    for (int nf = 0; nf < 4; nf++)
#pragma unroll
        for (int ks = 0; ks < 2; ks++)
            bfv[nf][ks] = *(const bf16x8*)&Bs[(wc * 64 + nf * 16 + fr) * 64 + ks * 32 + fq * 8];
#pragma unroll
    for (int mf = 0; mf < 4; mf++)
#pragma unroll
        for (int nf = 0; nf < 4; nf++)
#pragma unroll
            for (int ks = 0; ks < 2; ks++)
                acc[mf][nf] = __builtin_amdgcn_mfma_f32_16x16x32_bf16(af[mf][ks], bfv[nf][ks], acc[mf][nf], 0, 0, 0);
    // epilogue: per C-row gather f,g; emit X,V
#pragma unroll
    for (int mf = 0; mf < 4; mf++) {
#pragma unroll
        for (int r = 0; r < 4; r++) {
            int gr = bm * 128 + wr * 64 + mf * 16 + fq * 4 + r;  // chunk-local row
            int grow = row0 + gr;                                 // global row
            int b = grow >> 15;
            int n = (grow >> 4) & (Nc - 1);
            int s = idxb[grow];
            const float* frow = featT + ((size_t)b * Sc + n) * Cc;
            const float* grow_p = featT + ((size_t)b * Sc + s) * Cc;
#pragma unroll
            for (int nf = 0; nf < 4; nf++) {
                int gn = bn * 128 + wc * 64 + nf * 16 + fr;
                float p = acc[mf][nf][r] + pb2[gn];
                float fv = frow[gn];
                float gv = grow_p[gn];
                X[(size_t)gr * Cc + gn] = f2bf(fv - gv + p);
                V[(size_t)gr * Cc + gn] = f2bf(gv + p);
            }
        }
    }
}

// ---------------------------------------------------------------------------
// GEMM (m97 structure + XCD swizzle): C[m][n] = f(sum_k A[m][k]*B[n][k]+bias)
// A [M][Kd] bf16, B [N][Kd] bf16 (i.e. B^T layout), 128x128 tile, BK=64.
// ---------------------------------------------------------------------------
template <bool RELU, bool OBF16>
__global__ __launch_bounds__(256) void gemm_bt(const u16* __restrict__ Ag, const u16* __restrict__ Bg,
                                               const float* __restrict__ bias, void* __restrict__ Cg,
                                               int M, int N, int Kd) {
    __shared__ u16 As[128 * 64];
    __shared__ u16 Bs[128 * 64];
    const int t = threadIdx.x;
    u32 bmu, bnu;
    xcd_tiles(bmu, bnu);
    const int bm = (int)bmu, bn = (int)bnu;
    const int w = t >> 6, l = t & 63;
    const int wr = w >> 1, wc = w & 1;
    const int fr = l & 15, fq = l >> 4;
    f32x4 acc[4][4];
#pragma unroll
    for (int i = 0; i < 4; i++)
#pragma unroll
        for (int j = 0; j < 4; j++) {
            f32x4 z = {0.f, 0.f, 0.f, 0.f};
            acc[i][j] = z;
        }
    const char* Abase = (const char*)Ag + (size_t)bm * 128 * (size_t)Kd * 2;
    const char* Bbase = (const char*)Bg + (size_t)bn * 128 * (size_t)Kd * 2;
    const size_t ldb = (size_t)Kd * 2;

    for (int kt = 0; kt < Kd; kt += 64) {
#pragma unroll
        for (int i = 0; i < 4; i++) {
            int chunk = i * 256 + t;
            int row = chunk >> 3;
            int cb = (chunk & 7) * 16;
            gload_lds16(Abase + (size_t)row * ldb + (size_t)kt * 2 + cb, (char*)As + chunk * 16);
        }
#pragma unroll
        for (int i = 0; i < 4; i++) {
            int chunk = i * 256 + t;
            int row = chunk >> 3;
            int cb = (chunk & 7) * 16;
            gload_lds16(Bbase + (size_t)row * ldb + (size_t)kt * 2 + cb, (char*)Bs + chunk * 16);
        }
        __syncthreads();
        bf16x8 af[4][2], bfv[4][2];
#pragma unroll
        for (int mf = 0; mf < 4; mf++)
#pragma unroll
            for (int ks = 0; ks < 2; ks++)
                af[mf][ks] = *(const bf16x8*)&As[(wr * 64 + mf * 16 + fr) * 64 + ks * 32 + fq * 8];
#pragma unroll
        for (int nf = 0; nf < 4; nf++)
#pragma unroll
            for (int ks = 0; ks < 2; ks++)
                bfv[nf][ks] = *(const bf16x8*)&Bs[(wc * 64 + nf * 16 + fr) * 64 + ks * 32 + fq * 8];
#pragma unroll
        for (int mf = 0; mf < 4; mf++)
#pragma unroll
            for (int nf = 0; nf < 4; nf++)
#pragma unroll
                for (int ks = 0; ks < 2; ks++)
                    acc[mf][nf] = __builtin_amdgcn_mfma_f32_16x16x32_bf16(af[mf][ks], bfv[nf][ks], acc[mf][nf], 0, 0, 0);
        __syncthreads();
    }
#pragma unroll
    for (int mf = 0; mf < 4; mf++) {
#pragma unroll
        for (int nf = 0; nf < 4; nf++) {
            int gn = bn * 128 + wc * 64 + nf * 16 + fr;
            float bi = bias[gn];
            int gm0 = bm * 128 + wr * 64 + mf * 16 + fq * 4;
#pragma unroll
            for (int r = 0; r < 4; r++) {
                float v = acc[mf][nf][r] + bi;
                if (RELU) v = fmaxf(v, 0.f);
                size_t o = (size_t)(gm0 + r) * N + gn;
                if (OBF16) ((u16*)Cg)[o] = f2bf(v);
                else ((float*)Cg)[o] = v;
            }
        }
    }
}

// ---------------------------------------------------------------------------
// GEMM2_FUSED (double-buffered, T3-minimum): logits L = A @ W2^T + ab2
// (M=rows, N=512, K=1024) with softmax-over-k + weighted-V reduce fused.
// K-loop prefetches tile t+1's global_load_lds into buf^1 right after the
// barrier (loads in flight during ds_read+MFMA of tile t) instead of the
// m97 issue-then-drain pattern. LDS 64 KB (2 x As/Bs); V tile reuses buf0.
// Same K-summation order -> bit-identical results.
// ---------------------------------------------------------------------------
__global__ __launch_bounds__(256) void gemm2_fused(const u16* __restrict__ Ag, const u16* __restrict__ Bg,
                                                   const float* __restrict__ bias, const u16* __restrict__ Vb,
                                                   float* __restrict__ out, int row0, int Kd) {
    __shared__ u16 smem[32768];  // 64 KB: buf0 {As 16K|Bs 16K} buf1 {As|Bs}; V tile (32 KB) reuses buf0
    const int t = threadIdx.x;
    u32 bmu, bnu;
    xcd_tiles(bmu, bnu);
    const int bm = (int)bmu, bn = (int)bnu;
    const int w = t >> 6, l = t & 63;
    const int wr = w >> 1, wc = w & 1;
    const int fr = l & 15, fq = l >> 4;
    f32x4 acc[4][4];
#pragma unroll
    for (int i = 0; i < 4; i++)
#pragma unroll
        for (int j = 0; j < 4; j++) {
            f32x4 z = {0.f, 0.f, 0.f, 0.f};
            acc[i][j] = z;
        }
    const char* Abase = (const char*)Ag + (size_t)bm * 128 * (size_t)Kd * 2;
    const char* Bbase = (const char*)Bg + (size_t)bn * 128 * (size_t)Kd * 2;
    const size_t ldb = (size_t)Kd * 2;

    auto stage = [&](int buf, int kt) {
        char* Ad = (char*)smem + (size_t)buf * 32768;
        char* Bd = Ad + 16384;
#pragma unroll
        for (int i = 0; i < 4; i++) {
            int chunk = i * 256 + t;
            int row = chunk >> 3;
            int cb = (chunk & 7) * 16;
            gload_lds16(Abase + (size_t)row * ldb + (size_t)kt * 2 + cb, Ad + chunk * 16);
        }
#pragma unroll
        for (int i = 0; i < 4; i++) {
            int chunk = i * 256 + t;
            int row = chunk >> 3;
            int cb = (chunk & 7) * 16;
            gload_lds16(Bbase + (size_t)row * ldb + (size_t)kt * 2 + cb, Bd + chunk * 16);
        }
    };

    const int nt = Kd / 64;   // 16
    stage(0, 0);
    int cur = 0;
    for (int it = 0; it < nt; ++it) {
        __syncthreads();                      // drains stage(cur); prior reads of cur^1 done
        if (it + 1 < nt) stage(cur ^ 1, (it + 1) * 64);  // prefetch overlaps this tile's compute
        const u16* As = smem + (size_t)cur * 16384;
        const u16* Bs = As + 8192;
        bf16x8 af[4][2], bfv[4][2];
#pragma unroll
        for (int mf = 0; mf < 4; mf++)
#pragma unroll
            for (int ks = 0; ks < 2; ks++)
                af[mf][ks] = *(const bf16x8*)&As[(wr * 64 + mf * 16 + fr) * 64 + ks * 32 + fq * 8];
#pragma unroll
        for (int nf = 0; nf < 4; nf++)
#pragma unroll
            for (int ks = 0; ks < 2; ks++)
                bfv[nf][ks] = *(const bf16x8*)&Bs[(wc * 64 + nf * 16 + fr) * 64 + ks * 32 + fq * 8];
#pragma unroll
        for (int mf = 0; mf < 4; mf++)
#pragma unroll
            for (int nf = 0; nf < 4; nf++)
#pragma unroll
                for (int ks = 0; ks < 2; ks++)
                    acc[mf][nf] = __builtin_amdgcn_mfma_f32_16x16x32_bf16(af[mf][ks], bfv[nf][ks], acc[mf][nf], 0, 0, 0);
        cur ^= 1;
    }
    // stage V tile [bm*128 .. +128)[bn*128 .. +128) into buf0 (coalesced).
    // Safe: writes buf0 while any straggler reads buf1 (nt even -> last tile
    // was buf1); barrier below drains V loads before epilogue reads.
    const char* Vbase = (const char*)Vb + (size_t)bm * 128 * Cc * 2 + (size_t)bn * 256;
#pragma unroll
    for (int i = 0; i < 8; i++) {
        int chunk = i * 256 + t;       // 0..2047
        int row = chunk >> 4;          // 0..127
        int cb = (chunk & 15) * 16;    // byte offset in row (256B rows)
        gload_lds16(Vbase + (size_t)row * (Cc * 2) + cb, (char*)smem + chunk * 16);
    }
    __syncthreads();
    // fused epilogue: per (point, channel) softmax over k=fq*4+r + V-reduce
#pragma unroll
    for (int mf = 0; mf < 4; mf++) {
        int lp = bm * 8 + wr * 4 + mf;        // chunk-local point
        int gp = row0 / 16 + lp;              // global point
        int bb = gp >> 11, nn = gp & (Nc - 1);
        int vrow = (wr * 4 + mf) * 16 + fq * 4;  // tile-local V row for r=0
#pragma unroll
        for (int nf = 0; nf < 4; nf++) {
            int gn = bn * 128 + wc * 64 + nf * 16 + fr;
            int vch = wc * 64 + nf * 16 + fr;
            float bi = bias[gn];
            float v0 = acc[mf][nf][0] + bi, v1 = acc[mf][nf][1] + bi;
            float v2 = acc[mf][nf][2] + bi, v3 = acc[mf][nf][3] + bi;
            float mx = fmaxf(fmaxf(v0, v1), fmaxf(v2, v3));
            mx = fmaxf(mx, __shfl_xor(mx, 16));
            mx = fmaxf(mx, __shfl_xor(mx, 32));
            float e0 = __expf(v0 - mx), e1 = __expf(v1 - mx);
            float e2 = __expf(v2 - mx), e3 = __expf(v3 - mx);
            float ws = e0 * bf2f(smem[(size_t)vrow * 128 + vch])
                     + e1 * bf2f(smem[(size_t)(vrow + 1) * 128 + vch])
                     + e2 * bf2f(smem[(size_t)(vrow + 2) * 128 + vch])
                     + e3 * bf2f(smem[(size_t)(vrow + 3) * 128 + vch]);
            float es = e0 + e1 + e2 + e3;
            ws += __shfl_xor(ws, 16); ws += __shfl_xor(ws, 32);
            es += __shfl_xor(es, 16); es += __shfl_xor(es, 32);
            if (fq == 0) out[((size_t)bb * Cc + gn) * Nc + nn] = ws / es;
        }
    }
}

// ---------------------------------------------------------------------------
extern "C" void kernel_launch(void* const* d_in, const int* in_sizes, int n_in,
                              void* d_out, int out_size, void* d_ws, size_t ws_size,
                              hipStream_t stream) {
    (void)in_sizes; (void)n_in; (void)out_size;
    const float* pcd     = (const float*)d_in[0];
    const float* feat    = (const float*)d_in[1];
    const float* pcd_db  = (const float*)d_in[2];
    const float* feat_db = (const float*)d_in[3];
    const float* pw1 = (const float*)d_in[4];
    const float* pb1 = (const float*)d_in[5];
    const float* pg  = (const float*)d_in[6];
    const float* pbb = (const float*)d_in[7];
    const float* pm  = (const float*)d_in[8];
    const float* pv  = (const float*)d_in[9];
    const float* pw2 = (const float*)d_in[10];
    const float* pb2 = (const float*)d_in[11];
    const float* aw1 = (const float*)d_in[12];
    const float* ab1 = (const float*)d_in[13];
    const float* ag  = (const float*)d_in[14];
    const float* abb = (const float*)d_in[15];
    const float* am  = (const float*)d_in[16];
    const float* av  = (const float*)d_in[17];
    const float* aw2 = (const float*)d_in[18];
    const float* ab2 = (const float*)d_in[19];
    float* out = (float*)d_out;

    char* base = (char*)d_ws;
    size_t off = 0;
    auto alloc = [&](size_t bytes) -> char* {
        char* r = base + off;
        off = (off + bytes + 255) & ~(size_t)255;
        return r;
    };
    int*   idxb  = (int*)alloc((size_t)RT * 4);
    float* featT = (float*)alloc((size_t)Bc * Sc * Cc * 4);
    u16*   W1b   = (u16*)alloc((size_t)AH * Cc * 2);
    float* bias1 = (float*)alloc((size_t)AH * 4);
    u16*   W2b   = (u16*)alloc((size_t)Cc * AH * 2);
    u16*   PW2b  = (u16*)alloc((size_t)Cc * PH * 2);
    u16*   Hb    = (u16*)alloc((size_t)RT * PH * 2);

    // chunked row pipeline: cr=32768 is the measured optimum (r14/r17: 338 us).
    const size_t perrow = 1024 + 1024 + 2048;  // X,V bf16 + A bf16
    int cr = 32768;
    size_t avail = ws_size > off ? ws_size - off : 0;
    if (avail < (size_t)cr * perrow) {
        cr = (int)((avail / perrow) & ~(size_t)127);
        if (cr < 128) cr = 128;
    }
    u16*   Xb = (u16*)alloc((size_t)cr * Cc * 2);
    u16*   Vb = (u16*)alloc((size_t)cr * Cc * 2);
    u16*   Ab = (u16*)alloc((size_t)cr * AH * 2);

    transpose_kernel<<<dim3(Bc * 40 * 8), dim3(256), 0, stream>>>(feat, feat_db, featT);
    prep_kernel<<<dim3((AH * Cc) / 256), dim3(256), 0, stream>>>(aw1, ab1, ag, abb, am, av, aw2, pw2,
                                                                 W1b, bias1, W2b, PW2b);
    knn_kernel<<<dim3(Bc * Nc / 4), dim3(256), 0, stream>>>(pcd, pcd_db, idxb);
    hker<<<dim3(RT / 256), dim3(256), 0, stream>>>(pcd, pcd_db, idxb, pw1, pb1, pg, pbb, pm, pv, Hb);

    for (int r0 = 0; r0 < RT; r0 += cr) {
        int rows = (RT - r0 < cr) ? (RT - r0) : cr;
        pgemm_fused<<<dim3(rows / 128, Cc / 128), dim3(256), 0, stream>>>(Hb, PW2b, pb2, featT, idxb,
                                                                          Xb, Vb, r0);
        gemm_bt<true, true><<<dim3(rows / 128, AH / 128), dim3(256), 0, stream>>>(Xb, W1b, bias1, Ab, rows, AH, Cc);
        gemm2_fused<<<dim3(rows / 128, Cc / 128), dim3(256), 0, stream>>>(Ab, W2b, ab2, Vb, out, r0, AH);
    }
}

// Round 19
// 301.078 us; speedup vs baseline: 1.2709x; 1.0593x over previous
//
#include <hip/hip_runtime.h>

typedef unsigned short u16;
typedef unsigned int   u32;
typedef __attribute__((ext_vector_type(8))) short bf16x8;
typedef __attribute__((ext_vector_type(4))) float f32x4;
typedef __attribute__((ext_vector_type(4))) u32   u32x4;

// Problem constants
constexpr int Bc = 2, Cc = 512, Nc = 2048, Mc = 512, Sc = 2560, Kc = 16, PH = 64, AH = 1024;
constexpr int RT = Bc * Nc * Kc;  // 65536 rows (b,n,k)
constexpr float EPS = 1e-5f;

__device__ __forceinline__ u16 f2bf(float f) {
    u32 u = __float_as_uint(f);
    u32 r = (u + 0x7fffu + ((u >> 16) & 1u)) >> 16;  // RNE
    return (u16)r;
}
__device__ __forceinline__ float bf2f(u16 h) { return __uint_as_float(((u32)h) << 16); }

__device__ __forceinline__ void gload_lds16(const void* g, void* l) {
    __builtin_amdgcn_global_load_lds((const __attribute__((address_space(1))) u32*)g,
                                     (__attribute__((address_space(3))) u32*)l, 16, 0, 0);
}

// Bijective XCD-aware workgroup swizzle (m204 form): same-XCD wgs get a
// contiguous run of linear ids. With bn-fastest linearization this makes an
// XCD reuse one A-panel across all bn tiles (L2 locality).
__device__ __forceinline__ void xcd_tiles(u32& bm, u32& bn) {
    u32 gdx = gridDim.x, gdy = gridDim.y;
    u32 nwg = gdx * gdy;
    u32 wg = blockIdx.x + gdx * blockIdx.y;
    u32 q = nwg >> 3, r8 = nwg & 7;
    u32 xcd = wg & 7, loc = wg >> 3;
    u32 swz = (xcd < r8 ? xcd * (q + 1) : r8 * (q + 1) + (xcd - r8) * q) + loc;
    bn = swz % gdy;   // bn fastest within an XCD's contiguous run
    bm = swz / gdy;
}

// lex-min on (d, s): total order, associative -> tree order == scan order
__device__ __forceinline__ void lmin(float& da, int& sa, float db, int sb) {
    bool better = (db < da) || (db == da && sb < sa);
    da = better ? db : da;
    sa = better ? sb : sa;
}

// ---------------------------------------------------------------------------
// Transpose fusion_feat [B,C,S(split)] f32 -> featT [B,S,C] f32
// ---------------------------------------------------------------------------
__global__ __launch_bounds__(256) void transpose_kernel(const float* __restrict__ feat,
                                                        const float* __restrict__ feat_db,
                                                        float* __restrict__ featT) {
    __shared__ float tile[64][65];
    int bid = blockIdx.x;
    int b = bid / (40 * 8);
    int rem = bid - b * (40 * 8);
    int st = rem >> 3, ct = rem & 7;
    int t = threadIdx.x, lane = t & 63, g = t >> 6;
    int s0 = st * 64, c0 = ct * 64;
    const float* src;
    int sl0, stride;
    if (s0 < Nc) { src = feat + (size_t)b * Cc * Nc; sl0 = s0; stride = Nc; }
    else         { src = feat_db + (size_t)b * Cc * Mc; sl0 = s0 - Nc; stride = Mc; }
#pragma unroll
    for (int i = 0; i < 16; i++) {
        int cl = g * 16 + i;
        tile[cl][lane] = src[(size_t)(c0 + cl) * stride + sl0 + lane];
    }
    __syncthreads();
#pragma unroll
    for (int i = 0; i < 16; i++) {
        int sl = g * 16 + i;
        featT[((size_t)b * Sc + s0 + sl) * Cc + c0 + lane] = tile[lane][sl];
    }
}

// ---------------------------------------------------------------------------
// Weight prep: fold attn BN into W1/bias1, cast attn W1/W2 + pos W2 to bf16
// ---------------------------------------------------------------------------
__global__ __launch_bounds__(256) void prep_kernel(const float* __restrict__ aw1, const float* __restrict__ ab1,
                                                   const float* __restrict__ ag, const float* __restrict__ abb,
                                                   const float* __restrict__ am, const float* __restrict__ av,
                                                   const float* __restrict__ aw2, const float* __restrict__ pw2,
                                                   u16* __restrict__ W1b, float* __restrict__ bias1,
                                                   u16* __restrict__ W2b, u16* __restrict__ PW2b) {
    int i = blockIdx.x * 256 + threadIdx.x;  // grid covers 524288
    if (i < AH * Cc) {
        int o = i >> 9;
        float inv = ag[o] / sqrtf(av[o] + EPS);
        W1b[i] = f2bf(aw1[i] * inv);
    }
    if (i < AH) {
        float inv = ag[i] / sqrtf(av[i] + EPS);
        bias1[i] = ab1[i] * inv + abb[i] - am[i] * inv;
    }
    if (i < Cc * AH) W2b[i] = f2bf(aw2[i]);
    if (i < Cc * PH) PW2b[i] = f2bf(pw2[i]);
}

// ---------------------------------------------------------------------------
// KNN (v1 + tree-scan): one wave per query; distances mirror the reference
// decomposition qq + ss - 2*dot, no fma contraction; ties -> smaller index.
// ---------------------------------------------------------------------------
__global__ __launch_bounds__(256) void knn_kernel(const float* __restrict__ pcd,
                                                  const float* __restrict__ pcd_db,
                                                  int* __restrict__ idxout) {
    int t = threadIdx.x, w = t >> 6, l = t & 63;
    int q = blockIdx.x * 4 + w;  // 0..4095
    int b = q >> 11, n = q & (Nc - 1);
    const float* pc = pcd + (size_t)b * 3 * Nc;
    const float* pd = pcd_db + (size_t)b * 3 * Mc;
    float qx = pc[n], qy = pc[Nc + n], qz = pc[2 * Nc + n];
    float qq = __fadd_rn(__fadd_rn(__fmul_rn(qx, qx), __fmul_rn(qy, qy)), __fmul_rn(qz, qz));
    float dist[40];
#pragma unroll
    for (int j = 0; j < 40; j++) {
        int s = j * 64 + l;
        float sx, sy, sz;
        if (s < Nc) { sx = pc[s]; sy = pc[Nc + s]; sz = pc[2 * Nc + s]; }
        else { int ss = s - Nc; sx = pd[ss]; sy = pd[Mc + ss]; sz = pd[2 * Mc + ss]; }
        float ss2 = __fadd_rn(__fadd_rn(__fmul_rn(sx, sx), __fmul_rn(sy, sy)), __fmul_rn(sz, sz));
        float dt  = __fadd_rn(__fadd_rn(__fmul_rn(qx, sx), __fmul_rn(qy, sy)), __fmul_rn(qz, sz));
        dist[j] = __fsub_rn(__fadd_rn(qq, ss2), __fmul_rn(2.0f, dt));
    }
    for (int r = 0; r < 16; r++) {
        // tree lex-min over the 40 (dist[j], j*64+l) pairs
        float td[20];
        int   ts[20];
#pragma unroll
        for (int i = 0; i < 20; i++) {
            float d0 = dist[2 * i], d1 = dist[2 * i + 1];
            int s0 = (2 * i) * 64 + l, s1 = (2 * i + 1) * 64 + l;
            bool bt = (d1 < d0) || (d1 == d0 && s1 < s0);
            td[i] = bt ? d1 : d0;
            ts[i] = bt ? s1 : s0;
        }
#pragma unroll
        for (int i = 0; i < 10; i++) lmin(td[i], ts[i], td[i + 10], ts[i + 10]);
#pragma unroll
        for (int i = 0; i < 5; i++) lmin(td[i], ts[i], td[i + 5], ts[i + 5]);
        lmin(td[0], ts[0], td[3], ts[3]);
        lmin(td[1], ts[1], td[4], ts[4]);
        lmin(td[0], ts[0], td[2], ts[2]);
        lmin(td[0], ts[0], td[1], ts[1]);
        float bd = td[0];
        int   bs = ts[0];
        for (int off = 32; off; off >>= 1) {
            float od = __shfl_xor(bd, off);
            int   os = __shfl_xor(bs, off);
            bool better = (od < bd) || (od == bd && os < bs);
            bd = better ? od : bd;
            bs = better ? os : bs;
        }
        if (l == 0) idxout[q * 16 + r] = bs;
        int wj = bs >> 6, wl = bs & 63;
        if (l == wl) {
#pragma unroll
            for (int j = 0; j < 40; j++)
                if (j == wj) dist[j] = 1e30f;
        }
    }
}

// ---------------------------------------------------------------------------
// HKER: per row, pos-MLP layer-1: h[r][64] = relu(BN(W1 (q - s) + b1)) bf16
// ---------------------------------------------------------------------------
__global__ __launch_bounds__(256) void hker(const float* __restrict__ pcd, const float* __restrict__ pcd_db,
                                            const int* __restrict__ idxb,
                                            const float* __restrict__ pw1, const float* __restrict__ pb1,
                                            const float* __restrict__ pg, const float* __restrict__ pbb,
                                            const float* __restrict__ pm, const float* __restrict__ pv,
                                            u16* __restrict__ H) {
    __shared__ float W1s[64][4];
    int t = threadIdx.x;
    if (t < 64) {
        float inv = pg[t] / sqrtf(pv[t] + EPS);
        W1s[t][0] = pw1[t * 3 + 0] * inv;
        W1s[t][1] = pw1[t * 3 + 1] * inv;
        W1s[t][2] = pw1[t * 3 + 2] * inv;
        W1s[t][3] = pb1[t] * inv + pbb[t] - pm[t] * inv;
    }
    __syncthreads();
    int r = blockIdx.x * 256 + t;
    int b = r >> 15, n = (r >> 4) & (Nc - 1), s = idxb[r];
    const float* pc = pcd + (size_t)b * 3 * Nc;
    float qx = pc[n], qy = pc[Nc + n], qz = pc[2 * Nc + n];
    float sx, sy, sz;
    if (s < Nc) { sx = pc[s]; sy = pc[Nc + s]; sz = pc[2 * Nc + s]; }
    else {
        const float* pd = pcd_db + (size_t)b * 3 * Mc;
        int ss = s - Nc;
        sx = pd[ss]; sy = pd[Mc + ss]; sz = pd[2 * Mc + ss];
    }
    float dx = qx - sx, dy = qy - sy, dz = qz - sz;
    u16* hp = H + (size_t)r * 64;
#pragma unroll
    for (int u0 = 0; u0 < 64; u0 += 8) {
        u16 e[8];
#pragma unroll
        for (int j = 0; j < 8; j++) {
            int u = u0 + j;
            float hv = fmaxf(0.f, dx * W1s[u][0] + dy * W1s[u][1] + dz * W1s[u][2] + W1s[u][3]);
            e[j] = f2bf(hv);
        }
        u32x4 pk;
        pk.x = (u32)e[0] | ((u32)e[1] << 16); pk.y = (u32)e[2] | ((u32)e[3] << 16);
        pk.z = (u32)e[4] | ((u32)e[5] << 16); pk.w = (u32)e[6] | ((u32)e[7] << 16);
        *(u32x4*)(hp + u0) = pk;
    }
}

// ---------------------------------------------------------------------------
// PGEMM_FUSED: P = H @ PW2^T + pb2 via MFMA (M=rows, N=512, K=64), epilogue
// gathers f,g from featT and emits X = f-g+p, V = g+p (bf16).
// ---------------------------------------------------------------------------
__global__ __launch_bounds__(256) void pgemm_fused(const u16* __restrict__ Hg, const u16* __restrict__ Bg,
                                                   const float* __restrict__ pb2,
                                                   const float* __restrict__ featT, const int* __restrict__ idxb,
                                                   u16* __restrict__ X, u16* __restrict__ V, int row0) {
    __shared__ u16 As[128 * 64];
    __shared__ u16 Bs[128 * 64];
    const int t = threadIdx.x;
    u32 bmu, bnu;
    xcd_tiles(bmu, bnu);
    const int bm = (int)bmu, bn = (int)bnu;
    const int w = t >> 6, l = t & 63;
    const int wr = w >> 1, wc = w & 1;
    const int fr = l & 15, fq = l >> 4;
    f32x4 acc[4][4];
#pragma unroll
    for (int i = 0; i < 4; i++)
#pragma unroll
        for (int j = 0; j < 4; j++) {
            f32x4 z = {0.f, 0.f, 0.f, 0.f};
            acc[i][j] = z;
        }
    const char* Abase = (const char*)Hg + ((size_t)row0 + (size_t)bm * 128) * 64 * 2;
    const char* Bbase = (const char*)Bg + (size_t)bn * 128 * 64 * 2;
#pragma unroll
    for (int i = 0; i < 4; i++) {
        int chunk = i * 256 + t;
        int row = chunk >> 3;
        int cb = (chunk & 7) * 16;
        gload_lds16(Abase + (size_t)row * 128 + cb, (char*)As + chunk * 16);
    }
#pragma unroll
    for (int i = 0; i < 4; i++) {
        int chunk = i * 256 + t;
        int row = chunk >> 3;
        int cb = (chunk & 7) * 16;
        gload_lds16(Bbase + (size_t)row * 128 + cb, (char*)Bs + chunk * 16);
    }
    __syncthreads();
    bf16x8 af[4][2], bfv[4][2];
#pragma unroll
    for (int mf = 0; mf < 4; mf++)
#pragma unroll
        for (int ks = 0; ks < 2; ks++)
            af[mf][ks] = *(const bf16x8*)&As[(wr * 64 + mf * 16 + fr) * 64 + ks * 32 + fq * 8];
#pragma unroll
    for (int nf = 0; nf < 4; nf++)
#pragma unroll
        for (int ks = 0; ks < 2; ks++)
            bfv[nf][ks] = *(const bf16x8*)&Bs[(wc * 64 + nf * 16 + fr) * 64 + ks * 32 + fq * 8];
#pragma unroll
    for (int mf = 0; mf < 4; mf++)
#pragma unroll
        for (int nf = 0; nf < 4; nf++)
#pragma unroll
            for (int ks = 0; ks < 2; ks++)
                acc[mf][nf] = __builtin_amdgcn_mfma_f32_16x16x32_bf16(af[mf][ks], bfv[nf][ks], acc[mf][nf], 0, 0, 0);
    // epilogue: per C-row gather f,g; emit X,V
#pragma unroll
    for (int mf = 0; mf < 4; mf++) {
#pragma unroll
        for (int r = 0; r < 4; r++) {
            int gr = bm * 128 + wr * 64 + mf * 16 + fq * 4 + r;  // chunk-local row
            int grow = row0 + gr;                                 // global row
            int b = grow >> 15;
            int n = (grow >> 4) & (Nc - 1);
            int s = idxb[grow];
            const float* frow = featT + ((size_t)b * Sc + n) * Cc;
            const float* grow_p = featT + ((size_t)b * Sc + s) * Cc;
#pragma unroll
            for (int nf = 0; nf < 4; nf++) {
                int gn = bn * 128 + wc * 64 + nf * 16 + fr;
                float p = acc[mf][nf][r] + pb2[gn];
                float fv = frow[gn];
                float gv = grow_p[gn];
                X[(size_t)gr * Cc + gn] = f2bf(fv - gv + p);
                V[(size_t)gr * Cc + gn] = f2bf(gv + p);
            }
        }
    }
}

// ---------------------------------------------------------------------------
// GEMM (double-buffered + XCD swizzle): C[m][n] = f(sum_k A[m][k]*B[n][k]+b)
// A [M][Kd] bf16, B [N][Kd] bf16 (B^T layout), 128x128 tile, BK=64.
// K-loop prefetches tile t+1 into buf^1 right after the barrier (T3-minimum,
// proven on gemm2 in r18). Same K-order -> bit-identical results.
// ---------------------------------------------------------------------------
template <bool RELU, bool OBF16>
__global__ __launch_bounds__(256) void gemm_bt(const u16* __restrict__ Ag, const u16* __restrict__ Bg,
                                               const float* __restrict__ bias, void* __restrict__ Cg,
                                               int M, int N, int Kd) {
    __shared__ u16 smem[32768];  // 64 KB: buf0 {As 16K|Bs 16K} buf1 {As|Bs}
    const int t = threadIdx.x;
    u32 bmu, bnu;
    xcd_tiles(bmu, bnu);
    const int bm = (int)bmu, bn = (int)bnu;
    const int w = t >> 6, l = t & 63;
    const int wr = w >> 1, wc = w & 1;
    const int fr = l & 15, fq = l >> 4;
    f32x4 acc[4][4];
#pragma unroll
    for (int i = 0; i < 4; i++)
#pragma unroll
        for (int j = 0; j < 4; j++) {
            f32x4 z = {0.f, 0.f, 0.f, 0.f};
            acc[i][j] = z;
        }
    const char* Abase = (const char*)Ag + (size_t)bm * 128 * (size_t)Kd * 2;
    const char* Bbase = (const char*)Bg + (size_t)bn * 128 * (size_t)Kd * 2;
    const size_t ldb = (size_t)Kd * 2;

    auto stage = [&](int buf, int kt) {
        char* Ad = (char*)smem + (size_t)buf * 32768;
        char* Bd = Ad + 16384;
#pragma unroll
        for (int i = 0; i < 4; i++) {
            int chunk = i * 256 + t;
            int row = chunk >> 3;
            int cb = (chunk & 7) * 16;
            gload_lds16(Abase + (size_t)row * ldb + (size_t)kt * 2 + cb, Ad + chunk * 16);
        }
#pragma unroll
        for (int i = 0; i < 4; i++) {
            int chunk = i * 256 + t;
            int row = chunk >> 3;
            int cb = (chunk & 7) * 16;
            gload_lds16(Bbase + (size_t)row * ldb + (size_t)kt * 2 + cb, Bd + chunk * 16);
        }
    };

    const int nt = Kd / 64;
    stage(0, 0);
    int cur = 0;
    for (int it = 0; it < nt; ++it) {
        __syncthreads();
        if (it + 1 < nt) stage(cur ^ 1, (it + 1) * 64);
        const u16* As = smem + (size_t)cur * 16384;
        const u16* Bs = As + 8192;
        bf16x8 af[4][2], bfv[4][2];
#pragma unroll
        for (int mf = 0; mf < 4; mf++)
#pragma unroll
            for (int ks = 0; ks < 2; ks++)
                af[mf][ks] = *(const bf16x8*)&As[(wr * 64 + mf * 16 + fr) * 64 + ks * 32 + fq * 8];
#pragma unroll
        for (int nf = 0; nf < 4; nf++)
#pragma unroll
            for (int ks = 0; ks < 2; ks++)
                bfv[nf][ks] = *(const bf16x8*)&Bs[(wc * 64 + nf * 16 + fr) * 64 + ks * 32 + fq * 8];
#pragma unroll
        for (int mf = 0; mf < 4; mf++)
#pragma unroll
            for (int nf = 0; nf < 4; nf++)
#pragma unroll
                for (int ks = 0; ks < 2; ks++)
                    acc[mf][nf] = __builtin_amdgcn_mfma_f32_16x16x32_bf16(af[mf][ks], bfv[nf][ks], acc[mf][nf], 0, 0, 0);
        cur ^= 1;
    }
#pragma unroll
    for (int mf = 0; mf < 4; mf++) {
#pragma unroll
        for (int nf = 0; nf < 4; nf++) {
            int gn = bn * 128 + wc * 64 + nf * 16 + fr;
            float bi = bias[gn];
            int gm0 = bm * 128 + wr * 64 + mf * 16 + fq * 4;
#pragma unroll
            for (int r = 0; r < 4; r++) {
                float v = acc[mf][nf][r] + bi;
                if (RELU) v = fmaxf(v, 0.f);
                size_t o = (size_t)(gm0 + r) * N + gn;
                if (OBF16) ((u16*)Cg)[o] = f2bf(v);
                else ((float*)Cg)[o] = v;
            }
        }
    }
}

// ---------------------------------------------------------------------------
// GEMM2_FUSED (double-buffered): logits L = A @ W2^T + ab2 (M=rows, N=512,
// K=1024) with softmax-over-k + weighted-V reduce fused into the epilogue.
// ---------------------------------------------------------------------------
__global__ __launch_bounds__(256) void gemm2_fused(const u16* __restrict__ Ag, const u16* __restrict__ Bg,
                                                   const float* __restrict__ bias, const u16* __restrict__ Vb,
                                                   float* __restrict__ out, int row0, int Kd) {
    __shared__ u16 smem[32768];  // 64 KB: buf0 {As 16K|Bs 16K} buf1 {As|Bs}; V tile (32 KB) reuses buf0
    const int t = threadIdx.x;
    u32 bmu, bnu;
    xcd_tiles(bmu, bnu);
    const int bm = (int)bmu, bn = (int)bnu;
    const int w = t >> 6, l = t & 63;
    const int wr = w >> 1, wc = w & 1;
    const int fr = l & 15, fq = l >> 4;
    f32x4 acc[4][4];
#pragma unroll
    for (int i = 0; i < 4; i++)
#pragma unroll
        for (int j = 0; j < 4; j++) {
            f32x4 z = {0.f, 0.f, 0.f, 0.f};
            acc[i][j] = z;
        }
    const char* Abase = (const char*)Ag + (size_t)bm * 128 * (size_t)Kd * 2;
    const char* Bbase = (const char*)Bg + (size_t)bn * 128 * (size_t)Kd * 2;
    const size_t ldb = (size_t)Kd * 2;

    auto stage = [&](int buf, int kt) {
        char* Ad = (char*)smem + (size_t)buf * 32768;
        char* Bd = Ad + 16384;
#pragma unroll
        for (int i = 0; i < 4; i++) {
            int chunk = i * 256 + t;
            int row = chunk >> 3;
            int cb = (chunk & 7) * 16;
            gload_lds16(Abase + (size_t)row * ldb + (size_t)kt * 2 + cb, Ad + chunk * 16);
        }
#pragma unroll
        for (int i = 0; i < 4; i++) {
            int chunk = i * 256 + t;
            int row = chunk >> 3;
            int cb = (chunk & 7) * 16;
            gload_lds16(Bbase + (size_t)row * ldb + (size_t)kt * 2 + cb, Bd + chunk * 16);
        }
    };

    const int nt = Kd / 64;   // 16
    stage(0, 0);
    int cur = 0;
    for (int it = 0; it < nt; ++it) {
        __syncthreads();                      // drains stage(cur); prior reads of cur^1 done
        if (it + 1 < nt) stage(cur ^ 1, (it + 1) * 64);  // prefetch overlaps this tile's compute
        const u16* As = smem + (size_t)cur * 16384;
        const u16* Bs = As + 8192;
        bf16x8 af[4][2], bfv[4][2];
#pragma unroll
        for (int mf = 0; mf < 4; mf++)
#pragma unroll
            for (int ks = 0; ks < 2; ks++)
                af[mf][ks] = *(const bf16x8*)&As[(wr * 64 + mf * 16 + fr) * 64 + ks * 32 + fq * 8];
#pragma unroll
        for (int nf = 0; nf < 4; nf++)
#pragma unroll
            for (int ks = 0; ks < 2; ks++)
                bfv[nf][ks] = *(const bf16x8*)&Bs[(wc * 64 + nf * 16 + fr) * 64 + ks * 32 + fq * 8];
#pragma unroll
        for (int mf = 0; mf < 4; mf++)
#pragma unroll
            for (int nf = 0; nf < 4; nf++)
#pragma unroll
                for (int ks = 0; ks < 2; ks++)
                    acc[mf][nf] = __builtin_amdgcn_mfma_f32_16x16x32_bf16(af[mf][ks], bfv[nf][ks], acc[mf][nf], 0, 0, 0);
        cur ^= 1;
    }
    // stage V tile [bm*128 .. +128)[bn*128 .. +128) into buf0 (coalesced).
    const char* Vbase = (const char*)Vb + (size_t)bm * 128 * Cc * 2 + (size_t)bn * 256;
#pragma unroll
    for (int i = 0; i < 8; i++) {
        int chunk = i * 256 + t;       // 0..2047
        int row = chunk >> 4;          // 0..127
        int cb = (chunk & 15) * 16;    // byte offset in row (256B rows)
        gload_lds16(Vbase + (size_t)row * (Cc * 2) + cb, (char*)smem + chunk * 16);
    }
    __syncthreads();
    // fused epilogue: per (point, channel) softmax over k=fq*4+r + V-reduce
#pragma unroll
    for (int mf = 0; mf < 4; mf++) {
        int lp = bm * 8 + wr * 4 + mf;        // chunk-local point
        int gp = row0 / 16 + lp;              // global point
        int bb = gp >> 11, nn = gp & (Nc - 1);
        int vrow = (wr * 4 + mf) * 16 + fq * 4;  // tile-local V row for r=0
#pragma unroll
        for (int nf = 0; nf < 4; nf++) {
            int gn = bn * 128 + wc * 64 + nf * 16 + fr;
            int vch = wc * 64 + nf * 16 + fr;
            float bi = bias[gn];
            float v0 = acc[mf][nf][0] + bi, v1 = acc[mf][nf][1] + bi;
            float v2 = acc[mf][nf][2] + bi, v3 = acc[mf][nf][3] + bi;
            float mx = fmaxf(fmaxf(v0, v1), fmaxf(v2, v3));
            mx = fmaxf(mx, __shfl_xor(mx, 16));
            mx = fmaxf(mx, __shfl_xor(mx, 32));
            float e0 = __expf(v0 - mx), e1 = __expf(v1 - mx);
            float e2 = __expf(v2 - mx), e3 = __expf(v3 - mx);
            float ws = e0 * bf2f(smem[(size_t)vrow * 128 + vch])
                     + e1 * bf2f(smem[(size_t)(vrow + 1) * 128 + vch])
                     + e2 * bf2f(smem[(size_t)(vrow + 2) * 128 + vch])
                     + e3 * bf2f(smem[(size_t)(vrow + 3) * 128 + vch]);
            float es = e0 + e1 + e2 + e3;
            ws += __shfl_xor(ws, 16); ws += __shfl_xor(ws, 32);
            es += __shfl_xor(es, 16); es += __shfl_xor(es, 32);
            if (fq == 0) out[((size_t)bb * Cc + gn) * Nc + nn] = ws / es;
        }
    }
}

// ---------------------------------------------------------------------------
extern "C" void kernel_launch(void* const* d_in, const int* in_sizes, int n_in,
                              void* d_out, int out_size, void* d_ws, size_t ws_size,
                              hipStream_t stream) {
    (void)in_sizes; (void)n_in; (void)out_size;
    const float* pcd     = (const float*)d_in[0];
    const float* feat    = (const float*)d_in[1];
    const float* pcd_db  = (const float*)d_in[2];
    const float* feat_db = (const float*)d_in[3];
    const float* pw1 = (const float*)d_in[4];
    const float* pb1 = (const float*)d_in[5];
    const float* pg  = (const float*)d_in[6];
    const float* pbb = (const float*)d_in[7];
    const float* pm  = (const float*)d_in[8];
    const float* pv  = (const float*)d_in[9];
    const float* pw2 = (const float*)d_in[10];
    const float* pb2 = (const float*)d_in[11];
    const float* aw1 = (const float*)d_in[12];
    const float* ab1 = (const float*)d_in[13];
    const float* ag  = (const float*)d_in[14];
    const float* abb = (const float*)d_in[15];
    const float* am  = (const float*)d_in[16];
    const float* av  = (const float*)d_in[17];
    const float* aw2 = (const float*)d_in[18];
    const float* ab2 = (const float*)d_in[19];
    float* out = (float*)d_out;

    char* base = (char*)d_ws;
    size_t off = 0;
    auto alloc = [&](size_t bytes) -> char* {
        char* r = base + off;
        off = (off + bytes + 255) & ~(size_t)255;
        return r;
    };
    int*   idxb  = (int*)alloc((size_t)RT * 4);
    float* featT = (float*)alloc((size_t)Bc * Sc * Cc * 4);
    u16*   W1b   = (u16*)alloc((size_t)AH * Cc * 2);
    float* bias1 = (float*)alloc((size_t)AH * 4);
    u16*   W2b   = (u16*)alloc((size_t)Cc * AH * 2);
    u16*   PW2b  = (u16*)alloc((size_t)Cc * PH * 2);
    u16*   Hb    = (u16*)alloc((size_t)RT * PH * 2);

    // chunked row pipeline: cr=32768 is the measured optimum (r14/r17: 338 us).
    const size_t perrow = 1024 + 1024 + 2048;  // X,V bf16 + A bf16
    int cr = 32768;
    size_t avail = ws_size > off ? ws_size - off : 0;
    if (avail < (size_t)cr * perrow) {
        cr = (int)((avail / perrow) & ~(size_t)127);
        if (cr < 128) cr = 128;
    }
    u16*   Xb = (u16*)alloc((size_t)cr * Cc * 2);
    u16*   Vb = (u16*)alloc((size_t)cr * Cc * 2);
    u16*   Ab = (u16*)alloc((size_t)cr * AH * 2);

    transpose_kernel<<<dim3(Bc * 40 * 8), dim3(256), 0, stream>>>(feat, feat_db, featT);
    prep_kernel<<<dim3((AH * Cc) / 256), dim3(256), 0, stream>>>(aw1, ab1, ag, abb, am, av, aw2, pw2,
                                                                 W1b, bias1, W2b, PW2b);
    knn_kernel<<<dim3(Bc * Nc / 4), dim3(256), 0, stream>>>(pcd, pcd_db, idxb);
    hker<<<dim3(RT / 256), dim3(256), 0, stream>>>(pcd, pcd_db, idxb, pw1, pb1, pg, pbb, pm, pv, Hb);

    for (int r0 = 0; r0 < RT; r0 += cr) {
        int rows = (RT - r0 < cr) ? (RT - r0) : cr;
        pgemm_fused<<<dim3(rows / 128, Cc / 128), dim3(256), 0, stream>>>(Hb, PW2b, pb2, featT, idxb,
                                                                          Xb, Vb, r0);
        gemm_bt<true, true><<<dim3(rows / 128, AH / 128), dim3(256), 0, stream>>>(Xb, W1b, bias1, Ab, rows, AH, Cc);
        gemm2_fused<<<dim3(rows / 128, Cc / 128), dim3(256), 0, stream>>>(Ab, W2b, ab2, Vb, out, r0, AH);
    }
}

// Round 22
// 298.708 us; speedup vs baseline: 1.2810x; 1.0079x over previous
//
#include <hip/hip_runtime.h>

typedef unsigned short u16;
typedef unsigned int   u32;
typedef __attribute__((ext_vector_type(8))) short bf16x8;
typedef __attribute__((ext_vector_type(4))) float f32x4;
typedef __attribute__((ext_vector_type(4))) u32   u32x4;

// Problem constants
constexpr int Bc = 2, Cc = 512, Nc = 2048, Mc = 512, Sc = 2560, Kc = 16, PH = 64, AH = 1024;
constexpr int RT = Bc * Nc * Kc;  // 65536 rows (b,n,k)
constexpr float EPS = 1e-5f;

__device__ __forceinline__ u16 f2bf(float f) {
    u32 u = __float_as_uint(f);
    u32 r = (u + 0x7fffu + ((u >> 16) & 1u)) >> 16;  // RNE
    return (u16)r;
}
__device__ __forceinline__ float bf2f(u16 h) { return __uint_as_float(((u32)h) << 16); }

__device__ __forceinline__ void gload_lds16(const void* g, void* l) {
    __builtin_amdgcn_global_load_lds((const __attribute__((address_space(1))) u32*)g,
                                     (__attribute__((address_space(3))) u32*)l, 16, 0, 0);
}

// Bijective XCD-aware workgroup swizzle (m204 form): same-XCD wgs get a
// contiguous run of linear ids. With bn-fastest linearization this makes an
// XCD reuse one A-panel across all bn tiles (L2 locality).
__device__ __forceinline__ void xcd_tiles(u32& bm, u32& bn) {
    u32 gdx = gridDim.x, gdy = gridDim.y;
    u32 nwg = gdx * gdy;
    u32 wg = blockIdx.x + gdx * blockIdx.y;
    u32 q = nwg >> 3, r8 = nwg & 7;
    u32 xcd = wg & 7, loc = wg >> 3;
    u32 swz = (xcd < r8 ? xcd * (q + 1) : r8 * (q + 1) + (xcd - r8) * q) + loc;
    bn = swz % gdy;   // bn fastest within an XCD's contiguous run
    bm = swz / gdy;
}

// lex-min on (d, s): total order, associative -> tree order == scan order
__device__ __forceinline__ void lmin(float& da, int& sa, float db, int sb) {
    bool better = (db < da) || (db == da && sb < sa);
    da = better ? db : da;
    sa = better ? sb : sa;
}

// ---------------------------------------------------------------------------
// Transpose fusion_feat [B,C,S(split)] f32 -> featT [B,S,C] f32
// ---------------------------------------------------------------------------
__global__ __launch_bounds__(256) void transpose_kernel(const float* __restrict__ feat,
                                                        const float* __restrict__ feat_db,
                                                        float* __restrict__ featT) {
    __shared__ float tile[64][65];
    int bid = blockIdx.x;
    int b = bid / (40 * 8);
    int rem = bid - b * (40 * 8);
    int st = rem >> 3, ct = rem & 7;
    int t = threadIdx.x, lane = t & 63, g = t >> 6;
    int s0 = st * 64, c0 = ct * 64;
    const float* src;
    int sl0, stride;
    if (s0 < Nc) { src = feat + (size_t)b * Cc * Nc; sl0 = s0; stride = Nc; }
    else         { src = feat_db + (size_t)b * Cc * Mc; sl0 = s0 - Nc; stride = Mc; }
#pragma unroll
    for (int i = 0; i < 16; i++) {
        int cl = g * 16 + i;
        tile[cl][lane] = src[(size_t)(c0 + cl) * stride + sl0 + lane];
    }
    __syncthreads();
#pragma unroll
    for (int i = 0; i < 16; i++) {
        int sl = g * 16 + i;
        featT[((size_t)b * Sc + s0 + sl) * Cc + c0 + lane] = tile[lane][sl];
    }
}

// ---------------------------------------------------------------------------
// Weight prep: fold attn BN into W1/bias1, cast attn W1/W2 + pos W2 to bf16
// ---------------------------------------------------------------------------
__global__ __launch_bounds__(256) void prep_kernel(const float* __restrict__ aw1, const float* __restrict__ ab1,
                                                   const float* __restrict__ ag, const float* __restrict__ abb,
                                                   const float* __restrict__ am, const float* __restrict__ av,
                                                   const float* __restrict__ aw2, const float* __restrict__ pw2,
                                                   u16* __restrict__ W1b, float* __restrict__ bias1,
                                                   u16* __restrict__ W2b, u16* __restrict__ PW2b) {
    int i = blockIdx.x * 256 + threadIdx.x;  // grid covers 524288
    if (i < AH * Cc) {
        int o = i >> 9;
        float inv = ag[o] / sqrtf(av[o] + EPS);
        W1b[i] = f2bf(aw1[i] * inv);
    }
    if (i < AH) {
        float inv = ag[i] / sqrtf(av[i] + EPS);
        bias1[i] = ab1[i] * inv + abb[i] - am[i] * inv;
    }
    if (i < Cc * AH) W2b[i] = f2bf(aw2[i]);
    if (i < Cc * PH) PW2b[i] = f2bf(pw2[i]);
}

// ---------------------------------------------------------------------------
// KNN (v1 + tree-scan): one wave per query; distances mirror the reference
// decomposition qq + ss - 2*dot, no fma contraction; ties -> smaller index.
// ---------------------------------------------------------------------------
__global__ __launch_bounds__(256) void knn_kernel(const float* __restrict__ pcd,
                                                  const float* __restrict__ pcd_db,
                                                  int* __restrict__ idxout) {
    int t = threadIdx.x, w = t >> 6, l = t & 63;
    int q = blockIdx.x * 4 + w;  // 0..4095
    int b = q >> 11, n = q & (Nc - 1);
    const float* pc = pcd + (size_t)b * 3 * Nc;
    const float* pd = pcd_db + (size_t)b * 3 * Mc;
    float qx = pc[n], qy = pc[Nc + n], qz = pc[2 * Nc + n];
    float qq = __fadd_rn(__fadd_rn(__fmul_rn(qx, qx), __fmul_rn(qy, qy)), __fmul_rn(qz, qz));
    float dist[40];
#pragma unroll
    for (int j = 0; j < 40; j++) {
        int s = j * 64 + l;
        float sx, sy, sz;
        if (s < Nc) { sx = pc[s]; sy = pc[Nc + s]; sz = pc[2 * Nc + s]; }
        else { int ss = s - Nc; sx = pd[ss]; sy = pd[Mc + ss]; sz = pd[2 * Mc + ss]; }
        float ss2 = __fadd_rn(__fadd_rn(__fmul_rn(sx, sx), __fmul_rn(sy, sy)), __fmul_rn(sz, sz));
        float dt  = __fadd_rn(__fadd_rn(__fmul_rn(qx, sx), __fmul_rn(qy, sy)), __fmul_rn(qz, sz));
        dist[j] = __fsub_rn(__fadd_rn(qq, ss2), __fmul_rn(2.0f, dt));
    }
    for (int r = 0; r < 16; r++) {
        // tree lex-min over the 40 (dist[j], j*64+l) pairs
        float td[20];
        int   ts[20];
#pragma unroll
        for (int i = 0; i < 20; i++) {
            float d0 = dist[2 * i], d1 = dist[2 * i + 1];
            int s0 = (2 * i) * 64 + l, s1 = (2 * i + 1) * 64 + l;
            bool bt = (d1 < d0) || (d1 == d0 && s1 < s0);
            td[i] = bt ? d1 : d0;
            ts[i] = bt ? s1 : s0;
        }
#pragma unroll
        for (int i = 0; i < 10; i++) lmin(td[i], ts[i], td[i + 10], ts[i + 10]);
#pragma unroll
        for (int i = 0; i < 5; i++) lmin(td[i], ts[i], td[i + 5], ts[i + 5]);
        lmin(td[0], ts[0], td[3], ts[3]);
        lmin(td[1], ts[1], td[4], ts[4]);
        lmin(td[0], ts[0], td[2], ts[2]);
        lmin(td[0], ts[0], td[1], ts[1]);
        float bd = td[0];
        int   bs = ts[0];
        for (int off = 32; off; off >>= 1) {
            float od = __shfl_xor(bd, off);
            int   os = __shfl_xor(bs, off);
            bool better = (od < bd) || (od == bd && os < bs);
            bd = better ? od : bd;
            bs = better ? os : bs;
        }
        if (l == 0) idxout[q * 16 + r] = bs;
        int wj = bs >> 6, wl = bs & 63;
        if (l == wl) {
#pragma unroll
            for (int j = 0; j < 40; j++)
                if (j == wj) dist[j] = 1e30f;
        }
    }
}

// ---------------------------------------------------------------------------
// HKER: per row, pos-MLP layer-1: h[r][64] = relu(BN(W1 (q - s) + b1)) bf16
// ---------------------------------------------------------------------------
__global__ __launch_bounds__(256) void hker(const float* __restrict__ pcd, const float* __restrict__ pcd_db,
                                            const int* __restrict__ idxb,
                                            const float* __restrict__ pw1, const float* __restrict__ pb1,
                                            const float* __restrict__ pg, const float* __restrict__ pbb,
                                            const float* __restrict__ pm, const float* __restrict__ pv,
                                            u16* __restrict__ H) {
    __shared__ float W1s[64][4];
    int t = threadIdx.x;
    if (t < 64) {
        float inv = pg[t] / sqrtf(pv[t] + EPS);
        W1s[t][0] = pw1[t * 3 + 0] * inv;
        W1s[t][1] = pw1[t * 3 + 1] * inv;
        W1s[t][2] = pw1[t * 3 + 2] * inv;
        W1s[t][3] = pb1[t] * inv + pbb[t] - pm[t] * inv;
    }
    __syncthreads();
    int r = blockIdx.x * 256 + t;
    int b = r >> 15, n = (r >> 4) & (Nc - 1), s = idxb[r];
    const float* pc = pcd + (size_t)b * 3 * Nc;
    float qx = pc[n], qy = pc[Nc + n], qz = pc[2 * Nc + n];
    float sx, sy, sz;
    if (s < Nc) { sx = pc[s]; sy = pc[Nc + s]; sz = pc[2 * Nc + s]; }
    else {
        const float* pd = pcd_db + (size_t)b * 3 * Mc;
        int ss = s - Nc;
        sx = pd[ss]; sy = pd[Mc + ss]; sz = pd[2 * Mc + ss];
    }
    float dx = qx - sx, dy = qy - sy, dz = qz - sz;
    u16* hp = H + (size_t)r * 64;
#pragma unroll
    for (int u0 = 0; u0 < 64; u0 += 8) {
        u16 e[8];
#pragma unroll
        for (int j = 0; j < 8; j++) {
            int u = u0 + j;
            float hv = fmaxf(0.f, dx * W1s[u][0] + dy * W1s[u][1] + dz * W1s[u][2] + W1s[u][3]);
            e[j] = f2bf(hv);
        }
        u32x4 pk;
        pk.x = (u32)e[0] | ((u32)e[1] << 16); pk.y = (u32)e[2] | ((u32)e[3] << 16);
        pk.z = (u32)e[4] | ((u32)e[5] << 16); pk.w = (u32)e[6] | ((u32)e[7] << 16);
        *(u32x4*)(hp + u0) = pk;
    }
}

// ---------------------------------------------------------------------------
// PGEMM_FUSED: P = H @ PW2^T + pb2 via MFMA (M=rows, N=512, K=64), epilogue
// gathers f,g from featT and emits X = f-g+p, V = g+p (bf16).
// ---------------------------------------------------------------------------
__global__ __launch_bounds__(256) void pgemm_fused(const u16* __restrict__ Hg, const u16* __restrict__ Bg,
                                                   const float* __restrict__ pb2,
                                                   const float* __restrict__ featT, const int* __restrict__ idxb,
                                                   u16* __restrict__ X, u16* __restrict__ V, int row0) {
    __shared__ u16 As[128 * 64];
    __shared__ u16 Bs[128 * 64];
    const int t = threadIdx.x;
    u32 bmu, bnu;
    xcd_tiles(bmu, bnu);
    const int bm = (int)bmu, bn = (int)bnu;
    const int w = t >> 6, l = t & 63;
    const int wr = w >> 1, wc = w & 1;
    const int fr = l & 15, fq = l >> 4;
    f32x4 acc[4][4];
#pragma unroll
    for (int i = 0; i < 4; i++)
#pragma unroll
        for (int j = 0; j < 4; j++) {
            f32x4 z = {0.f, 0.f, 0.f, 0.f};
            acc[i][j] = z;
        }
    const char* Abase = (const char*)Hg + ((size_t)row0 + (size_t)bm * 128) * 64 * 2;
    const char* Bbase = (const char*)Bg + (size_t)bn * 128 * 64 * 2;
#pragma unroll
    for (int i = 0; i < 4; i++) {
        int chunk = i * 256 + t;
        int row = chunk >> 3;
        int cb = (chunk & 7) * 16;
        gload_lds16(Abase + (size_t)row * 128 + cb, (char*)As + chunk * 16);
    }
#pragma unroll
    for (int i = 0; i < 4; i++) {
        int chunk = i * 256 + t;
        int row = chunk >> 3;
        int cb = (chunk & 7) * 16;
        gload_lds16(Bbase + (size_t)row * 128 + cb, (char*)Bs + chunk * 16);
    }
    __syncthreads();
    bf16x8 af[4][2], bfv[4][2];
#pragma unroll
    for (int mf = 0; mf < 4; mf++)
#pragma unroll
        for (int ks = 0; ks < 2; ks++)
            af[mf][ks] = *(const bf16x8*)&As[(wr * 64 + mf * 16 + fr) * 64 + ks * 32 + fq * 8];
#pragma unroll
    for (int nf = 0; nf < 4; nf++)
#pragma unroll
        for (int ks = 0; ks < 2; ks++)
            bfv[nf][ks] = *(const bf16x8*)&Bs[(wc * 64 + nf * 16 + fr) * 64 + ks * 32 + fq * 8];
#pragma unroll
    for (int mf = 0; mf < 4; mf++)
#pragma unroll
        for (int nf = 0; nf < 4; nf++)
#pragma unroll
            for (int ks = 0; ks < 2; ks++)
                acc[mf][nf] = __builtin_amdgcn_mfma_f32_16x16x32_bf16(af[mf][ks], bfv[nf][ks], acc[mf][nf], 0, 0, 0);
    // epilogue: per C-row gather f,g; emit X,V
#pragma unroll
    for (int mf = 0; mf < 4; mf++) {
#pragma unroll
        for (int r = 0; r < 4; r++) {
            int gr = bm * 128 + wr * 64 + mf * 16 + fq * 4 + r;  // chunk-local row
            int grow = row0 + gr;                                 // global row
            int b = grow >> 15;
            int n = (grow >> 4) & (Nc - 1);
            int s = idxb[grow];
            const float* frow = featT + ((size_t)b * Sc + n) * Cc;
            const float* grow_p = featT + ((size_t)b * Sc + s) * Cc;
#pragma unroll
            for (int nf = 0; nf < 4; nf++) {
                int gn = bn * 128 + wc * 64 + nf * 16 + fr;
                float p = acc[mf][nf][r] + pb2[gn];
                float fv = frow[gn];
                float gv = grow_p[gn];
                X[(size_t)gr * Cc + gn] = f2bf(fv - gv + p);
                V[(size_t)gr * Cc + gn] = f2bf(gv + p);
            }
        }
    }
}

// ---------------------------------------------------------------------------
// GEMM (double-buffered + XCD swizzle): C[m][n] = f(sum_k A[m][k]*B[n][k]+b)
// A [M][Kd] bf16, B [N][Kd] bf16 (B^T layout), 128x128 tile, BK=64.
// ---------------------------------------------------------------------------
template <bool RELU, bool OBF16>
__global__ __launch_bounds__(256) void gemm_bt(const u16* __restrict__ Ag, const u16* __restrict__ Bg,
                                               const float* __restrict__ bias, void* __restrict__ Cg,
                                               int M, int N, int Kd) {
    __shared__ u16 smem[32768];  // 64 KB: buf0 {As 16K|Bs 16K} buf1 {As|Bs}
    const int t = threadIdx.x;
    u32 bmu, bnu;
    xcd_tiles(bmu, bnu);
    const int bm = (int)bmu, bn = (int)bnu;
    const int w = t >> 6, l = t & 63;
    const int wr = w >> 1, wc = w & 1;
    const int fr = l & 15, fq = l >> 4;
    f32x4 acc[4][4];
#pragma unroll
    for (int i = 0; i < 4; i++)
#pragma unroll
        for (int j = 0; j < 4; j++) {
            f32x4 z = {0.f, 0.f, 0.f, 0.f};
            acc[i][j] = z;
        }
    const char* Abase = (const char*)Ag + (size_t)bm * 128 * (size_t)Kd * 2;
    const char* Bbase = (const char*)Bg + (size_t)bn * 128 * (size_t)Kd * 2;
    const size_t ldb = (size_t)Kd * 2;

    auto stage = [&](int buf, int kt) {
        char* Ad = (char*)smem + (size_t)buf * 32768;
        char* Bd = Ad + 16384;
#pragma unroll
        for (int i = 0; i < 4; i++) {
            int chunk = i * 256 + t;
            int row = chunk >> 3;
            int cb = (chunk & 7) * 16;
            gload_lds16(Abase + (size_t)row * ldb + (size_t)kt * 2 + cb, Ad + chunk * 16);
        }
#pragma unroll
        for (int i = 0; i < 4; i++) {
            int chunk = i * 256 + t;
            int row = chunk >> 3;
            int cb = (chunk & 7) * 16;
            gload_lds16(Bbase + (size_t)row * ldb + (size_t)kt * 2 + cb, Bd + chunk * 16);
        }
    };

    const int nt = Kd / 64;
    stage(0, 0);
    int cur = 0;
    for (int it = 0; it < nt; ++it) {
        __syncthreads();
        if (it + 1 < nt) stage(cur ^ 1, (it + 1) * 64);
        const u16* As = smem + (size_t)cur * 16384;
        const u16* Bs = As + 8192;
        bf16x8 af[4][2], bfv[4][2];
#pragma unroll
        for (int mf = 0; mf < 4; mf++)
#pragma unroll
            for (int ks = 0; ks < 2; ks++)
                af[mf][ks] = *(const bf16x8*)&As[(wr * 64 + mf * 16 + fr) * 64 + ks * 32 + fq * 8];
#pragma unroll
        for (int nf = 0; nf < 4; nf++)
#pragma unroll
            for (int ks = 0; ks < 2; ks++)
                bfv[nf][ks] = *(const bf16x8*)&Bs[(wc * 64 + nf * 16 + fr) * 64 + ks * 32 + fq * 8];
#pragma unroll
        for (int mf = 0; mf < 4; mf++)
#pragma unroll
            for (int nf = 0; nf < 4; nf++)
#pragma unroll
                for (int ks = 0; ks < 2; ks++)
                    acc[mf][nf] = __builtin_amdgcn_mfma_f32_16x16x32_bf16(af[mf][ks], bfv[nf][ks], acc[mf][nf], 0, 0, 0);
        cur ^= 1;
    }
#pragma unroll
    for (int mf = 0; mf < 4; mf++) {
#pragma unroll
        for (int nf = 0; nf < 4; nf++) {
            int gn = bn * 128 + wc * 64 + nf * 16 + fr;
            float bi = bias[gn];
            int gm0 = bm * 128 + wr * 64 + mf * 16 + fq * 4;
#pragma unroll
            for (int r = 0; r < 4; r++) {
                float v = acc[mf][nf][r] + bi;
                if (RELU) v = fmaxf(v, 0.f);
                size_t o = (size_t)(gm0 + r) * N + gn;
                if (OBF16) ((u16*)Cg)[o] = f2bf(v);
                else ((float*)Cg)[o] = v;
            }
        }
    }
}

// ---------------------------------------------------------------------------
// GEMM2_FUSED (4-deep counted-vmcnt pipeline, BK=32): L = A @ W2^T + ab2
// (M=rows, N=512, K=1024) with softmax-over-k + weighted-V reduce fused.
// 4 x 16KB buffers; 3 stages in flight; before reading buf[it] only the
// oldest stage must retire -> s_waitcnt vmcnt(8) (AITER never-drain pattern),
// raw s_barrier. Re-stage target (it+3)&3 == (it-1)&3, re-used only after
// the barrier all waves reach post-read. K-order unchanged -> bit-identical.
// ---------------------------------------------------------------------------
__global__ __launch_bounds__(256) void gemm2_fused(const u16* __restrict__ Ag, const u16* __restrict__ Bg,
                                                   const float* __restrict__ bias, const u16* __restrict__ Vb,
                                                   float* __restrict__ out, int row0, int Kd) {
    __shared__ u16 smem[32768];  // 64 KB: 4 bufs x {As 8K | Bs 8K}; V tile (32 KB) reuses bufs 0-1
    const int t = threadIdx.x;
    u32 bmu, bnu;
    xcd_tiles(bmu, bnu);
    const int bm = (int)bmu, bn = (int)bnu;
    const int w = t >> 6, l = t & 63;
    const int wr = w >> 1, wc = w & 1;
    const int fr = l & 15, fq = l >> 4;
    f32x4 acc[4][4];
#pragma unroll
    for (int i = 0; i < 4; i++)
#pragma unroll
        for (int j = 0; j < 4; j++) {
            f32x4 z = {0.f, 0.f, 0.f, 0.f};
            acc[i][j] = z;
        }
    const char* Abase = (const char*)Ag + (size_t)bm * 128 * (size_t)Kd * 2;
    const char* Bbase = (const char*)Bg + (size_t)bn * 128 * (size_t)Kd * 2;
    const size_t ldb = (size_t)Kd * 2;

    // stage one BK=32 tile (As 128x32 + Bs 128x32, 8KB each): 4 loads/thread
    auto stage = [&](int buf, int kt) {
        char* Ad = (char*)smem + (size_t)buf * 16384;
        char* Bd = Ad + 8192;
#pragma unroll
        for (int i = 0; i < 2; i++) {
            int chunk = i * 256 + t;       // 0..511: row = chunk>>2 (64B rows), cb = (chunk&3)*16
            int row = chunk >> 2;
            int cb = (chunk & 3) * 16;
            gload_lds16(Abase + (size_t)row * ldb + (size_t)kt * 2 + cb, Ad + chunk * 16);
        }
#pragma unroll
        for (int i = 0; i < 2; i++) {
            int chunk = i * 256 + t;
            int row = chunk >> 2;
            int cb = (chunk & 3) * 16;
            gload_lds16(Bbase + (size_t)row * ldb + (size_t)kt * 2 + cb, Bd + chunk * 16);
        }
    };

    const int nt = Kd / 32;   // 32
    stage(0, 0);
    stage(1, 32);
    stage(2, 64);
    for (int it = 0; it < nt; ++it) {
        // retire oldest stage (4 loads); keep 2 newer stages (8 loads) in flight
        if (it < nt - 2)      asm volatile("s_waitcnt vmcnt(8)" ::: "memory");
        else if (it == nt - 2) asm volatile("s_waitcnt vmcnt(4)" ::: "memory");
        else                   asm volatile("s_waitcnt vmcnt(0)" ::: "memory");
        __builtin_amdgcn_sched_barrier(0);
        __builtin_amdgcn_s_barrier();
        if (it + 3 < nt) stage((it + 3) & 3, (it + 3) * 32);  // target buf was read in iter it-1
        const u16* As = smem + (size_t)(it & 3) * 8192;
        const u16* Bs = As + 4096;
        bf16x8 af[4], bfv[4];
#pragma unroll
        for (int mf = 0; mf < 4; mf++)
            af[mf] = *(const bf16x8*)&As[(wr * 64 + mf * 16 + fr) * 32 + fq * 8];
#pragma unroll
        for (int nf = 0; nf < 4; nf++)
            bfv[nf] = *(const bf16x8*)&Bs[(wc * 64 + nf * 16 + fr) * 32 + fq * 8];
#pragma unroll
        for (int mf = 0; mf < 4; mf++)
#pragma unroll
            for (int nf = 0; nf < 4; nf++)
                acc[mf][nf] = __builtin_amdgcn_mfma_f32_16x16x32_bf16(af[mf], bfv[nf], acc[mf][nf], 0, 0, 0);
    }
    __builtin_amdgcn_s_barrier();   // all waves done reading last buf before V-stage overwrites
    // stage V tile [bm*128 .. +128)[bn*128 .. +128) into bufs 0-1 (coalesced)
    const char* Vbase = (const char*)Vb + (size_t)bm * 128 * Cc * 2 + (size_t)bn * 256;
#pragma unroll
    for (int i = 0; i < 8; i++) {
        int chunk = i * 256 + t;       // 0..2047
        int row = chunk >> 4;          // 0..127
        int cb = (chunk & 15) * 16;    // byte offset in row (256B rows)
        gload_lds16(Vbase + (size_t)row * (Cc * 2) + cb, (char*)smem + chunk * 16);
    }
    __syncthreads();
    // fused epilogue: per (point, channel) softmax over k=fq*4+r + V-reduce
#pragma unroll
    for (int mf = 0; mf < 4; mf++) {
        int lp = bm * 8 + wr * 4 + mf;        // chunk-local point
        int gp = row0 / 16 + lp;              // global point
        int bb = gp >> 11, nn = gp & (Nc - 1);
        int vrow = (wr * 4 + mf) * 16 + fq * 4;  // tile-local V row for r=0
#pragma unroll
        for (int nf = 0; nf < 4; nf++) {
            int gn = bn * 128 + wc * 64 + nf * 16 + fr;
            int vch = wc * 64 + nf * 16 + fr;
            float bi = bias[gn];
            float v0 = acc[mf][nf][0] + bi, v1 = acc[mf][nf][1] + bi;
            float v2 = acc[mf][nf][2] + bi, v3 = acc[mf][nf][3] + bi;
            float mx = fmaxf(fmaxf(v0, v1), fmaxf(v2, v3));
            mx = fmaxf(mx, __shfl_xor(mx, 16));
            mx = fmaxf(mx, __shfl_xor(mx, 32));
            float e0 = __expf(v0 - mx), e1 = __expf(v1 - mx);
            float e2 = __expf(v2 - mx), e3 = __expf(v3 - mx);
            float ws = e0 * bf2f(smem[(size_t)vrow * 128 + vch])
                     + e1 * bf2f(smem[(size_t)(vrow + 1) * 128 + vch])
                     + e2 * bf2f(smem[(size_t)(vrow + 2) * 128 + vch])
                     + e3 * bf2f(smem[(size_t)(vrow + 3) * 128 + vch]);
            float es = e0 + e1 + e2 + e3;
            ws += __shfl_xor(ws, 16); ws += __shfl_xor(ws, 32);
            es += __shfl_xor(es, 16); es += __shfl_xor(es, 32);
            if (fq == 0) out[((size_t)bb * Cc + gn) * Nc + nn] = ws / es;
        }
    }
}

// ---------------------------------------------------------------------------
extern "C" void kernel_launch(void* const* d_in, const int* in_sizes, int n_in,
                              void* d_out, int out_size, void* d_ws, size_t ws_size,
                              hipStream_t stream) {
    (void)in_sizes; (void)n_in; (void)out_size;
    const float* pcd     = (const float*)d_in[0];
    const float* feat    = (const float*)d_in[1];
    const float* pcd_db  = (const float*)d_in[2];
    const float* feat_db = (const float*)d_in[3];
    const float* pw1 = (const float*)d_in[4];
    const float* pb1 = (const float*)d_in[5];
    const float* pg  = (const float*)d_in[6];
    const float* pbb = (const float*)d_in[7];
    const float* pm  = (const float*)d_in[8];
    const float* pv  = (const float*)d_in[9];
    const float* pw2 = (const float*)d_in[10];
    const float* pb2 = (const float*)d_in[11];
    const float* aw1 = (const float*)d_in[12];
    const float* ab1 = (const float*)d_in[13];
    const float* ag  = (const float*)d_in[14];
    const float* abb = (const float*)d_in[15];
    const float* am  = (const float*)d_in[16];
    const float* av  = (const float*)d_in[17];
    const float* aw2 = (const float*)d_in[18];
    const float* ab2 = (const float*)d_in[19];
    float* out = (float*)d_out;

    char* base = (char*)d_ws;
    size_t off = 0;
    auto alloc = [&](size_t bytes) -> char* {
        char* r = base + off;
        off = (off + bytes + 255) & ~(size_t)255;
        return r;
    };
    int*   idxb  = (int*)alloc((size_t)RT * 4);
    float* featT = (float*)alloc((size_t)Bc * Sc * Cc * 4);
    u16*   W1b   = (u16*)alloc((size_t)AH * Cc * 2);
    float* bias1 = (float*)alloc((size_t)AH * 4);
    u16*   W2b   = (u16*)alloc((size_t)Cc * AH * 2);
    u16*   PW2b  = (u16*)alloc((size_t)Cc * PH * 2);
    u16*   Hb    = (u16*)alloc((size_t)RT * PH * 2);

    // chunked row pipeline: cr=32768 is the measured optimum (r14/r17: 338 us).
    const size_t perrow = 1024 + 1024 + 2048;  // X,V bf16 + A bf16
    int cr = 32768;
    size_t avail = ws_size > off ? ws_size - off : 0;
    if (avail < (size_t)cr * perrow) {
        cr = (int)((avail / perrow) & ~(size_t)127);
        if (cr < 128) cr = 128;
    }
    u16*   Xb = (u16*)alloc((size_t)cr * Cc * 2);
    u16*   Vb = (u16*)alloc((size_t)cr * Cc * 2);
    u16*   Ab = (u16*)alloc((size_t)cr * AH * 2);

    transpose_kernel<<<dim3(Bc * 40 * 8), dim3(256), 0, stream>>>(feat, feat_db, featT);
    prep_kernel<<<dim3((AH * Cc) / 256), dim3(256), 0, stream>>>(aw1, ab1, ag, abb, am, av, aw2, pw2,
                                                                 W1b, bias1, W2b, PW2b);
    knn_kernel<<<dim3(Bc * Nc / 4), dim3(256), 0, stream>>>(pcd, pcd_db, idxb);
    hker<<<dim3(RT / 256), dim3(256), 0, stream>>>(pcd, pcd_db, idxb, pw1, pb1, pg, pbb, pm, pv, Hb);

    for (int r0 = 0; r0 < RT; r0 += cr) {
        int rows = (RT - r0 < cr) ? (RT - r0) : cr;
        pgemm_fused<<<dim3(rows / 128, Cc / 128), dim3(256), 0, stream>>>(Hb, PW2b, pb2, featT, idxb,
                                                                          Xb, Vb, r0);
        gemm_bt<true, true><<<dim3(rows / 128, AH / 128), dim3(256), 0, stream>>>(Xb, W1b, bias1, Ab, rows, AH, Cc);
        gemm2_fused<<<dim3(rows / 128, Cc / 128), dim3(256), 0, stream>>>(Ab, W2b, ab2, Vb, out, r0, AH);
    }
}

// Round 23
// 296.311 us; speedup vs baseline: 1.2914x; 1.0081x over previous
//
#include <hip/hip_runtime.h>

typedef unsigned short u16;
typedef unsigned int   u32;
typedef __attribute__((ext_vector_type(8))) short bf16x8;
typedef __attribute__((ext_vector_type(4))) float f32x4;
typedef __attribute__((ext_vector_type(4))) u32   u32x4;

// Problem constants
constexpr int Bc = 2, Cc = 512, Nc = 2048, Mc = 512, Sc = 2560, Kc = 16, PH = 64, AH = 1024;
constexpr int RT = Bc * Nc * Kc;  // 65536 rows (b,n,k)
constexpr float EPS = 1e-5f;

__device__ __forceinline__ u16 f2bf(float f) {
    u32 u = __float_as_uint(f);
    u32 r = (u + 0x7fffu + ((u >> 16) & 1u)) >> 16;  // RNE
    return (u16)r;
}
__device__ __forceinline__ float bf2f(u16 h) { return __uint_as_float(((u32)h) << 16); }

__device__ __forceinline__ void gload_lds16(const void* g, void* l) {
    __builtin_amdgcn_global_load_lds((const __attribute__((address_space(1))) u32*)g,
                                     (__attribute__((address_space(3))) u32*)l, 16, 0, 0);
}

// Bijective XCD-aware workgroup swizzle (m204 form): same-XCD wgs get a
// contiguous run of linear ids. With bn-fastest linearization this makes an
// XCD reuse one A-panel across all bn tiles (L2 locality).
__device__ __forceinline__ void xcd_tiles(u32& bm, u32& bn) {
    u32 gdx = gridDim.x, gdy = gridDim.y;
    u32 nwg = gdx * gdy;
    u32 wg = blockIdx.x + gdx * blockIdx.y;
    u32 q = nwg >> 3, r8 = nwg & 7;
    u32 xcd = wg & 7, loc = wg >> 3;
    u32 swz = (xcd < r8 ? xcd * (q + 1) : r8 * (q + 1) + (xcd - r8) * q) + loc;
    bn = swz % gdy;   // bn fastest within an XCD's contiguous run
    bm = swz / gdy;
}

// lex-min on (d, s): total order, associative -> tree order == scan order
__device__ __forceinline__ void lmin(float& da, int& sa, float db, int sb) {
    bool better = (db < da) || (db == da && sb < sa);
    da = better ? db : da;
    sa = better ? sb : sa;
}

// ---------------------------------------------------------------------------
// Transpose fusion_feat [B,C,S(split)] f32 -> featT [B,S,C] f32
// ---------------------------------------------------------------------------
__global__ __launch_bounds__(256) void transpose_kernel(const float* __restrict__ feat,
                                                        const float* __restrict__ feat_db,
                                                        float* __restrict__ featT) {
    __shared__ float tile[64][65];
    int bid = blockIdx.x;
    int b = bid / (40 * 8);
    int rem = bid - b * (40 * 8);
    int st = rem >> 3, ct = rem & 7;
    int t = threadIdx.x, lane = t & 63, g = t >> 6;
    int s0 = st * 64, c0 = ct * 64;
    const float* src;
    int sl0, stride;
    if (s0 < Nc) { src = feat + (size_t)b * Cc * Nc; sl0 = s0; stride = Nc; }
    else         { src = feat_db + (size_t)b * Cc * Mc; sl0 = s0 - Nc; stride = Mc; }
#pragma unroll
    for (int i = 0; i < 16; i++) {
        int cl = g * 16 + i;
        tile[cl][lane] = src[(size_t)(c0 + cl) * stride + sl0 + lane];
    }
    __syncthreads();
#pragma unroll
    for (int i = 0; i < 16; i++) {
        int sl = g * 16 + i;
        featT[((size_t)b * Sc + s0 + sl) * Cc + c0 + lane] = tile[lane][sl];
    }
}

// ---------------------------------------------------------------------------
// Weight prep: fold attn BN into W1/bias1, cast attn W1/W2 + pos W2 to bf16
// ---------------------------------------------------------------------------
__global__ __launch_bounds__(256) void prep_kernel(const float* __restrict__ aw1, const float* __restrict__ ab1,
                                                   const float* __restrict__ ag, const float* __restrict__ abb,
                                                   const float* __restrict__ am, const float* __restrict__ av,
                                                   const float* __restrict__ aw2, const float* __restrict__ pw2,
                                                   u16* __restrict__ W1b, float* __restrict__ bias1,
                                                   u16* __restrict__ W2b, u16* __restrict__ PW2b) {
    int i = blockIdx.x * 256 + threadIdx.x;  // grid covers 524288
    if (i < AH * Cc) {
        int o = i >> 9;
        float inv = ag[o] / sqrtf(av[o] + EPS);
        W1b[i] = f2bf(aw1[i] * inv);
    }
    if (i < AH) {
        float inv = ag[i] / sqrtf(av[i] + EPS);
        bias1[i] = ab1[i] * inv + abb[i] - am[i] * inv;
    }
    if (i < Cc * AH) W2b[i] = f2bf(aw2[i]);
    if (i < Cc * PH) PW2b[i] = f2bf(pw2[i]);
}

// ---------------------------------------------------------------------------
// KNN (v1 + tree-scan): one wave per query; distances mirror the reference
// decomposition qq + ss - 2*dot, no fma contraction; ties -> smaller index.
// ---------------------------------------------------------------------------
__global__ __launch_bounds__(256) void knn_kernel(const float* __restrict__ pcd,
                                                  const float* __restrict__ pcd_db,
                                                  int* __restrict__ idxout) {
    int t = threadIdx.x, w = t >> 6, l = t & 63;
    int q = blockIdx.x * 4 + w;  // 0..4095
    int b = q >> 11, n = q & (Nc - 1);
    const float* pc = pcd + (size_t)b * 3 * Nc;
    const float* pd = pcd_db + (size_t)b * 3 * Mc;
    float qx = pc[n], qy = pc[Nc + n], qz = pc[2 * Nc + n];
    float qq = __fadd_rn(__fadd_rn(__fmul_rn(qx, qx), __fmul_rn(qy, qy)), __fmul_rn(qz, qz));
    float dist[40];
#pragma unroll
    for (int j = 0; j < 40; j++) {
        int s = j * 64 + l;
        float sx, sy, sz;
        if (s < Nc) { sx = pc[s]; sy = pc[Nc + s]; sz = pc[2 * Nc + s]; }
        else { int ss = s - Nc; sx = pd[ss]; sy = pd[Mc + ss]; sz = pd[2 * Mc + ss]; }
        float ss2 = __fadd_rn(__fadd_rn(__fmul_rn(sx, sx), __fmul_rn(sy, sy)), __fmul_rn(sz, sz));
        float dt  = __fadd_rn(__fadd_rn(__fmul_rn(qx, sx), __fmul_rn(qy, sy)), __fmul_rn(qz, sz));
        dist[j] = __fsub_rn(__fadd_rn(qq, ss2), __fmul_rn(2.0f, dt));
    }
    for (int r = 0; r < 16; r++) {
        // tree lex-min over the 40 (dist[j], j*64+l) pairs
        float td[20];
        int   ts[20];
#pragma unroll
        for (int i = 0; i < 20; i++) {
            float d0 = dist[2 * i], d1 = dist[2 * i + 1];
            int s0 = (2 * i) * 64 + l, s1 = (2 * i + 1) * 64 + l;
            bool bt = (d1 < d0) || (d1 == d0 && s1 < s0);
            td[i] = bt ? d1 : d0;
            ts[i] = bt ? s1 : s0;
        }
#pragma unroll
        for (int i = 0; i < 10; i++) lmin(td[i], ts[i], td[i + 10], ts[i + 10]);
#pragma unroll
        for (int i = 0; i < 5; i++) lmin(td[i], ts[i], td[i + 5], ts[i + 5]);
        lmin(td[0], ts[0], td[3], ts[3]);
        lmin(td[1], ts[1], td[4], ts[4]);
        lmin(td[0], ts[0], td[2], ts[2]);
        lmin(td[0], ts[0], td[1], ts[1]);
        float bd = td[0];
        int   bs = ts[0];
        for (int off = 32; off; off >>= 1) {
            float od = __shfl_xor(bd, off);
            int   os = __shfl_xor(bs, off);
            bool better = (od < bd) || (od == bd && os < bs);
            bd = better ? od : bd;
            bs = better ? os : bs;
        }
        if (l == 0) idxout[q * 16 + r] = bs;
        int wj = bs >> 6, wl = bs & 63;
        if (l == wl) {
#pragma unroll
            for (int j = 0; j < 40; j++)
                if (j == wj) dist[j] = 1e30f;
        }
    }
}

// ---------------------------------------------------------------------------
// HKER: per row, pos-MLP layer-1: h[r][64] = relu(BN(W1 (q - s) + b1)) bf16
// ---------------------------------------------------------------------------
__global__ __launch_bounds__(256) void hker(const float* __restrict__ pcd, const float* __restrict__ pcd_db,
                                            const int* __restrict__ idxb,
                                            const float* __restrict__ pw1, const float* __restrict__ pb1,
                                            const float* __restrict__ pg, const float* __restrict__ pbb,
                                            const float* __restrict__ pm, const float* __restrict__ pv,
                                            u16* __restrict__ H) {
    __shared__ float W1s[64][4];
    int t = threadIdx.x;
    if (t < 64) {
        float inv = pg[t] / sqrtf(pv[t] + EPS);
        W1s[t][0] = pw1[t * 3 + 0] * inv;
        W1s[t][1] = pw1[t * 3 + 1] * inv;
        W1s[t][2] = pw1[t * 3 + 2] * inv;
        W1s[t][3] = pb1[t] * inv + pbb[t] - pm[t] * inv;
    }
    __syncthreads();
    int r = blockIdx.x * 256 + t;
    int b = r >> 15, n = (r >> 4) & (Nc - 1), s = idxb[r];
    const float* pc = pcd + (size_t)b * 3 * Nc;
    float qx = pc[n], qy = pc[Nc + n], qz = pc[2 * Nc + n];
    float sx, sy, sz;
    if (s < Nc) { sx = pc[s]; sy = pc[Nc + s]; sz = pc[2 * Nc + s]; }
    else {
        const float* pd = pcd_db + (size_t)b * 3 * Mc;
        int ss = s - Nc;
        sx = pd[ss]; sy = pd[Mc + ss]; sz = pd[2 * Mc + ss];
    }
    float dx = qx - sx, dy = qy - sy, dz = qz - sz;
    u16* hp = H + (size_t)r * 64;
#pragma unroll
    for (int u0 = 0; u0 < 64; u0 += 8) {
        u16 e[8];
#pragma unroll
        for (int j = 0; j < 8; j++) {
            int u = u0 + j;
            float hv = fmaxf(0.f, dx * W1s[u][0] + dy * W1s[u][1] + dz * W1s[u][2] + W1s[u][3]);
            e[j] = f2bf(hv);
        }
        u32x4 pk;
        pk.x = (u32)e[0] | ((u32)e[1] << 16); pk.y = (u32)e[2] | ((u32)e[3] << 16);
        pk.z = (u32)e[4] | ((u32)e[5] << 16); pk.w = (u32)e[6] | ((u32)e[7] << 16);
        *(u32x4*)(hp + u0) = pk;
    }
}

// ---------------------------------------------------------------------------
// PGEMM_FUSED: P = H @ PW2^T + pb2 via MFMA (M=rows, N=512, K=64), epilogue
// gathers f,g from featT and emits X = f-g+p, V = g+p (bf16).
// ---------------------------------------------------------------------------
__global__ __launch_bounds__(256) void pgemm_fused(const u16* __restrict__ Hg, const u16* __restrict__ Bg,
                                                   const float* __restrict__ pb2,
                                                   const float* __restrict__ featT, const int* __restrict__ idxb,
                                                   u16* __restrict__ X, u16* __restrict__ V, int row0) {
    __shared__ u16 As[128 * 64];
    __shared__ u16 Bs[128 * 64];
    const int t = threadIdx.x;
    u32 bmu, bnu;
    xcd_tiles(bmu, bnu);
    const int bm = (int)bmu, bn = (int)bnu;
    const int w = t >> 6, l = t & 63;
    const int wr = w >> 1, wc = w & 1;
    const int fr = l & 15, fq = l >> 4;
    f32x4 acc[4][4];
#pragma unroll
    for (int i = 0; i < 4; i++)
#pragma unroll
        for (int j = 0; j < 4; j++) {
            f32x4 z = {0.f, 0.f, 0.f, 0.f};
            acc[i][j] = z;
        }
    const char* Abase = (const char*)Hg + ((size_t)row0 + (size_t)bm * 128) * 64 * 2;
    const char* Bbase = (const char*)Bg + (size_t)bn * 128 * 64 * 2;
#pragma unroll
    for (int i = 0; i < 4; i++) {
        int chunk = i * 256 + t;
        int row = chunk >> 3;
        int cb = (chunk & 7) * 16;
        gload_lds16(Abase + (size_t)row * 128 + cb, (char*)As + chunk * 16);
    }
#pragma unroll
    for (int i = 0; i < 4; i++) {
        int chunk = i * 256 + t;
        int row = chunk >> 3;
        int cb = (chunk & 7) * 16;
        gload_lds16(Bbase + (size_t)row * 128 + cb, (char*)Bs + chunk * 16);
    }
    __syncthreads();
    bf16x8 af[4][2], bfv[4][2];
#pragma unroll
    for (int mf = 0; mf < 4; mf++)
#pragma unroll
        for (int ks = 0; ks < 2; ks++)
            af[mf][ks] = *(const bf16x8*)&As[(wr * 64 + mf * 16 + fr) * 64 + ks * 32 + fq * 8];
#pragma unroll
    for (int nf = 0; nf < 4; nf++)
#pragma unroll
        for (int ks = 0; ks < 2; ks++)
            bfv[nf][ks] = *(const bf16x8*)&Bs[(wc * 64 + nf * 16 + fr) * 64 + ks * 32 + fq * 8];
#pragma unroll
    for (int mf = 0; mf < 4; mf++)
#pragma unroll
        for (int nf = 0; nf < 4; nf++)
#pragma unroll
            for (int ks = 0; ks < 2; ks++)
                acc[mf][nf] = __builtin_amdgcn_mfma_f32_16x16x32_bf16(af[mf][ks], bfv[nf][ks], acc[mf][nf], 0, 0, 0);
    // epilogue: per C-row gather f,g; emit X,V
#pragma unroll
    for (int mf = 0; mf < 4; mf++) {
#pragma unroll
        for (int r = 0; r < 4; r++) {
            int gr = bm * 128 + wr * 64 + mf * 16 + fq * 4 + r;  // chunk-local row
            int grow = row0 + gr;                                 // global row
            int b = grow >> 15;
            int n = (grow >> 4) & (Nc - 1);
            int s = idxb[grow];
            const float* frow = featT + ((size_t)b * Sc + n) * Cc;
            const float* grow_p = featT + ((size_t)b * Sc + s) * Cc;
#pragma unroll
            for (int nf = 0; nf < 4; nf++) {
                int gn = bn * 128 + wc * 64 + nf * 16 + fr;
                float p = acc[mf][nf][r] + pb2[gn];
                float fv = frow[gn];
                float gv = grow_p[gn];
                X[(size_t)gr * Cc + gn] = f2bf(fv - gv + p);
                V[(size_t)gr * Cc + gn] = f2bf(gv + p);
            }
        }
    }
}

// ---------------------------------------------------------------------------
// GEMM (4-deep counted-vmcnt pipeline, BK=32, + XCD swizzle):
// C[m][n] = f(sum_k A[m][k]*B[n][k]+b). A [M][Kd], B [N][Kd] bf16 (B^T).
// Same never-drain pattern proven on gemm2 in r22. K-order unchanged ->
// bit-identical results.
// ---------------------------------------------------------------------------
template <bool RELU, bool OBF16>
__global__ __launch_bounds__(256) void gemm_bt(const u16* __restrict__ Ag, const u16* __restrict__ Bg,
                                               const float* __restrict__ bias, void* __restrict__ Cg,
                                               int M, int N, int Kd) {
    __shared__ u16 smem[32768];  // 64 KB: 4 bufs x {As 8K | Bs 8K}
    const int t = threadIdx.x;
    u32 bmu, bnu;
    xcd_tiles(bmu, bnu);
    const int bm = (int)bmu, bn = (int)bnu;
    const int w = t >> 6, l = t & 63;
    const int wr = w >> 1, wc = w & 1;
    const int fr = l & 15, fq = l >> 4;
    f32x4 acc[4][4];
#pragma unroll
    for (int i = 0; i < 4; i++)
#pragma unroll
        for (int j = 0; j < 4; j++) {
            f32x4 z = {0.f, 0.f, 0.f, 0.f};
            acc[i][j] = z;
        }
    const char* Abase = (const char*)Ag + (size_t)bm * 128 * (size_t)Kd * 2;
    const char* Bbase = (const char*)Bg + (size_t)bn * 128 * (size_t)Kd * 2;
    const size_t ldb = (size_t)Kd * 2;

    auto stage = [&](int buf, int kt) {
        char* Ad = (char*)smem + (size_t)buf * 16384;
        char* Bd = Ad + 8192;
#pragma unroll
        for (int i = 0; i < 2; i++) {
            int chunk = i * 256 + t;
            int row = chunk >> 2;
            int cb = (chunk & 3) * 16;
            gload_lds16(Abase + (size_t)row * ldb + (size_t)kt * 2 + cb, Ad + chunk * 16);
        }
#pragma unroll
        for (int i = 0; i < 2; i++) {
            int chunk = i * 256 + t;
            int row = chunk >> 2;
            int cb = (chunk & 3) * 16;
            gload_lds16(Bbase + (size_t)row * ldb + (size_t)kt * 2 + cb, Bd + chunk * 16);
        }
    };

    const int nt = Kd / 32;   // 16 for gemm1
    stage(0, 0);
    stage(1, 32);
    stage(2, 64);
    for (int it = 0; it < nt; ++it) {
        if (it < nt - 2)      asm volatile("s_waitcnt vmcnt(8)" ::: "memory");
        else if (it == nt - 2) asm volatile("s_waitcnt vmcnt(4)" ::: "memory");
        else                   asm volatile("s_waitcnt vmcnt(0)" ::: "memory");
        __builtin_amdgcn_sched_barrier(0);
        __builtin_amdgcn_s_barrier();
        if (it + 3 < nt) stage((it + 3) & 3, (it + 3) * 32);
        const u16* As = smem + (size_t)(it & 3) * 8192;
        const u16* Bs = As + 4096;
        bf16x8 af[4], bfv[4];
#pragma unroll
        for (int mf = 0; mf < 4; mf++)
            af[mf] = *(const bf16x8*)&As[(wr * 64 + mf * 16 + fr) * 32 + fq * 8];
#pragma unroll
        for (int nf = 0; nf < 4; nf++)
            bfv[nf] = *(const bf16x8*)&Bs[(wc * 64 + nf * 16 + fr) * 32 + fq * 8];
#pragma unroll
        for (int mf = 0; mf < 4; mf++)
#pragma unroll
            for (int nf = 0; nf < 4; nf++)
                acc[mf][nf] = __builtin_amdgcn_mfma_f32_16x16x32_bf16(af[mf], bfv[nf], acc[mf][nf], 0, 0, 0);
    }
#pragma unroll
    for (int mf = 0; mf < 4; mf++) {
#pragma unroll
        for (int nf = 0; nf < 4; nf++) {
            int gn = bn * 128 + wc * 64 + nf * 16 + fr;
            float bi = bias[gn];
            int gm0 = bm * 128 + wr * 64 + mf * 16 + fq * 4;
#pragma unroll
            for (int r = 0; r < 4; r++) {
                float v = acc[mf][nf][r] + bi;
                if (RELU) v = fmaxf(v, 0.f);
                size_t o = (size_t)(gm0 + r) * N + gn;
                if (OBF16) ((u16*)Cg)[o] = f2bf(v);
                else ((float*)Cg)[o] = v;
            }
        }
    }
}

// ---------------------------------------------------------------------------
// GEMM2_FUSED (4-deep counted-vmcnt pipeline, BK=32): L = A @ W2^T + ab2
// (M=rows, N=512, K=1024) with softmax-over-k + weighted-V reduce fused.
// ---------------------------------------------------------------------------
__global__ __launch_bounds__(256) void gemm2_fused(const u16* __restrict__ Ag, const u16* __restrict__ Bg,
                                                   const float* __restrict__ bias, const u16* __restrict__ Vb,
                                                   float* __restrict__ out, int row0, int Kd) {
    __shared__ u16 smem[32768];  // 64 KB: 4 bufs x {As 8K | Bs 8K}; V tile (32 KB) reuses bufs 0-1
    const int t = threadIdx.x;
    u32 bmu, bnu;
    xcd_tiles(bmu, bnu);
    const int bm = (int)bmu, bn = (int)bnu;
    const int w = t >> 6, l = t & 63;
    const int wr = w >> 1, wc = w & 1;
    const int fr = l & 15, fq = l >> 4;
    f32x4 acc[4][4];
#pragma unroll
    for (int i = 0; i < 4; i++)
#pragma unroll
        for (int j = 0; j < 4; j++) {
            f32x4 z = {0.f, 0.f, 0.f, 0.f};
            acc[i][j] = z;
        }
    const char* Abase = (const char*)Ag + (size_t)bm * 128 * (size_t)Kd * 2;
    const char* Bbase = (const char*)Bg + (size_t)bn * 128 * (size_t)Kd * 2;
    const size_t ldb = (size_t)Kd * 2;

    auto stage = [&](int buf, int kt) {
        char* Ad = (char*)smem + (size_t)buf * 16384;
        char* Bd = Ad + 8192;
#pragma unroll
        for (int i = 0; i < 2; i++) {
            int chunk = i * 256 + t;
            int row = chunk >> 2;
            int cb = (chunk & 3) * 16;
            gload_lds16(Abase + (size_t)row * ldb + (size_t)kt * 2 + cb, Ad + chunk * 16);
        }
#pragma unroll
        for (int i = 0; i < 2; i++) {
            int chunk = i * 256 + t;
            int row = chunk >> 2;
            int cb = (chunk & 3) * 16;
            gload_lds16(Bbase + (size_t)row * ldb + (size_t)kt * 2 + cb, Bd + chunk * 16);
        }
    };

    const int nt = Kd / 32;   // 32
    stage(0, 0);
    stage(1, 32);
    stage(2, 64);
    for (int it = 0; it < nt; ++it) {
        if (it < nt - 2)      asm volatile("s_waitcnt vmcnt(8)" ::: "memory");
        else if (it == nt - 2) asm volatile("s_waitcnt vmcnt(4)" ::: "memory");
        else                   asm volatile("s_waitcnt vmcnt(0)" ::: "memory");
        __builtin_amdgcn_sched_barrier(0);
        __builtin_amdgcn_s_barrier();
        if (it + 3 < nt) stage((it + 3) & 3, (it + 3) * 32);
        const u16* As = smem + (size_t)(it & 3) * 8192;
        const u16* Bs = As + 4096;
        bf16x8 af[4], bfv[4];
#pragma unroll
        for (int mf = 0; mf < 4; mf++)
            af[mf] = *(const bf16x8*)&As[(wr * 64 + mf * 16 + fr) * 32 + fq * 8];
#pragma unroll
        for (int nf = 0; nf < 4; nf++)
            bfv[nf] = *(const bf16x8*)&Bs[(wc * 64 + nf * 16 + fr) * 32 + fq * 8];
#pragma unroll
        for (int mf = 0; mf < 4; mf++)
#pragma unroll
            for (int nf = 0; nf < 4; nf++)
                acc[mf][nf] = __builtin_amdgcn_mfma_f32_16x16x32_bf16(af[mf], bfv[nf], acc[mf][nf], 0, 0, 0);
    }
    __builtin_amdgcn_s_barrier();   // all waves done reading last buf before V-stage overwrites
    // stage V tile [bm*128 .. +128)[bn*128 .. +128) into bufs 0-1 (coalesced)
    const char* Vbase = (const char*)Vb + (size_t)bm * 128 * Cc * 2 + (size_t)bn * 256;
#pragma unroll
    for (int i = 0; i < 8; i++) {
        int chunk = i * 256 + t;       // 0..2047
        int row = chunk >> 4;          // 0..127
        int cb = (chunk & 15) * 16;    // byte offset in row (256B rows)
        gload_lds16(Vbase + (size_t)row * (Cc * 2) + cb, (char*)smem + chunk * 16);
    }
    __syncthreads();
    // fused epilogue: per (point, channel) softmax over k=fq*4+r + V-reduce
#pragma unroll
    for (int mf = 0; mf < 4; mf++) {
        int lp = bm * 8 + wr * 4 + mf;        // chunk-local point
        int gp = row0 / 16 + lp;              // global point
        int bb = gp >> 11, nn = gp & (Nc - 1);
        int vrow = (wr * 4 + mf) * 16 + fq * 4;  // tile-local V row for r=0
#pragma unroll
        for (int nf = 0; nf < 4; nf++) {
            int gn = bn * 128 + wc * 64 + nf * 16 + fr;
            int vch = wc * 64 + nf * 16 + fr;
            float bi = bias[gn];
            float v0 = acc[mf][nf][0] + bi, v1 = acc[mf][nf][1] + bi;
            float v2 = acc[mf][nf][2] + bi, v3 = acc[mf][nf][3] + bi;
            float mx = fmaxf(fmaxf(v0, v1), fmaxf(v2, v3));
            mx = fmaxf(mx, __shfl_xor(mx, 16));
            mx = fmaxf(mx, __shfl_xor(mx, 32));
            float e0 = __expf(v0 - mx), e1 = __expf(v1 - mx);
            float e2 = __expf(v2 - mx), e3 = __expf(v3 - mx);
            float ws = e0 * bf2f(smem[(size_t)vrow * 128 + vch])
                     + e1 * bf2f(smem[(size_t)(vrow + 1) * 128 + vch])
                     + e2 * bf2f(smem[(size_t)(vrow + 2) * 128 + vch])
                     + e3 * bf2f(smem[(size_t)(vrow + 3) * 128 + vch]);
            float es = e0 + e1 + e2 + e3;
            ws += __shfl_xor(ws, 16); ws += __shfl_xor(ws, 32);
            es += __shfl_xor(es, 16); es += __shfl_xor(es, 32);
            if (fq == 0) out[((size_t)bb * Cc + gn) * Nc + nn] = ws / es;
        }
    }
}

// ---------------------------------------------------------------------------
extern "C" void kernel_launch(void* const* d_in, const int* in_sizes, int n_in,
                              void* d_out, int out_size, void* d_ws, size_t ws_size,
                              hipStream_t stream) {
    (void)in_sizes; (void)n_in; (void)out_size;
    const float* pcd     = (const float*)d_in[0];
    const float* feat    = (const float*)d_in[1];
    const float* pcd_db  = (const float*)d_in[2];
    const float* feat_db = (const float*)d_in[3];
    const float* pw1 = (const float*)d_in[4];
    const float* pb1 = (const float*)d_in[5];
    const float* pg  = (const float*)d_in[6];
    const float* pbb = (const float*)d_in[7];
    const float* pm  = (const float*)d_in[8];
    const float* pv  = (const float*)d_in[9];
    const float* pw2 = (const float*)d_in[10];
    const float* pb2 = (const float*)d_in[11];
    const float* aw1 = (const float*)d_in[12];
    const float* ab1 = (const float*)d_in[13];
    const float* ag  = (const float*)d_in[14];
    const float* abb = (const float*)d_in[15];
    const float* am  = (const float*)d_in[16];
    const float* av  = (const float*)d_in[17];
    const float* aw2 = (const float*)d_in[18];
    const float* ab2 = (const float*)d_in[19];
    float* out = (float*)d_out;

    char* base = (char*)d_ws;
    size_t off = 0;
    auto alloc = [&](size_t bytes) -> char* {
        char* r = base + off;
        off = (off + bytes + 255) & ~(size_t)255;
        return r;
    };
    int*   idxb  = (int*)alloc((size_t)RT * 4);
    float* featT = (float*)alloc((size_t)Bc * Sc * Cc * 4);
    u16*   W1b   = (u16*)alloc((size_t)AH * Cc * 2);
    float* bias1 = (float*)alloc((size_t)AH * 4);
    u16*   W2b   = (u16*)alloc((size_t)Cc * AH * 2);
    u16*   PW2b  = (u16*)alloc((size_t)Cc * PH * 2);
    u16*   Hb    = (u16*)alloc((size_t)RT * PH * 2);

    // chunked row pipeline: cr=32768 is the measured optimum (r14/r17: 338 us).
    const size_t perrow = 1024 + 1024 + 2048;  // X,V bf16 + A bf16
    int cr = 32768;
    size_t avail = ws_size > off ? ws_size - off : 0;
    if (avail < (size_t)cr * perrow) {
        cr = (int)((avail / perrow) & ~(size_t)127);
        if (cr < 128) cr = 128;
    }
    u16*   Xb = (u16*)alloc((size_t)cr * Cc * 2);
    u16*   Vb = (u16*)alloc((size_t)cr * Cc * 2);
    u16*   Ab = (u16*)alloc((size_t)cr * AH * 2);

    transpose_kernel<<<dim3(Bc * 40 * 8), dim3(256), 0, stream>>>(feat, feat_db, featT);
    prep_kernel<<<dim3((AH * Cc) / 256), dim3(256), 0, stream>>>(aw1, ab1, ag, abb, am, av, aw2, pw2,
                                                                 W1b, bias1, W2b, PW2b);
    knn_kernel<<<dim3(Bc * Nc / 4), dim3(256), 0, stream>>>(pcd, pcd_db, idxb);
    hker<<<dim3(RT / 256), dim3(256), 0, stream>>>(pcd, pcd_db, idxb, pw1, pb1, pg, pbb, pm, pv, Hb);

    for (int r0 = 0; r0 < RT; r0 += cr) {
        int rows = (RT - r0 < cr) ? (RT - r0) : cr;
        pgemm_fused<<<dim3(rows / 128, Cc / 128), dim3(256), 0, stream>>>(Hb, PW2b, pb2, featT, idxb,
                                                                          Xb, Vb, r0);
        gemm_bt<true, true><<<dim3(rows / 128, AH / 128), dim3(256), 0, stream>>>(Xb, W1b, bias1, Ab, rows, AH, Cc);
        gemm2_fused<<<dim3(rows / 128, Cc / 128), dim3(256), 0, stream>>>(Ab, W2b, ab2, Vb, out, r0, AH);
    }
}

// Round 24
// 293.414 us; speedup vs baseline: 1.3041x; 1.0099x over previous
//
#include <hip/hip_runtime.h>

typedef unsigned short u16;
typedef unsigned int   u32;
typedef __attribute__((ext_vector_type(8))) short bf16x8;
typedef __attribute__((ext_vector_type(4))) float f32x4;
typedef __attribute__((ext_vector_type(4))) u32   u32x4;

// Problem constants
constexpr int Bc = 2, Cc = 512, Nc = 2048, Mc = 512, Sc = 2560, Kc = 16, PH = 64, AH = 1024;
constexpr int RT = Bc * Nc * Kc;  // 65536 rows (b,n,k)
constexpr float EPS = 1e-5f;

__device__ __forceinline__ u16 f2bf(float f) {
    u32 u = __float_as_uint(f);
    u32 r = (u + 0x7fffu + ((u >> 16) & 1u)) >> 16;  // RNE
    return (u16)r;
}
__device__ __forceinline__ float bf2f(u16 h) { return __uint_as_float(((u32)h) << 16); }

__device__ __forceinline__ void gload_lds16(const void* g, void* l) {
    __builtin_amdgcn_global_load_lds((const __attribute__((address_space(1))) u32*)g,
                                     (__attribute__((address_space(3))) u32*)l, 16, 0, 0);
}

// Bijective XCD-aware workgroup swizzle (m204 form): same-XCD wgs get a
// contiguous run of linear ids. With bn-fastest linearization this makes an
// XCD reuse one A-panel across all bn tiles (L2 locality).
__device__ __forceinline__ void xcd_tiles(u32& bm, u32& bn) {
    u32 gdx = gridDim.x, gdy = gridDim.y;
    u32 nwg = gdx * gdy;
    u32 wg = blockIdx.x + gdx * blockIdx.y;
    u32 q = nwg >> 3, r8 = nwg & 7;
    u32 xcd = wg & 7, loc = wg >> 3;
    u32 swz = (xcd < r8 ? xcd * (q + 1) : r8 * (q + 1) + (xcd - r8) * q) + loc;
    bn = swz % gdy;   // bn fastest within an XCD's contiguous run
    bm = swz / gdy;
}

// lex-min on (d, s): total order, associative -> tree order == scan order
__device__ __forceinline__ void lmin(float& da, int& sa, float db, int sb) {
    bool better = (db < da) || (db == da && sb < sa);
    da = better ? db : da;
    sa = better ? sb : sa;
}

// ---------------------------------------------------------------------------
// Transpose fusion_feat [B,C,S(split)] f32 -> featT [B,S,C] f32
// ---------------------------------------------------------------------------
__global__ __launch_bounds__(256) void transpose_kernel(const float* __restrict__ feat,
                                                        const float* __restrict__ feat_db,
                                                        float* __restrict__ featT) {
    __shared__ float tile[64][65];
    int bid = blockIdx.x;
    int b = bid / (40 * 8);
    int rem = bid - b * (40 * 8);
    int st = rem >> 3, ct = rem & 7;
    int t = threadIdx.x, lane = t & 63, g = t >> 6;
    int s0 = st * 64, c0 = ct * 64;
    const float* src;
    int sl0, stride;
    if (s0 < Nc) { src = feat + (size_t)b * Cc * Nc; sl0 = s0; stride = Nc; }
    else         { src = feat_db + (size_t)b * Cc * Mc; sl0 = s0 - Nc; stride = Mc; }
#pragma unroll
    for (int i = 0; i < 16; i++) {
        int cl = g * 16 + i;
        tile[cl][lane] = src[(size_t)(c0 + cl) * stride + sl0 + lane];
    }
    __syncthreads();
#pragma unroll
    for (int i = 0; i < 16; i++) {
        int sl = g * 16 + i;
        featT[((size_t)b * Sc + s0 + sl) * Cc + c0 + lane] = tile[lane][sl];
    }
}

// ---------------------------------------------------------------------------
// Weight prep: fold attn BN into W1/bias1, cast attn W1/W2 + pos W2 to bf16
// ---------------------------------------------------------------------------
__global__ __launch_bounds__(256) void prep_kernel(const float* __restrict__ aw1, const float* __restrict__ ab1,
                                                   const float* __restrict__ ag, const float* __restrict__ abb,
                                                   const float* __restrict__ am, const float* __restrict__ av,
                                                   const float* __restrict__ aw2, const float* __restrict__ pw2,
                                                   u16* __restrict__ W1b, float* __restrict__ bias1,
                                                   u16* __restrict__ W2b, u16* __restrict__ PW2b) {
    int i = blockIdx.x * 256 + threadIdx.x;  // grid covers 524288
    if (i < AH * Cc) {
        int o = i >> 9;
        float inv = ag[o] / sqrtf(av[o] + EPS);
        W1b[i] = f2bf(aw1[i] * inv);
    }
    if (i < AH) {
        float inv = ag[i] / sqrtf(av[i] + EPS);
        bias1[i] = ab1[i] * inv + abb[i] - am[i] * inv;
    }
    if (i < Cc * AH) W2b[i] = f2bf(aw2[i]);
    if (i < Cc * PH) PW2b[i] = f2bf(pw2[i]);
}

// ---------------------------------------------------------------------------
// KNN (v1 + tree-scan): one wave per query; distances mirror the reference
// decomposition qq + ss - 2*dot, no fma contraction; ties -> smaller index.
// ---------------------------------------------------------------------------
__global__ __launch_bounds__(256) void knn_kernel(const float* __restrict__ pcd,
                                                  const float* __restrict__ pcd_db,
                                                  int* __restrict__ idxout) {
    int t = threadIdx.x, w = t >> 6, l = t & 63;
    int q = blockIdx.x * 4 + w;  // 0..4095
    int b = q >> 11, n = q & (Nc - 1);
    const float* pc = pcd + (size_t)b * 3 * Nc;
    const float* pd = pcd_db + (size_t)b * 3 * Mc;
    float qx = pc[n], qy = pc[Nc + n], qz = pc[2 * Nc + n];
    float qq = __fadd_rn(__fadd_rn(__fmul_rn(qx, qx), __fmul_rn(qy, qy)), __fmul_rn(qz, qz));
    float dist[40];
#pragma unroll
    for (int j = 0; j < 40; j++) {
        int s = j * 64 + l;
        float sx, sy, sz;
        if (s < Nc) { sx = pc[s]; sy = pc[Nc + s]; sz = pc[2 * Nc + s]; }
        else { int ss = s - Nc; sx = pd[ss]; sy = pd[Mc + ss]; sz = pd[2 * Mc + ss]; }
        float ss2 = __fadd_rn(__fadd_rn(__fmul_rn(sx, sx), __fmul_rn(sy, sy)), __fmul_rn(sz, sz));
        float dt  = __fadd_rn(__fadd_rn(__fmul_rn(qx, sx), __fmul_rn(qy, sy)), __fmul_rn(qz, sz));
        dist[j] = __fsub_rn(__fadd_rn(qq, ss2), __fmul_rn(2.0f, dt));
    }
    for (int r = 0; r < 16; r++) {
        // tree lex-min over the 40 (dist[j], j*64+l) pairs
        float td[20];
        int   ts[20];
#pragma unroll
        for (int i = 0; i < 20; i++) {
            float d0 = dist[2 * i], d1 = dist[2 * i + 1];
            int s0 = (2 * i) * 64 + l, s1 = (2 * i + 1) * 64 + l;
            bool bt = (d1 < d0) || (d1 == d0 && s1 < s0);
            td[i] = bt ? d1 : d0;
            ts[i] = bt ? s1 : s0;
        }
#pragma unroll
        for (int i = 0; i < 10; i++) lmin(td[i], ts[i], td[i + 10], ts[i + 10]);
#pragma unroll
        for (int i = 0; i < 5; i++) lmin(td[i], ts[i], td[i + 5], ts[i + 5]);
        lmin(td[0], ts[0], td[3], ts[3]);
        lmin(td[1], ts[1], td[4], ts[4]);
        lmin(td[0], ts[0], td[2], ts[2]);
        lmin(td[0], ts[0], td[1], ts[1]);
        float bd = td[0];
        int   bs = ts[0];
        for (int off = 32; off; off >>= 1) {
            float od = __shfl_xor(bd, off);
            int   os = __shfl_xor(bs, off);
            bool better = (od < bd) || (od == bd && os < bs);
            bd = better ? od : bd;
            bs = better ? os : bs;
        }
        if (l == 0) idxout[q * 16 + r] = bs;
        int wj = bs >> 6, wl = bs & 63;
        if (l == wl) {
#pragma unroll
            for (int j = 0; j < 40; j++)
                if (j == wj) dist[j] = 1e30f;
        }
    }
}

// ---------------------------------------------------------------------------
// HKER: per row, pos-MLP layer-1: h[r][64] = relu(BN(W1 (q - s) + b1)) bf16
// ---------------------------------------------------------------------------
__global__ __launch_bounds__(256) void hker(const float* __restrict__ pcd, const float* __restrict__ pcd_db,
                                            const int* __restrict__ idxb,
                                            const float* __restrict__ pw1, const float* __restrict__ pb1,
                                            const float* __restrict__ pg, const float* __restrict__ pbb,
                                            const float* __restrict__ pm, const float* __restrict__ pv,
                                            u16* __restrict__ H) {
    __shared__ float W1s[64][4];
    int t = threadIdx.x;
    if (t < 64) {
        float inv = pg[t] / sqrtf(pv[t] + EPS);
        W1s[t][0] = pw1[t * 3 + 0] * inv;
        W1s[t][1] = pw1[t * 3 + 1] * inv;
        W1s[t][2] = pw1[t * 3 + 2] * inv;
        W1s[t][3] = pb1[t] * inv + pbb[t] - pm[t] * inv;
    }
    __syncthreads();
    int r = blockIdx.x * 256 + t;
    int b = r >> 15, n = (r >> 4) & (Nc - 1), s = idxb[r];
    const float* pc = pcd + (size_t)b * 3 * Nc;
    float qx = pc[n], qy = pc[Nc + n], qz = pc[2 * Nc + n];
    float sx, sy, sz;
    if (s < Nc) { sx = pc[s]; sy = pc[Nc + s]; sz = pc[2 * Nc + s]; }
    else {
        const float* pd = pcd_db + (size_t)b * 3 * Mc;
        int ss = s - Nc;
        sx = pd[ss]; sy = pd[Mc + ss]; sz = pd[2 * Mc + ss];
    }
    float dx = qx - sx, dy = qy - sy, dz = qz - sz;
    u16* hp = H + (size_t)r * 64;
#pragma unroll
    for (int u0 = 0; u0 < 64; u0 += 8) {
        u16 e[8];
#pragma unroll
        for (int j = 0; j < 8; j++) {
            int u = u0 + j;
            float hv = fmaxf(0.f, dx * W1s[u][0] + dy * W1s[u][1] + dz * W1s[u][2] + W1s[u][3]);
            e[j] = f2bf(hv);
        }
        u32x4 pk;
        pk.x = (u32)e[0] | ((u32)e[1] << 16); pk.y = (u32)e[2] | ((u32)e[3] << 16);
        pk.z = (u32)e[4] | ((u32)e[5] << 16); pk.w = (u32)e[6] | ((u32)e[7] << 16);
        *(u32x4*)(hp + u0) = pk;
    }
}

// ---------------------------------------------------------------------------
// PGEMM_FUSED: P = H @ PW2^T + pb2 via MFMA (M=rows, N=512, K=64), epilogue
// gathers f,g from featT and emits X = f-g+p, V = g+p (bf16).
// ---------------------------------------------------------------------------
__global__ __launch_bounds__(256) void pgemm_fused(const u16* __restrict__ Hg, const u16* __restrict__ Bg,
                                                   const float* __restrict__ pb2,
                                                   const float* __restrict__ featT, const int* __restrict__ idxb,
                                                   u16* __restrict__ X, u16* __restrict__ V, int row0) {
    __shared__ u16 As[128 * 64];
    __shared__ u16 Bs[128 * 64];
    const int t = threadIdx.x;
    u32 bmu, bnu;
    xcd_tiles(bmu, bnu);
    const int bm = (int)bmu, bn = (int)bnu;
    const int w = t >> 6, l = t & 63;
    const int wr = w >> 1, wc = w & 1;
    const int fr = l & 15, fq = l >> 4;
    f32x4 acc[4][4];
#pragma unroll
    for (int i = 0; i < 4; i++)
#pragma unroll
        for (int j = 0; j < 4; j++) {
            f32x4 z = {0.f, 0.f, 0.f, 0.f};
            acc[i][j] = z;
        }
    const char* Abase = (const char*)Hg + ((size_t)row0 + (size_t)bm * 128) * 64 * 2;
    const char* Bbase = (const char*)Bg + (size_t)bn * 128 * 64 * 2;
#pragma unroll
    for (int i = 0; i < 4; i++) {
        int chunk = i * 256 + t;
        int row = chunk >> 3;
        int cb = (chunk & 7) * 16;
        gload_lds16(Abase + (size_t)row * 128 + cb, (char*)As + chunk * 16);
    }
#pragma unroll
    for (int i = 0; i < 4; i++) {
        int chunk = i * 256 + t;
        int row = chunk >> 3;
        int cb = (chunk & 7) * 16;
        gload_lds16(Bbase + (size_t)row * 128 + cb, (char*)Bs + chunk * 16);
    }
    __syncthreads();
    bf16x8 af[4][2], bfv[4][2];
#pragma unroll
    for (int mf = 0; mf < 4; mf++)
#pragma unroll
        for (int ks = 0; ks < 2; ks++)
            af[mf][ks] = *(const bf16x8*)&As[(wr * 64 + mf * 16 + fr) * 64 + ks * 32 + fq * 8];
#pragma unroll
    for (int nf = 0; nf < 4; nf++)
#pragma unroll
        for (int ks = 0; ks < 2; ks++)
            bfv[nf][ks] = *(const bf16x8*)&Bs[(wc * 64 + nf * 16 + fr) * 64 + ks * 32 + fq * 8];
#pragma unroll
    for (int mf = 0; mf < 4; mf++)
#pragma unroll
        for (int nf = 0; nf < 4; nf++)
#pragma unroll
            for (int ks = 0; ks < 2; ks++)
                acc[mf][nf] = __builtin_amdgcn_mfma_f32_16x16x32_bf16(af[mf][ks], bfv[nf][ks], acc[mf][nf], 0, 0, 0);
    // epilogue: per C-row gather f,g; emit X,V
#pragma unroll
    for (int mf = 0; mf < 4; mf++) {
#pragma unroll
        for (int r = 0; r < 4; r++) {
            int gr = bm * 128 + wr * 64 + mf * 16 + fq * 4 + r;  // chunk-local row
            int grow = row0 + gr;                                 // global row
            int b = grow >> 15;
            int n = (grow >> 4) & (Nc - 1);
            int s = idxb[grow];
            const float* frow = featT + ((size_t)b * Sc + n) * Cc;
            const float* grow_p = featT + ((size_t)b * Sc + s) * Cc;
#pragma unroll
            for (int nf = 0; nf < 4; nf++) {
                int gn = bn * 128 + wc * 64 + nf * 16 + fr;
                float p = acc[mf][nf][r] + pb2[gn];
                float fv = frow[gn];
                float gv = grow_p[gn];
                X[(size_t)gr * Cc + gn] = f2bf(fv - gv + p);
                V[(size_t)gr * Cc + gn] = f2bf(gv + p);
            }
        }
    }
}

// ---------------------------------------------------------------------------
// GEMM (4-deep counted-vmcnt pipeline, BK=32, + XCD swizzle):
// C[m][n] = f(sum_k A[m][k]*B[n][k]+b). A [M][Kd], B [N][Kd] bf16 (B^T).
// ---------------------------------------------------------------------------
template <bool RELU, bool OBF16>
__global__ __launch_bounds__(256) void gemm_bt(const u16* __restrict__ Ag, const u16* __restrict__ Bg,
                                               const float* __restrict__ bias, void* __restrict__ Cg,
                                               int M, int N, int Kd) {
    __shared__ u16 smem[32768];  // 64 KB: 4 bufs x {As 8K | Bs 8K}
    const int t = threadIdx.x;
    u32 bmu, bnu;
    xcd_tiles(bmu, bnu);
    const int bm = (int)bmu, bn = (int)bnu;
    const int w = t >> 6, l = t & 63;
    const int wr = w >> 1, wc = w & 1;
    const int fr = l & 15, fq = l >> 4;
    f32x4 acc[4][4];
#pragma unroll
    for (int i = 0; i < 4; i++)
#pragma unroll
        for (int j = 0; j < 4; j++) {
            f32x4 z = {0.f, 0.f, 0.f, 0.f};
            acc[i][j] = z;
        }
    const char* Abase = (const char*)Ag + (size_t)bm * 128 * (size_t)Kd * 2;
    const char* Bbase = (const char*)Bg + (size_t)bn * 128 * (size_t)Kd * 2;
    const size_t ldb = (size_t)Kd * 2;

    auto stage = [&](int buf, int kt) {
        char* Ad = (char*)smem + (size_t)buf * 16384;
        char* Bd = Ad + 8192;
#pragma unroll
        for (int i = 0; i < 2; i++) {
            int chunk = i * 256 + t;
            int row = chunk >> 2;
            int cb = (chunk & 3) * 16;
            gload_lds16(Abase + (size_t)row * ldb + (size_t)kt * 2 + cb, Ad + chunk * 16);
        }
#pragma unroll
        for (int i = 0; i < 2; i++) {
            int chunk = i * 256 + t;
            int row = chunk >> 2;
            int cb = (chunk & 3) * 16;
            gload_lds16(Bbase + (size_t)row * ldb + (size_t)kt * 2 + cb, Bd + chunk * 16);
        }
    };

    const int nt = Kd / 32;   // 16 for gemm1
    stage(0, 0);
    stage(1, 32);
    stage(2, 64);
    for (int it = 0; it < nt; ++it) {
        if (it < nt - 2)      asm volatile("s_waitcnt vmcnt(8)" ::: "memory");
        else if (it == nt - 2) asm volatile("s_waitcnt vmcnt(4)" ::: "memory");
        else                   asm volatile("s_waitcnt vmcnt(0)" ::: "memory");
        __builtin_amdgcn_sched_barrier(0);
        __builtin_amdgcn_s_barrier();
        if (it + 3 < nt) stage((it + 3) & 3, (it + 3) * 32);
        const u16* As = smem + (size_t)(it & 3) * 8192;
        const u16* Bs = As + 4096;
        bf16x8 af[4], bfv[4];
#pragma unroll
        for (int mf = 0; mf < 4; mf++)
            af[mf] = *(const bf16x8*)&As[(wr * 64 + mf * 16 + fr) * 32 + fq * 8];
#pragma unroll
        for (int nf = 0; nf < 4; nf++)
            bfv[nf] = *(const bf16x8*)&Bs[(wc * 64 + nf * 16 + fr) * 32 + fq * 8];
#pragma unroll
        for (int mf = 0; mf < 4; mf++)
#pragma unroll
            for (int nf = 0; nf < 4; nf++)
                acc[mf][nf] = __builtin_amdgcn_mfma_f32_16x16x32_bf16(af[mf], bfv[nf], acc[mf][nf], 0, 0, 0);
    }
#pragma unroll
    for (int mf = 0; mf < 4; mf++) {
#pragma unroll
        for (int nf = 0; nf < 4; nf++) {
            int gn = bn * 128 + wc * 64 + nf * 16 + fr;
            float bi = bias[gn];
            int gm0 = bm * 128 + wr * 64 + mf * 16 + fq * 4;
#pragma unroll
            for (int r = 0; r < 4; r++) {
                float v = acc[mf][nf][r] + bi;
                if (RELU) v = fmaxf(v, 0.f);
                size_t o = (size_t)(gm0 + r) * N + gn;
                if (OBF16) ((u16*)Cg)[o] = f2bf(v);
                else ((float*)Cg)[o] = v;
            }
        }
    }
}

// ---------------------------------------------------------------------------
// GEMM2_FUSED (3-buffer counted-vmcnt pipeline, BK=32, 48 KB LDS):
// L = A @ W2^T + ab2 (M=rows, N=512, K=1024) with softmax-over-k +
// weighted-V reduce fused. 48 KB LDS -> 3 blocks/CU residency (vs 2 at
// 64 KB); 2 stages in flight, vmcnt(4) retires the oldest. Re-stage target
// (it+2)%3 == (it-1)%3, safe after the iter-it barrier. K-order unchanged
// -> bit-identical results. V tile (32 KB) reuses bufs 0-1.
// ---------------------------------------------------------------------------
__global__ __launch_bounds__(256) void gemm2_fused(const u16* __restrict__ Ag, const u16* __restrict__ Bg,
                                                   const float* __restrict__ bias, const u16* __restrict__ Vb,
                                                   float* __restrict__ out, int row0, int Kd) {
    __shared__ u16 smem[24576];  // 48 KB: 3 bufs x {As 8K | Bs 8K}
    const int t = threadIdx.x;
    u32 bmu, bnu;
    xcd_tiles(bmu, bnu);
    const int bm = (int)bmu, bn = (int)bnu;
    const int w = t >> 6, l = t & 63;
    const int wr = w >> 1, wc = w & 1;
    const int fr = l & 15, fq = l >> 4;
    f32x4 acc[4][4];
#pragma unroll
    for (int i = 0; i < 4; i++)
#pragma unroll
        for (int j = 0; j < 4; j++) {
            f32x4 z = {0.f, 0.f, 0.f, 0.f};
            acc[i][j] = z;
        }
    const char* Abase = (const char*)Ag + (size_t)bm * 128 * (size_t)Kd * 2;
    const char* Bbase = (const char*)Bg + (size_t)bn * 128 * (size_t)Kd * 2;
    const size_t ldb = (size_t)Kd * 2;

    auto stage = [&](int buf, int kt) {
        char* Ad = (char*)smem + (size_t)buf * 16384;
        char* Bd = Ad + 8192;
#pragma unroll
        for (int i = 0; i < 2; i++) {
            int chunk = i * 256 + t;
            int row = chunk >> 2;
            int cb = (chunk & 3) * 16;
            gload_lds16(Abase + (size_t)row * ldb + (size_t)kt * 2 + cb, Ad + chunk * 16);
        }
#pragma unroll
        for (int i = 0; i < 2; i++) {
            int chunk = i * 256 + t;
            int row = chunk >> 2;
            int cb = (chunk & 3) * 16;
            gload_lds16(Bbase + (size_t)row * ldb + (size_t)kt * 2 + cb, Bd + chunk * 16);
        }
    };

    const int nt = Kd / 32;   // 32
    stage(0, 0);
    stage(1, 32);
    int rb = 0;               // buffer holding tile 'it'
    for (int it = 0; it < nt; ++it) {
        // retire the oldest stage (4 loads); keep 1 newer stage in flight
        if (it < nt - 1) asm volatile("s_waitcnt vmcnt(4)" ::: "memory");
        else             asm volatile("s_waitcnt vmcnt(0)" ::: "memory");
        __builtin_amdgcn_sched_barrier(0);
        __builtin_amdgcn_s_barrier();
        int sb = rb + 2; if (sb >= 3) sb -= 3;      // == (it-1)%3, read finished pre-barrier
        if (it + 2 < nt) stage(sb, (it + 2) * 32);
        const u16* As = smem + (size_t)rb * 8192;
        const u16* Bs = As + 4096;
        bf16x8 af[4], bfv[4];
#pragma unroll
        for (int mf = 0; mf < 4; mf++)
            af[mf] = *(const bf16x8*)&As[(wr * 64 + mf * 16 + fr) * 32 + fq * 8];
#pragma unroll
        for (int nf = 0; nf < 4; nf++)
            bfv[nf] = *(const bf16x8*)&Bs[(wc * 64 + nf * 16 + fr) * 32 + fq * 8];
#pragma unroll
        for (int mf = 0; mf < 4; mf++)
#pragma unroll
            for (int nf = 0; nf < 4; nf++)
                acc[mf][nf] = __builtin_amdgcn_mfma_f32_16x16x32_bf16(af[mf], bfv[nf], acc[mf][nf], 0, 0, 0);
        rb += 1; if (rb == 3) rb = 0;
    }
    __builtin_amdgcn_s_barrier();   // all waves done reading last buf before V-stage overwrites
    // stage V tile [bm*128 .. +128)[bn*128 .. +128) into bufs 0-1 (coalesced)
    const char* Vbase = (const char*)Vb + (size_t)bm * 128 * Cc * 2 + (size_t)bn * 256;
#pragma unroll
    for (int i = 0; i < 8; i++) {
        int chunk = i * 256 + t;       // 0..2047
        int row = chunk >> 4;          // 0..127
        int cb = (chunk & 15) * 16;    // byte offset in row (256B rows)
        gload_lds16(Vbase + (size_t)row * (Cc * 2) + cb, (char*)smem + chunk * 16);
    }
    __syncthreads();
    // fused epilogue: per (point, channel) softmax over k=fq*4+r + V-reduce
#pragma unroll
    for (int mf = 0; mf < 4; mf++) {
        int lp = bm * 8 + wr * 4 + mf;        // chunk-local point
        int gp = row0 / 16 + lp;              // global point
        int bb = gp >> 11, nn = gp & (Nc - 1);
        int vrow = (wr * 4 + mf) * 16 + fq * 4;  // tile-local V row for r=0
#pragma unroll
        for (int nf = 0; nf < 4; nf++) {
            int gn = bn * 128 + wc * 64 + nf * 16 + fr;
            int vch = wc * 64 + nf * 16 + fr;
            float bi = bias[gn];
            float v0 = acc[mf][nf][0] + bi, v1 = acc[mf][nf][1] + bi;
            float v2 = acc[mf][nf][2] + bi, v3 = acc[mf][nf][3] + bi;
            float mx = fmaxf(fmaxf(v0, v1), fmaxf(v2, v3));
            mx = fmaxf(mx, __shfl_xor(mx, 16));
            mx = fmaxf(mx, __shfl_xor(mx, 32));
            float e0 = __expf(v0 - mx), e1 = __expf(v1 - mx);
            float e2 = __expf(v2 - mx), e3 = __expf(v3 - mx);
            float ws = e0 * bf2f(smem[(size_t)vrow * 128 + vch])
                     + e1 * bf2f(smem[(size_t)(vrow + 1) * 128 + vch])
                     + e2 * bf2f(smem[(size_t)(vrow + 2) * 128 + vch])
                     + e3 * bf2f(smem[(size_t)(vrow + 3) * 128 + vch]);
            float es = e0 + e1 + e2 + e3;
            ws += __shfl_xor(ws, 16); ws += __shfl_xor(ws, 32);
            es += __shfl_xor(es, 16); es += __shfl_xor(es, 32);
            if (fq == 0) out[((size_t)bb * Cc + gn) * Nc + nn] = ws / es;
        }
    }
}

// ---------------------------------------------------------------------------
extern "C" void kernel_launch(void* const* d_in, const int* in_sizes, int n_in,
                              void* d_out, int out_size, void* d_ws, size_t ws_size,
                              hipStream_t stream) {
    (void)in_sizes; (void)n_in; (void)out_size;
    const float* pcd     = (const float*)d_in[0];
    const float* feat    = (const float*)d_in[1];
    const float* pcd_db  = (const float*)d_in[2];
    const float* feat_db = (const float*)d_in[3];
    const float* pw1 = (const float*)d_in[4];
    const float* pb1 = (const float*)d_in[5];
    const float* pg  = (const float*)d_in[6];
    const float* pbb = (const float*)d_in[7];
    const float* pm  = (const float*)d_in[8];
    const float* pv  = (const float*)d_in[9];
    const float* pw2 = (const float*)d_in[10];
    const float* pb2 = (const float*)d_in[11];
    const float* aw1 = (const float*)d_in[12];
    const float* ab1 = (const float*)d_in[13];
    const float* ag  = (const float*)d_in[14];
    const float* abb = (const float*)d_in[15];
    const float* am  = (const float*)d_in[16];
    const float* av  = (const float*)d_in[17];
    const float* aw2 = (const float*)d_in[18];
    const float* ab2 = (const float*)d_in[19];
    float* out = (float*)d_out;

    char* base = (char*)d_ws;
    size_t off = 0;
    auto alloc = [&](size_t bytes) -> char* {
        char* r = base + off;
        off = (off + bytes + 255) & ~(size_t)255;
        return r;
    };
    int*   idxb  = (int*)alloc((size_t)RT * 4);
    float* featT = (float*)alloc((size_t)Bc * Sc * Cc * 4);
    u16*   W1b   = (u16*)alloc((size_t)AH * Cc * 2);
    float* bias1 = (float*)alloc((size_t)AH * 4);
    u16*   W2b   = (u16*)alloc((size_t)Cc * AH * 2);
    u16*   PW2b  = (u16*)alloc((size_t)Cc * PH * 2);
    u16*   Hb    = (u16*)alloc((size_t)RT * PH * 2);

    // chunked row pipeline: cr=32768 is the measured optimum (r14/r17: 338 us).
    const size_t perrow = 1024 + 1024 + 2048;  // X,V bf16 + A bf16
    int cr = 32768;
    size_t avail = ws_size > off ? ws_size - off : 0;
    if (avail < (size_t)cr * perrow) {
        cr = (int)((avail / perrow) & ~(size_t)127);
        if (cr < 128) cr = 128;
    }
    u16*   Xb = (u16*)alloc((size_t)cr * Cc * 2);
    u16*   Vb = (u16*)alloc((size_t)cr * Cc * 2);
    u16*   Ab = (u16*)alloc((size_t)cr * AH * 2);

    transpose_kernel<<<dim3(Bc * 40 * 8), dim3(256), 0, stream>>>(feat, feat_db, featT);
    prep_kernel<<<dim3((AH * Cc) / 256), dim3(256), 0, stream>>>(aw1, ab1, ag, abb, am, av, aw2, pw2,
                                                                 W1b, bias1, W2b, PW2b);
    knn_kernel<<<dim3(Bc * Nc / 4), dim3(256), 0, stream>>>(pcd, pcd_db, idxb);
    hker<<<dim3(RT / 256), dim3(256), 0, stream>>>(pcd, pcd_db, idxb, pw1, pb1, pg, pbb, pm, pv, Hb);

    for (int r0 = 0; r0 < RT; r0 += cr) {
        int rows = (RT - r0 < cr) ? (RT - r0) : cr;
        pgemm_fused<<<dim3(rows / 128, Cc / 128), dim3(256), 0, stream>>>(Hb, PW2b, pb2, featT, idxb,
                                                                          Xb, Vb, r0);
        gemm_bt<true, true><<<dim3(rows / 128, AH / 128), dim3(256), 0, stream>>>(Xb, W1b, bias1, Ab, rows, AH, Cc);
        gemm2_fused<<<dim3(rows / 128, Cc / 128), dim3(256), 0, stream>>>(Ab, W2b, ab2, Vb, out, r0, AH);
    }
}